// Round 10
// baseline (647.377 us; speedup 1.0000x reference)
//
#include <hip/hip_runtime.h>
#include <math.h>

#define FILTERS 8
#define NB 32
#define NT 16
#define NH 64
#define NW 64

typedef _Float16 f16;
typedef _Float16 half2f __attribute__((ext_vector_type(2)));
typedef _Float16 half4f __attribute__((ext_vector_type(4)));
typedef _Float16 half8f __attribute__((ext_vector_type(8)));
typedef float    floatx2 __attribute__((ext_vector_type(2)));
typedef float    floatx4 __attribute__((ext_vector_type(4)));

// LDS (bytes): H band 4 rows x 68 cols x 8ch f16 = 4352 ; X 4 x 68 x 4ch = 2176
#define H_OFF 0
#define X_OFF 4352
#define SMEM_BYTES 6528

__device__ __forceinline__ float hard_sigmoid(float v) {
    return fminf(fmaxf(fmaf(0.2f, v, 0.5f), 0.0f), 1.0f);
}
__device__ __forceinline__ float fast_tanh(float v) {
    float e = __builtin_amdgcn_exp2f(v * 2.8853900817779268f);
    return 1.0f - 2.0f * __builtin_amdgcn_rcpf(e + 1.0f);
}

// ---- Weight-fragment prepack (validated rounds 7-9) ----
__global__ __launch_bounds__(256) void prepack(
    const float* __restrict__ Wx,    // (3,3,3,32)
    const float* __restrict__ Wh,    // (3,3,8,32)
    const float* __restrict__ bias,  // (32,)
    f16* __restrict__ WB)            // 4096 entries
{
    int i = blockIdx.x * 256 + threadIdx.x;
    if (i >= 4096) return;
    int e = i & 7;
    int l = (i >> 3) & 63;
    int n = (i >> 9) & 1;
    int j = i >> 10;
    int h = l >> 4;
    int g = n * 16 + (l & 15);

    float wv = 0.f;
    if (j == 0) {
        wv = Wh[(h * 8 + e) * 32 + g];
    } else if (j == 1) {
        wv = Wh[((4 + h) * 8 + e) * 32 + g];
    } else if (j == 2 && h == 0) {
        wv = Wh[(8 * 8 + e) * 32 + g];
    } else if (j == 3 && h == 3) {
        wv = (e == 3) ? bias[g] : 0.f;   // bias rides the const-1.0 patch slot
    } else {
        int ty, txp;
        if (j == 2) { ty = (h == 3) ? 1 : 0; txp = (h == 2) ? 2 : 0; }
        else        { ty = (h == 0) ? 1 : 2; txp = (h == 1) ? 0 : 2; }
        int txq = txp + (e >> 2);
        int c = e & 3;
        if (txq < 3 && c < 3)
            wv = Wx[((ty * 3 + txq) * 3 + c) * 32 + g];
    }
    WB[i] = (f16)wv;
}

#define LDA(off) ({                                                        \
    half4f lo_ = *(const half4f*)(smem + (off));                           \
    half4f hi_ = *(const half4f*)(smem + (off) + 8);                       \
    __builtin_shufflevector(lo_, hi_, 0, 1, 2, 3, 4, 5, 6, 7); })

#define GATE_BODY(A0, A1, A2, A3, COLD0, COLD1, CC0, CC1, HH0, HH1)        \
    {                                                                      \
        floatx4 acc0 = {0.f, 0.f, 0.f, 0.f};                               \
        floatx4 acc1 = {0.f, 0.f, 0.f, 0.f};                               \
        acc0 = __builtin_amdgcn_mfma_f32_16x16x32_f16(B00, A0, acc0,0,0,0);\
        acc1 = __builtin_amdgcn_mfma_f32_16x16x32_f16(B01, A0, acc1,0,0,0);\
        acc0 = __builtin_amdgcn_mfma_f32_16x16x32_f16(B10, A1, acc0,0,0,0);\
        acc1 = __builtin_amdgcn_mfma_f32_16x16x32_f16(B11, A1, acc1,0,0,0);\
        acc0 = __builtin_amdgcn_mfma_f32_16x16x32_f16(B20, A2, acc0,0,0,0);\
        acc1 = __builtin_amdgcn_mfma_f32_16x16x32_f16(B21, A2, acc1,0,0,0);\
        acc0 = __builtin_amdgcn_mfma_f32_16x16x32_f16(B30, A3, acc0,0,0,0);\
        acc1 = __builtin_amdgcn_mfma_f32_16x16x32_f16(B31, A3, acc1,0,0,0);\
        float ex0 = (g4 & 2) ? acc0[0] : acc0[2];                          \
        float ex1 = (g4 & 2) ? acc0[1] : acc0[3];                          \
        float ex2 = (g4 & 2) ? acc1[0] : acc1[2];                          \
        float ex3 = (g4 & 2) ? acc1[1] : acc1[3];                          \
        ex0 = __shfl_xor(ex0, 32, 64);                                     \
        ex1 = __shfl_xor(ex1, 32, 64);                                     \
        ex2 = __shfl_xor(ex2, 32, 64);                                     \
        ex3 = __shfl_xor(ex3, 32, 64);                                     \
        float zi0, zi1, zf0, zf1, zc0, zc1, zo0, zo1;                      \
        if (g4 & 2) {                                                      \
            zi0 = ex0;     zi1 = ex1;     zf0 = acc0[2]; zf1 = acc0[3];    \
            zc0 = ex2;     zc1 = ex3;     zo0 = acc1[2]; zo1 = acc1[3];    \
        } else {                                                           \
            zi0 = acc0[0]; zi1 = acc0[1]; zf0 = ex0;     zf1 = ex1;        \
            zc0 = acc1[0]; zc1 = acc1[1]; zo0 = ex2;     zo1 = ex3;        \
        }                                                                  \
        float ig0 = hard_sigmoid(zi0), fg0 = hard_sigmoid(zf0);            \
        float cg0 = fast_tanh(zc0),    og0 = hard_sigmoid(zo0);            \
        CC0 = fmaf(fg0, COLD0, ig0 * cg0);                                 \
        HH0 = og0 * fast_tanh(CC0);                                        \
        float ig1 = hard_sigmoid(zi1), fg1 = hard_sigmoid(zf1);            \
        float cg1 = fast_tanh(zc1),    og1 = hard_sigmoid(zo1);            \
        CC1 = fmaf(fg1, COLD1, ig1 * cg1);                                 \
        HH1 = og1 * fast_tanh(CC1);                                        \
    }

// ---- Persistent cooperative kernel: all 16 steps, neighbor-flag pipeline ----
// 1024 blocks (co-resident, 4/CU). Block = (batch, 2-row strip), fixed for all
// t. c-state lives in registers. Per step: wait <=3 neighbor flags(t-1), stage
// 2 halo rows (own 2 rows persist in LDS), compute, store own h, release flag.
__global__ __launch_bounds__(256, 4) void convlstm_persist(
    const float* __restrict__ x,     // (B,T,H,W,3) f32
    const f16*   __restrict__ WB,    // prepacked weight fragments
    f16* __restrict__ hbuf0,         // (B,H,W,8) f16 ping  (final: t=15 writes here)
    f16* __restrict__ hbuf1,         // (B,H,W,8) f16 pong
    int* __restrict__ flags)         // [16][32][32], memset 0 per launch
{
    __shared__ __attribute__((aligned(16))) char smem[SMEM_BYTES];

    const int bid   = blockIdx.x;
    // XCD-local strips: batch fully contained in one XCD (bid%8 heuristic;
    // correctness does not depend on it - agent-scope sync throughout).
    const int xcd   = bid & 7;
    const int idx   = bid >> 3;
    const int bi    = (xcd << 2) | (idx >> 5);
    const int strip = idx & 31;
    const int r0    = strip << 1;
    const int tid   = threadIdx.x;
    const int w     = __builtin_amdgcn_readfirstlane(tid >> 6);
    const int lane  = tid & 63;
    const int p16   = lane & 15;
    const int g4    = lane >> 4;
    const int pr    = w >> 1;
    const int wcol  = (w & 1) << 5;

    // weight fragments: loaded ONCE for all 16 steps
    const half8f* WBv = (const half8f*)WB;
    half8f B00 = WBv[0*64+lane], B01 = WBv[1*64+lane];
    half8f B10 = WBv[2*64+lane], B11 = WBv[3*64+lane];
    half8f B20 = WBv[4*64+lane], B21 = WBv[5*64+lane];
    half8f B30 = WBv[6*64+lane], B31 = WBv[7*64+lane];

    // invariant addressing (validated tap->offset maps, rounds 7-9)
    const int f0  = (g4 & 1) * 4 + (g4 & 2);
    const int ty0 = (g4 >= 3) ? 1 : 0, tx0 = g4 - 3 * ty0;
    const int ty1 = 1 + ((g4 >= 2) ? 1 : 0), tx1 = (g4 + 4) - 3 * ty1;
    const int ty2 = (g4 == 3) ? 1 : 0, tx2 = (g4 == 2) ? 2 : 0;
    const int ty3 = (g4 == 0) ? 1 : 2, tx3 = (g4 == 1) ? 0 : 2;
    const int inc2 = (g4 == 0) ? 256 : 128;
    const int o0 = H_OFF + ((pr + ty0) * 68 + wcol + p16 + tx0) * 16;
    const int o1 = H_OFF + ((pr + ty1) * 68 + wcol + p16 + tx1) * 16;
    const int o2 = (g4 == 0) ? H_OFF + ((pr + 2) * 68 + wcol + p16 + 2) * 16
                             : X_OFF + ((pr + ty2) * 68 + wcol + p16 + tx2) * 8;
    const int o3 = X_OFF + ((pr + ty3) * 68 + wcol + p16 + tx3) * 8;
    const int ow0 = H_OFF + ((1 + pr) * 68 + 1 + wcol + p16) * 16 + f0 * 2;
    const size_t gp0 = (size_t)(bi * 4096 + (r0 + pr) * 64 + wcol + p16);

    const int slo = (strip == 0) ? 0 : strip - 1;
    const int shi = (strip == 31) ? 31 : strip + 1;

    floatx2 cA = {0.f, 0.f}, cB2 = {0.f, 0.f};   // c-state in registers

    // prologue: zero H band, stage x(0)
    for (int i = tid; i < 272; i += 256) {
        half8f zz = {0, 0, 0, 0, 0, 0, 0, 0};
        *(half8f*)(smem + H_OFF + i * 16) = zz;
    }
    {
        const float* xt = x + ((size_t)bi * NT * 4096) * 3;
        for (int i = tid; i < 272; i += 256) {
            int lr = i / 68, lc = i - lr * 68;
            int gr = r0 - 1 + lr, gc = lc - 1;
            half4f xv = {0, 0, 0, (f16)1.0f};
            if (((unsigned)gr < 64u) && ((unsigned)gc < 64u)) {
                const float* xp2 = xt + (gr * 64 + gc) * 3;
                xv[0] = (f16)xp2[0]; xv[1] = (f16)xp2[1]; xv[2] = (f16)xp2[2];
            }
            *(half4f*)(smem + X_OFF + i * 8) = xv;
        }
    }
    __syncthreads();

    for (int t = 0; t < NT; ++t) {
        const f16* hrd = (t & 1) ? hbuf1 : hbuf0;
        f16*       hwr = (t & 1) ? hbuf0 : hbuf1;

        if (t > 0) {
            if (tid == 0) {
                const int fb = (t - 1) * 1024 + bi * 32;
                for (int s = slo; s <= shi; ++s) {
                    int guard = 0;
                    while (__hip_atomic_load(&flags[fb + s], __ATOMIC_ACQUIRE,
                                             __HIP_MEMORY_SCOPE_AGENT) == 0 &&
                           guard < (1 << 17)) {
                        __builtin_amdgcn_s_sleep(2);
                        ++guard;
                    }
                }
            }
            __syncthreads();                     // A: flags seen, LDS tail done
            // stage halo rows 0 (r0-1) and 3 (r0+2) from neighbors' h
            if (tid < 136) {
                int br = (tid < 68) ? 0 : 3;
                int lc = tid - ((tid < 68) ? 0 : 68);
                int gr = r0 - 1 + br;
                int gc = lc - 1;
                half8f hv = {0, 0, 0, 0, 0, 0, 0, 0};
                if (((unsigned)gr < 64u) && ((unsigned)gc < 64u))
                    hv = *(const half8f*)(hrd + ((size_t)(bi * 4096 + gr * 64 + gc)) * 8);
                *(half8f*)(smem + H_OFF + (br * 68 + lc) * 16) = hv;
            }
            __syncthreads();                     // B: band ready
        }

        half2f hwA, hwB;
        {   // tile 0
            half8f a0 = LDA(o0), a1 = LDA(o1), a2 = LDA(o2), a3 = LDA(o3);
            float cc0, cc1, hh0, hh1;
            GATE_BODY(a0, a1, a2, a3, cA[0], cA[1], cc0, cc1, hh0, hh1);
            cA[0] = cc0; cA[1] = cc1;
            hwA[0] = (f16)hh0; hwA[1] = (f16)hh1;
            *(half2f*)(hwr + gp0 * 8 + f0) = hwA;
        }
        {   // tile 1
            half8f a0 = LDA(o0 + 256), a1 = LDA(o1 + 256);
            half8f a2 = LDA(o2 + inc2), a3 = LDA(o3 + 128);
            float cc0, cc1, hh0, hh1;
            GATE_BODY(a0, a1, a2, a3, cB2[0], cB2[1], cc0, cc1, hh0, hh1);
            cB2[0] = cc0; cB2[1] = cc1;
            hwB[0] = (f16)hh0; hwB[1] = (f16)hh1;
            *(half2f*)(hwr + (gp0 + 16) * 8 + f0) = hwB;
        }

        __syncthreads();   // C: LDS reads done; vmcnt(0) => h stores complete

        if (t < NT - 1) {
            if (tid == 0)
                __hip_atomic_store(&flags[t * 1024 + bi * 32 + strip], 1,
                                   __ATOMIC_RELEASE, __HIP_MEMORY_SCOPE_AGENT);
            // keep own h rows in LDS band rows 1,2 for next step
            *(half2f*)(smem + ow0)       = hwA;
            *(half2f*)(smem + ow0 + 256) = hwB;
            // stage x(t+1); ordered vs next compute by barriers A/B
            const float* xt = x + (((size_t)bi * NT + (t + 1)) * 4096) * 3;
            for (int i = tid; i < 272; i += 256) {
                int lr = i / 68, lc = i - lr * 68;
                int gr = r0 - 1 + lr, gc = lc - 1;
                half4f xv = {0, 0, 0, (f16)1.0f};
                if (((unsigned)gr < 64u) && ((unsigned)gc < 64u)) {
                    const float* xp2 = xt + (gr * 64 + gc) * 3;
                    xv[0] = (f16)xp2[0]; xv[1] = (f16)xp2[1]; xv[2] = (f16)xp2[2];
                }
                *(half4f*)(smem + X_OFF + i * 8) = xv;
            }
        }
    }
}

// ---- fallback: round-8 per-step kernel (validated, 109 us path) ----
__global__ __launch_bounds__(256, 4) void convlstm_step(
    const float* __restrict__ x,
    const f16*   __restrict__ WB,
    const f16*   __restrict__ h_in,
    f16*         __restrict__ h_out,
    float*       __restrict__ c_buf,
    int t, int first)
{
    __shared__ __attribute__((aligned(16))) char smem[SMEM_BYTES];

    const int bid = blockIdx.x;
    const int bi  = bid >> 5;
    const int r0  = (bid & 31) << 1;
    const int tid = threadIdx.x;
    const int w    = tid >> 6;
    const int lane = tid & 63;
    const int p16  = lane & 15;
    const int g4   = lane >> 4;
    const int pr   = w >> 1;
    const int wcol = (w & 1) << 5;

    const float* xt = x + (((size_t)bi * NT + t) * 4096) * 3;

    for (int i = tid; i < 272; i += 256) {
        int lr = i / 68;
        int lc = i - lr * 68;
        int gr = r0 - 1 + lr;
        int gc = lc - 1;
        bool ok = ((unsigned)gr < 64u) && ((unsigned)gc < 64u);
        half4f xv = {0, 0, 0, (f16)1.0f};
        half8f hv = {0, 0, 0, 0, 0, 0, 0, 0};
        if (ok) {
            const float* xp = xt + (gr * 64 + gc) * 3;
            xv[0] = (f16)xp[0]; xv[1] = (f16)xp[1]; xv[2] = (f16)xp[2];
            if (!first)
                hv = *(const half8f*)(h_in + ((size_t)(bi * 4096 + gr * 64 + gc)) * 8);
        }
        *(half8f*)(smem + H_OFF + i * 16) = hv;
        *(half4f*)(smem + X_OFF + i * 8)  = xv;
    }

    const half8f* WBv = (const half8f*)WB;
    half8f B00 = WBv[0*64+lane], B01 = WBv[1*64+lane];
    half8f B10 = WBv[2*64+lane], B11 = WBv[3*64+lane];
    half8f B20 = WBv[4*64+lane], B21 = WBv[5*64+lane];
    half8f B30 = WBv[6*64+lane], B31 = WBv[7*64+lane];

    const int f0 = (g4 & 1) * 4 + (g4 & 2);
    const size_t gp0 = (size_t)(bi * 4096 + (r0 + pr) * 64 + wcol + p16);
    const size_t gp1 = gp0 + 16;
    floatx2 cold0 = {0.f, 0.f}, cold1 = {0.f, 0.f};
    if (!first) {
        cold0 = *(const floatx2*)(c_buf + gp0 * 8 + f0);
        cold1 = *(const floatx2*)(c_buf + gp1 * 8 + f0);
    }

    __syncthreads();

    const int ty0 = (g4 >= 3) ? 1 : 0, tx0 = g4 - 3 * ty0;
    const int ty1 = 1 + ((g4 >= 2) ? 1 : 0), tx1 = (g4 + 4) - 3 * ty1;
    const int ty2 = (g4 == 3) ? 1 : 0, tx2 = (g4 == 2) ? 2 : 0;
    const int ty3 = (g4 == 0) ? 1 : 2, tx3 = (g4 == 1) ? 0 : 2;
    const int inc2 = (g4 == 0) ? 256 : 128;
    int o0 = H_OFF + ((pr + ty0) * 68 + wcol + p16 + tx0) * 16;
    int o1 = H_OFF + ((pr + ty1) * 68 + wcol + p16 + tx1) * 16;
    int o2 = (g4 == 0) ? H_OFF + ((pr + 2) * 68 + wcol + p16 + 2) * 16
                       : X_OFF + ((pr + ty2) * 68 + wcol + p16 + tx2) * 8;
    int o3 = X_OFF + ((pr + ty3) * 68 + wcol + p16 + tx3) * 8;

    #pragma unroll
    for (int tt = 0; tt < 2; ++tt) {
        half8f a0 = LDA(o0), a1 = LDA(o1), a2 = LDA(o2), a3 = LDA(o3);
        floatx2 cold = tt ? cold1 : cold0;
        float cc0, cc1, hh0, hh1;
        GATE_BODY(a0, a1, a2, a3, cold[0], cold[1], cc0, cc1, hh0, hh1);
        const size_t gp = tt ? gp1 : gp0;
        floatx2 cw = {cc0, cc1};
        *(floatx2*)(c_buf + gp * 8 + f0) = cw;
        half2f hw = {(f16)hh0, (f16)hh1};
        *(half2f*)(h_out + gp * 8 + f0) = hw;
        o0 += 256; o1 += 256; o2 += inc2; o3 += 128;
    }
}

__global__ __launch_bounds__(256) void head_partial(
    const f16* __restrict__ h,       // (B, 32768) f16
    const float* __restrict__ Wout,  // (32768, 4)
    float* __restrict__ partial)     // (B*16, 4)
{
    const int b = blockIdx.x >> 4;
    const int chunk = blockIdx.x & 15;
    const int tid = threadIdx.x;
    const f16* hb = h + (size_t)b * 32768 + chunk * 2048;
    const float* wb = Wout + (size_t)(chunk * 2048) * 4;

    float acc[4] = {0.f, 0.f, 0.f, 0.f};
    #pragma unroll
    for (int it = 0; it < 8; ++it) {
        int i = it * 256 + tid;
        float hv = (float)hb[i];
        float4 wv = *(const float4*)(wb + (size_t)i * 4);
        acc[0] = fmaf(hv, wv.x, acc[0]);
        acc[1] = fmaf(hv, wv.y, acc[1]);
        acc[2] = fmaf(hv, wv.z, acc[2]);
        acc[3] = fmaf(hv, wv.w, acc[3]);
    }
    #pragma unroll
    for (int j = 0; j < 4; ++j)
        #pragma unroll
        for (int off = 32; off >= 1; off >>= 1)
            acc[j] += __shfl_down(acc[j], off, 64);

    __shared__ float red[4][4];
    int lane = tid & 63, wv2 = tid >> 6;
    if (lane == 0) {
        #pragma unroll
        for (int j = 0; j < 4; ++j) red[wv2][j] = acc[j];
    }
    __syncthreads();
    if (tid == 0) {
        #pragma unroll
        for (int j = 0; j < 4; ++j)
            partial[(size_t)blockIdx.x * 4 + j] =
                red[0][j] + red[1][j] + red[2][j] + red[3][j];
    }
}

__global__ __launch_bounds__(64) void head_finish(
    const float* __restrict__ partial,
    const float* __restrict__ bout,
    float* __restrict__ out)
{
    int b = threadIdx.x;
    if (b >= NB) return;
    float logit[4] = {bout[0], bout[1], bout[2], bout[3]};
    #pragma unroll
    for (int k = 0; k < 16; ++k) {
        const float* p = partial + (size_t)(b * 16 + k) * 4;
        logit[0] += p[0]; logit[1] += p[1]; logit[2] += p[2]; logit[3] += p[3];
    }
    float m = fmaxf(fmaxf(logit[0], logit[1]), fmaxf(logit[2], logit[3]));
    float e[4], s = 0.f;
    #pragma unroll
    for (int j = 0; j < 4; ++j) { e[j] = expf(logit[j] - m); s += e[j]; }
    float inv = 1.0f / s;
    #pragma unroll
    for (int j = 0; j < 4; ++j) out[b * 4 + j] = e[j] * inv;
}

extern "C" void kernel_launch(void* const* d_in, const int* in_sizes, int n_in,
                              void* d_out, int out_size, void* d_ws, size_t ws_size,
                              hipStream_t stream) {
    const float* x    = (const float*)d_in[0];
    const float* Wx   = (const float*)d_in[1];
    const float* Wh   = (const float*)d_in[2];
    const float* b    = (const float*)d_in[3];
    const float* Wout = (const float*)d_in[4];
    const float* bout = (const float*)d_in[5];
    float* out = (float*)d_out;

    char* ws = (char*)d_ws;
    f16*   hA      = (f16*)ws;                        // 2 MB
    f16*   hB      = (f16*)(ws + (1u << 21));         // 2 MB
    float* cb      = (float*)(ws + (1u << 22));       // 4 MB (fallback only)
    f16*   WB      = (f16*)(ws + (1u << 23));         // 8 KB
    float* partial = (float*)(ws + (1u << 23) + 8192);
    int*   flags   = (int*)(ws + (1u << 23) + 32768); // 64 KB

    prepack<<<16, 256, 0, stream>>>(Wx, Wh, b, WB);
    hipMemsetAsync(flags, 0, 16 * 1024 * sizeof(int), stream);

    const float* xa = x; const f16* wba = WB;
    f16* h0a = hA; f16* h1a = hB; int* fla = flags;
    void* args[] = {(void*)&xa, (void*)&wba, (void*)&h0a, (void*)&h1a,
                    (void*)&fla};

    hipError_t err = hipLaunchCooperativeKernel(convlstm_persist,
                                                dim3(1024), dim3(256),
                                                args, 0, stream);
    if (err == hipSuccess) {
        // t=15 wrote hbuf0 = hA
        head_partial<<<512, 256, 0, stream>>>(hA, Wout, partial);
    } else {
        // fallback: round-8 16-launch path (hin/hout ping-pong, final in hB)
        for (int t = 0; t < NT; ++t) {
            const f16* hin = (t & 1) ? hA : hB;
            f16*       hout = (t & 1) ? hB : hA;
            convlstm_step<<<1024, 256, 0, stream>>>(xa, WB, hin, hout, cb,
                                                    t, (t == 0) ? 1 : 0);
        }
        head_partial<<<512, 256, 0, stream>>>(hB, Wout, partial);
    }
    head_finish<<<1, 64, 0, stream>>>(partial, bout, out);
}

// Round 11
// 326.031 us; speedup vs baseline: 1.9856x; 1.9856x over previous
//
#include <hip/hip_runtime.h>
#include <math.h>

#define NB 32
#define NT 16

typedef _Float16 f16;
typedef _Float16 half2f __attribute__((ext_vector_type(2)));
typedef _Float16 half4f __attribute__((ext_vector_type(4)));
typedef _Float16 half8f __attribute__((ext_vector_type(8)));
typedef float    floatx4 __attribute__((ext_vector_type(4)));

// Mega-kernel LDS layout (bytes). Padded 66x66 image (border = zero halo).
#define H_OFF   0
#define H_BYTES (66 * 66 * 16)          // 69696: 8ch f16 per pixel
#define X_OFF   H_BYTES
#define X_BYTES (66 * 66 * 8)           // 34848: 4ch f16 (ch3 == 1.0 bias feed)
#define WB_OFF  (X_OFF + X_BYTES)       // 104544
#define RED_OFF (WB_OFF + 8192)         // 112736
#define SMEM_TOTAL (RED_OFF + 256)      // 112992

__device__ __forceinline__ float hard_sigmoid(float v) {
    return fminf(fmaxf(fmaf(0.2f, v, 0.5f), 0.0f), 1.0f);
}
__device__ __forceinline__ float fast_tanh(float v) {
    float e = __builtin_amdgcn_exp2f(v * 2.8853900817779268f);
    return 1.0f - 2.0f * __builtin_amdgcn_rcpf(e + 1.0f);
}

// Weight-fragment entry. Same validated K-map as rounds 7-9; gate order
// PERMUTED so D-rows = [i,f,c,o] x filter: lane g4 gets acc0=[i,f,c,o] of
// filter g4, acc1=[i,f,c,o] of filter g4+4 -> NO cross-lane exchange needed.
__device__ __forceinline__ float wb_entry(int i, const float* Wx,
                                          const float* Wh, const float* bias) {
    int e = i & 7, l = (i >> 3) & 63, n = (i >> 9) & 1, j = i >> 10;
    int h = l >> 4;
    int rr = l & 15;
    int g = (rr & 3) * 8 + n * 4 + (rr >> 2);   // gate-type*8 + filter
    float wv = 0.f;
    if (j == 0) {
        wv = Wh[(h * 8 + e) * 32 + g];
    } else if (j == 1) {
        wv = Wh[((4 + h) * 8 + e) * 32 + g];
    } else if (j == 2 && h == 0) {
        wv = Wh[(64 + e) * 32 + g];
    } else if (j == 3 && h == 3) {
        wv = (e == 3) ? bias[g] : 0.f;          // bias rides const-1.0 x-ch3
    } else {
        int ty, txp;
        if (j == 2) { ty = (h == 3) ? 1 : 0; txp = (h == 2) ? 2 : 0; }
        else        { ty = (h == 0) ? 1 : 2; txp = (h == 1) ? 0 : 2; }
        int txq = txp + (e >> 2), c = e & 3;
        if (txq < 3 && c < 3)
            wv = Wx[((ty * 3 + txq) * 3 + c) * 32 + g];
    }
    return wv;
}

#define LDA(off) ({                                                        \
    half4f lo_ = *(const half4f*)(smem + (off));                           \
    half4f hi_ = *(const half4f*)(smem + (off) + 8);                       \
    __builtin_shufflevector(lo_, hi_, 0, 1, 2, 3, 4, 5, 6, 7); })

// 8 MFMA + gates, shuffle-free (permuted gate order).
#define GATE_BODY(A0, A1, A2, A3, COLD0, COLD1, CC0, CC1, HH0, HH1)        \
    {                                                                      \
        floatx4 acc0 = {0.f, 0.f, 0.f, 0.f};                               \
        floatx4 acc1 = {0.f, 0.f, 0.f, 0.f};                               \
        acc0 = __builtin_amdgcn_mfma_f32_16x16x32_f16(B00, A0, acc0,0,0,0);\
        acc1 = __builtin_amdgcn_mfma_f32_16x16x32_f16(B01, A0, acc1,0,0,0);\
        acc0 = __builtin_amdgcn_mfma_f32_16x16x32_f16(B10, A1, acc0,0,0,0);\
        acc1 = __builtin_amdgcn_mfma_f32_16x16x32_f16(B11, A1, acc1,0,0,0);\
        acc0 = __builtin_amdgcn_mfma_f32_16x16x32_f16(B20, A2, acc0,0,0,0);\
        acc1 = __builtin_amdgcn_mfma_f32_16x16x32_f16(B21, A2, acc1,0,0,0);\
        acc0 = __builtin_amdgcn_mfma_f32_16x16x32_f16(B30, A3, acc0,0,0,0);\
        acc1 = __builtin_amdgcn_mfma_f32_16x16x32_f16(B31, A3, acc1,0,0,0);\
        float ig0 = hard_sigmoid(acc0[0]), fg0 = hard_sigmoid(acc0[1]);    \
        float cg0 = fast_tanh(acc0[2]),    og0 = hard_sigmoid(acc0[3]);    \
        CC0 = fmaf(fg0, COLD0, ig0 * cg0);                                 \
        HH0 = og0 * fast_tanh(CC0);                                        \
        float ig1 = hard_sigmoid(acc1[0]), fg1 = hard_sigmoid(acc1[1]);    \
        float cg1 = fast_tanh(acc1[2]),    og1 = hard_sigmoid(acc1[3]);    \
        CC1 = fmaf(fg1, COLD1, ig1 * cg1);                                 \
        HH1 = og1 * fast_tanh(CC1);                                        \
    }

// ---- THE kernel: 1 block = 1 batch, whole image in LDS, 16 steps + head ----
__global__ __launch_bounds__(1024) void convlstm_mega(
    const float* __restrict__ x,     // (B,T,H,W,3) f32
    const float* __restrict__ Wx,    // (3,3,3,32)
    const float* __restrict__ Wh,    // (3,3,8,32)
    const float* __restrict__ bias,  // (32,)
    const float* __restrict__ Wout,  // (32768, 4)
    const float* __restrict__ bout,  // (4,)
    float* __restrict__ out)         // (B, 4)
{
    extern __shared__ char smem[];

    const int bi   = blockIdx.x;
    const int tid  = threadIdx.x;
    const int wv   = __builtin_amdgcn_readfirstlane(tid >> 6);  // wave 0..15
    const int lane = tid & 63;
    const int p16  = lane & 15;
    const int g4   = lane >> 4;

    // ---- prologue: zero H everywhere; X borders = {0,0,0,1} ----
    for (int i = tid; i < 4356; i += 1024) {
        half8f zz = {0, 0, 0, 0, 0, 0, 0, 0};
        *(half8f*)(smem + H_OFF + i * 16) = zz;
        int prp = i / 66, pcp = i - prp * 66;
        if (prp == 0 || prp == 65 || pcp == 0 || pcp == 65) {
            half4f xb = {0, 0, 0, (f16)1.0f};
            *(half4f*)(smem + X_OFF + i * 8) = xb;
        }
    }
    // ---- WB prepack into LDS (4 entries/thread) ----
    #pragma unroll
    for (int k = 0; k < 4; ++k) {
        int i = tid * 4 + k;
        *(f16*)(smem + WB_OFF + i * 2) = (f16)wb_entry(i, Wx, Wh, bias);
    }
    // ---- stage x(0) interior ----
    {
        const float* xt = x + ((size_t)bi * NT) * 4096 * 3;
        #pragma unroll
        for (int k = 0; k < 4; ++k) {
            int px = tid + k * 1024;
            float x0 = xt[px * 3], x1 = xt[px * 3 + 1], x2 = xt[px * 3 + 2];
            half4f xv = {(f16)x0, (f16)x1, (f16)x2, (f16)1.0f};
            int pr = px >> 6, pc = px & 63;
            *(half4f*)(smem + X_OFF + ((pr + 1) * 66 + pc + 1) * 8) = xv;
        }
    }
    __syncthreads();

    // ---- weight fragments (registers, all 16 steps) ----
    half8f B00 = *(half8f*)(smem + WB_OFF + (0 * 64 + lane) * 16);
    half8f B01 = *(half8f*)(smem + WB_OFF + (1 * 64 + lane) * 16);
    half8f B10 = *(half8f*)(smem + WB_OFF + (2 * 64 + lane) * 16);
    half8f B11 = *(half8f*)(smem + WB_OFF + (3 * 64 + lane) * 16);
    half8f B20 = *(half8f*)(smem + WB_OFF + (4 * 64 + lane) * 16);
    half8f B21 = *(half8f*)(smem + WB_OFF + (5 * 64 + lane) * 16);
    half8f B30 = *(half8f*)(smem + WB_OFF + (6 * 64 + lane) * 16);
    half8f B31 = *(half8f*)(smem + WB_OFF + (7 * 64 + lane) * 16);

    // tap->offset constants (validated rounds 7-9; stride 66 here)
    const int ty0 = (g4 >= 3) ? 1 : 0, tx0 = g4 - 3 * ty0;
    const int ty1 = 1 + ((g4 >= 2) ? 1 : 0), tx1 = (g4 + 4) - 3 * ty1;
    const int ty2 = (g4 == 3) ? 1 : 0, tx2 = (g4 == 2) ? 2 : 0;
    const int ty3 = (g4 == 0) ? 1 : 2, tx3 = (g4 == 1) ? 0 : 2;

    float   cst0[16], cst1[16];          // c-state: filters g4, g4+4
    #pragma unroll
    for (int i = 0; i < 16; ++i) { cst0[i] = 0.f; cst1[i] = 0.f; }
    half2f hold[16];

    for (int t = 0; t < NT; ++t) {
        // prefetch x(t+1) to regs (latency hides under conv)
        float xr0[4], xr1[4], xr2[4];
        if (t < NT - 1) {
            const float* xt = x + ((size_t)bi * NT + t + 1) * 4096 * 3;
            #pragma unroll
            for (int k = 0; k < 4; ++k) {
                int px = tid + k * 1024;
                xr0[k] = xt[px * 3];
                xr1[k] = xt[px * 3 + 1];
                xr2[k] = xt[px * 3 + 2];
            }
        }
        // conv: wave wv owns rows wv*4..wv*4+3, 4 col-tiles of 16
        #pragma unroll
        for (int tr = 0; tr < 4; ++tr) {
            const int r = wv * 4 + tr;
            #pragma unroll
            for (int ct = 0; ct < 4; ++ct) {
                const int c  = ct * 16 + p16;
                const int ti = tr * 4 + ct;
                const int o0 = H_OFF + ((r + ty0) * 66 + c + tx0) * 16;
                const int o1 = H_OFF + ((r + ty1) * 66 + c + tx1) * 16;
                const int o2 = (g4 == 0)
                    ? H_OFF + ((r + 2) * 66 + c + 2) * 16
                    : X_OFF + ((r + ty2) * 66 + c + tx2) * 8;
                const int o3 = X_OFF + ((r + ty3) * 66 + c + tx3) * 8;
                half8f a0 = LDA(o0), a1 = LDA(o1), a2 = LDA(o2), a3 = LDA(o3);
                float cc0, cc1, hh0, hh1;
                GATE_BODY(a0, a1, a2, a3, cst0[ti], cst1[ti],
                          cc0, cc1, hh0, hh1);
                cst0[ti] = cc0; cst1[ti] = cc1;
                half2f hw = {(f16)hh0, (f16)hh1};
                hold[ti] = hw;
            }
        }
        __syncthreads();                 // all reads of h(t-1) complete

        if (t < NT - 1) {
            #pragma unroll
            for (int tr = 0; tr < 4; ++tr) {
                const int r = wv * 4 + tr;
                #pragma unroll
                for (int ct = 0; ct < 4; ++ct) {
                    const int c = ct * 16 + p16;
                    const int base = H_OFF + ((r + 1) * 66 + c + 1) * 16;
                    *(f16*)(smem + base + g4 * 2)       = hold[tr * 4 + ct][0];
                    *(f16*)(smem + base + (g4 + 4) * 2) = hold[tr * 4 + ct][1];
                }
            }
            #pragma unroll
            for (int k = 0; k < 4; ++k) {
                int px = tid + k * 1024;
                int pr = px >> 6, pc = px & 63;
                half4f xv = {(f16)xr0[k], (f16)xr1[k], (f16)xr2[k], (f16)1.0f};
                *(half4f*)(smem + X_OFF + ((pr + 1) * 66 + pc + 1) * 8) = xv;
            }
            __syncthreads();             // h(t), x(t+1) ready
        }
    }

    // ---- head: dot(h_final, Wout) from registers + block reduce + softmax ----
    float a0 = 0.f, a1 = 0.f, a2 = 0.f, a3 = 0.f;
    #pragma unroll
    for (int tr = 0; tr < 4; ++tr) {
        const int r = wv * 4 + tr;
        #pragma unroll
        for (int ct = 0; ct < 4; ++ct) {
            const int c = ct * 16 + p16;
            const int ti = tr * 4 + ct;
            float h0 = (float)hold[ti][0], h1 = (float)hold[ti][1];
            const int pix = r * 64 + c;
            float4 wA = *(const float4*)(Wout + (size_t)(pix * 8 + g4) * 4);
            float4 wB = *(const float4*)(Wout + (size_t)(pix * 8 + g4 + 4) * 4);
            a0 = fmaf(h0, wA.x, fmaf(h1, wB.x, a0));
            a1 = fmaf(h0, wA.y, fmaf(h1, wB.y, a1));
            a2 = fmaf(h0, wA.z, fmaf(h1, wB.z, a2));
            a3 = fmaf(h0, wA.w, fmaf(h1, wB.w, a3));
        }
    }
    #pragma unroll
    for (int off = 32; off >= 1; off >>= 1) {
        a0 += __shfl_down(a0, off, 64);
        a1 += __shfl_down(a1, off, 64);
        a2 += __shfl_down(a2, off, 64);
        a3 += __shfl_down(a3, off, 64);
    }
    if (lane == 0) {
        float4 v = {a0, a1, a2, a3};
        *(float4*)(smem + RED_OFF + wv * 16) = v;
    }
    __syncthreads();
    if (tid == 0) {
        float l0 = bout[0], l1 = bout[1], l2 = bout[2], l3 = bout[3];
        #pragma unroll
        for (int k = 0; k < 16; ++k) {
            float4 v = *(const float4*)(smem + RED_OFF + k * 16);
            l0 += v.x; l1 += v.y; l2 += v.z; l3 += v.w;
        }
        float m = fmaxf(fmaxf(l0, l1), fmaxf(l2, l3));
        float e0 = expf(l0 - m), e1 = expf(l1 - m);
        float e2 = expf(l2 - m), e3 = expf(l3 - m);
        float inv = 1.0f / (e0 + e1 + e2 + e3);
        out[bi * 4 + 0] = e0 * inv;
        out[bi * 4 + 1] = e1 * inv;
        out[bi * 4 + 2] = e2 * inv;
        out[bi * 4 + 3] = e3 * inv;
    }
}

// =================== fallback: r8-style multi-kernel path ===================
#define FB_XOFF 4352
#define FB_SMEM 6528

__global__ __launch_bounds__(256) void prepack_fb(
    const float* __restrict__ Wx, const float* __restrict__ Wh,
    const float* __restrict__ bias, f16* __restrict__ WB)
{
    int i = blockIdx.x * 256 + threadIdx.x;
    if (i < 4096) WB[i] = (f16)wb_entry(i, Wx, Wh, bias);
}

__global__ __launch_bounds__(256, 4) void convlstm_step_fb(
    const float* __restrict__ x, const f16* __restrict__ WB,
    const f16* __restrict__ h_in, f16* __restrict__ h_out,
    float* __restrict__ c_buf, int t, int first)
{
    __shared__ __attribute__((aligned(16))) char smem[FB_SMEM];

    const int bid = blockIdx.x;
    const int bi  = bid >> 5;
    const int r0  = (bid & 31) << 1;
    const int tid = threadIdx.x;
    const int w    = tid >> 6;
    const int lane = tid & 63;
    const int p16  = lane & 15;
    const int g4   = lane >> 4;
    const int pr   = w >> 1;
    const int wcol = (w & 1) << 5;

    const float* xt = x + (((size_t)bi * NT + t) * 4096) * 3;

    for (int i = tid; i < 272; i += 256) {
        int lr = i / 68, lc = i - lr * 68;
        int gr = r0 - 1 + lr, gc = lc - 1;
        bool ok = ((unsigned)gr < 64u) && ((unsigned)gc < 64u);
        half4f xv = {0, 0, 0, (f16)1.0f};
        half8f hv = {0, 0, 0, 0, 0, 0, 0, 0};
        if (ok) {
            const float* xp = xt + (gr * 64 + gc) * 3;
            xv[0] = (f16)xp[0]; xv[1] = (f16)xp[1]; xv[2] = (f16)xp[2];
            if (!first)
                hv = *(const half8f*)(h_in + ((size_t)(bi * 4096 + gr * 64 + gc)) * 8);
        }
        *(half8f*)(smem + i * 16) = hv;
        *(half4f*)(smem + FB_XOFF + i * 8) = xv;
    }

    const half8f* WBv = (const half8f*)WB;
    half8f B00 = WBv[0*64+lane], B01 = WBv[1*64+lane];
    half8f B10 = WBv[2*64+lane], B11 = WBv[3*64+lane];
    half8f B20 = WBv[4*64+lane], B21 = WBv[5*64+lane];
    half8f B30 = WBv[6*64+lane], B31 = WBv[7*64+lane];

    const size_t gp0 = (size_t)(bi * 4096 + (r0 + pr) * 64 + wcol + p16);
    const size_t gp1 = gp0 + 16;
    float c0a = 0.f, c0b = 0.f, c1a = 0.f, c1b = 0.f;
    if (!first) {
        c0a = c_buf[gp0 * 8 + g4]; c0b = c_buf[gp0 * 8 + g4 + 4];
        c1a = c_buf[gp1 * 8 + g4]; c1b = c_buf[gp1 * 8 + g4 + 4];
    }

    __syncthreads();

    const int ty0 = (g4 >= 3) ? 1 : 0, tx0 = g4 - 3 * ty0;
    const int ty1 = 1 + ((g4 >= 2) ? 1 : 0), tx1 = (g4 + 4) - 3 * ty1;
    const int ty2 = (g4 == 3) ? 1 : 0, tx2 = (g4 == 2) ? 2 : 0;
    const int ty3 = (g4 == 0) ? 1 : 2, tx3 = (g4 == 1) ? 0 : 2;
    const int inc2 = (g4 == 0) ? 256 : 128;
    int o0 = ((pr + ty0) * 68 + wcol + p16 + tx0) * 16;
    int o1 = ((pr + ty1) * 68 + wcol + p16 + tx1) * 16;
    int o2 = (g4 == 0) ? ((pr + 2) * 68 + wcol + p16 + 2) * 16
                       : FB_XOFF + ((pr + ty2) * 68 + wcol + p16 + tx2) * 8;
    int o3 = FB_XOFF + ((pr + ty3) * 68 + wcol + p16 + tx3) * 8;

    #pragma unroll
    for (int tt = 0; tt < 2; ++tt) {
        half8f a0 = LDA(o0), a1 = LDA(o1), a2 = LDA(o2), a3 = LDA(o3);
        float ca = tt ? c1a : c0a, cb2 = tt ? c1b : c0b;
        float cc0, cc1, hh0, hh1;
        GATE_BODY(a0, a1, a2, a3, ca, cb2, cc0, cc1, hh0, hh1);
        const size_t gp = tt ? gp1 : gp0;
        c_buf[gp * 8 + g4]     = cc0;
        c_buf[gp * 8 + g4 + 4] = cc1;
        h_out[gp * 8 + g4]     = (f16)hh0;
        h_out[gp * 8 + g4 + 4] = (f16)hh1;
        o0 += 256; o1 += 256; o2 += inc2; o3 += 128;
    }
}

__global__ __launch_bounds__(256) void head_partial(
    const f16* __restrict__ h, const float* __restrict__ Wout,
    float* __restrict__ partial)
{
    const int b = blockIdx.x >> 4;
    const int chunk = blockIdx.x & 15;
    const int tid = threadIdx.x;
    const f16* hb = h + (size_t)b * 32768 + chunk * 2048;
    const float* wb = Wout + (size_t)(chunk * 2048) * 4;

    float acc[4] = {0.f, 0.f, 0.f, 0.f};
    #pragma unroll
    for (int it = 0; it < 8; ++it) {
        int i = it * 256 + tid;
        float hv = (float)hb[i];
        float4 wv = *(const float4*)(wb + (size_t)i * 4);
        acc[0] = fmaf(hv, wv.x, acc[0]);
        acc[1] = fmaf(hv, wv.y, acc[1]);
        acc[2] = fmaf(hv, wv.z, acc[2]);
        acc[3] = fmaf(hv, wv.w, acc[3]);
    }
    #pragma unroll
    for (int j = 0; j < 4; ++j)
        #pragma unroll
        for (int off = 32; off >= 1; off >>= 1)
            acc[j] += __shfl_down(acc[j], off, 64);

    __shared__ float red[4][4];
    int lane = tid & 63, wv2 = tid >> 6;
    if (lane == 0) {
        #pragma unroll
        for (int j = 0; j < 4; ++j) red[wv2][j] = acc[j];
    }
    __syncthreads();
    if (tid == 0) {
        #pragma unroll
        for (int j = 0; j < 4; ++j)
            partial[(size_t)blockIdx.x * 4 + j] =
                red[0][j] + red[1][j] + red[2][j] + red[3][j];
    }
}

__global__ __launch_bounds__(64) void head_finish(
    const float* __restrict__ partial, const float* __restrict__ bout,
    float* __restrict__ out)
{
    int b = threadIdx.x;
    if (b >= NB) return;
    float logit[4] = {bout[0], bout[1], bout[2], bout[3]};
    #pragma unroll
    for (int k = 0; k < 16; ++k) {
        const float* p = partial + (size_t)(b * 16 + k) * 4;
        logit[0] += p[0]; logit[1] += p[1]; logit[2] += p[2]; logit[3] += p[3];
    }
    float m = fmaxf(fmaxf(logit[0], logit[1]), fmaxf(logit[2], logit[3]));
    float e[4], s = 0.f;
    #pragma unroll
    for (int j = 0; j < 4; ++j) { e[j] = expf(logit[j] - m); s += e[j]; }
    float inv = 1.0f / s;
    #pragma unroll
    for (int j = 0; j < 4; ++j) out[b * 4 + j] = e[j] * inv;
}

extern "C" void kernel_launch(void* const* d_in, const int* in_sizes, int n_in,
                              void* d_out, int out_size, void* d_ws, size_t ws_size,
                              hipStream_t stream) {
    const float* x    = (const float*)d_in[0];
    const float* Wx   = (const float*)d_in[1];
    const float* Wh   = (const float*)d_in[2];
    const float* b    = (const float*)d_in[3];
    const float* Wout = (const float*)d_in[4];
    const float* bout = (const float*)d_in[5];
    float* out = (float*)d_out;

    static bool attr_done = false;   // host-side only; idempotent, no capture op
    if (!attr_done) {
        hipFuncSetAttribute((const void*)convlstm_mega,
                            hipFuncAttributeMaxDynamicSharedMemorySize,
                            SMEM_TOTAL);
        attr_done = true;
    }

    convlstm_mega<<<dim3(NB), dim3(1024), SMEM_TOTAL, stream>>>(
        x, Wx, Wh, b, Wout, bout, out);
    hipError_t err = hipGetLastError();

    if (err != hipSuccess) {
        // fallback: round-8 style multi-kernel path
        char* ws = (char*)d_ws;
        f16*   hA      = (f16*)ws;                    // 2 MB
        f16*   hB      = (f16*)(ws + (1u << 21));     // 2 MB
        float* cb      = (float*)(ws + (1u << 22));   // 4 MB
        f16*   WB      = (f16*)(ws + (1u << 23));     // 8 KB
        float* partial = (float*)(ws + (1u << 23) + 8192);

        prepack_fb<<<16, 256, 0, stream>>>(Wx, Wh, b, WB);
        for (int t = 0; t < NT; ++t) {
            const f16* hin = (t & 1) ? hA : hB;
            f16*       hout = (t & 1) ? hB : hA;
            convlstm_step_fb<<<1024, 256, 0, stream>>>(x, WB, hin, hout, cb,
                                                       t, (t == 0) ? 1 : 0);
        }
        head_partial<<<512, 256, 0, stream>>>(hB, Wout, partial);
        head_finish<<<1, 64, 0, stream>>>(partial, bout, out);
    }
}

// Round 12
// 142.144 us; speedup vs baseline: 4.5544x; 2.2937x over previous
//
#include <hip/hip_runtime.h>
#include <math.h>

#define NB 32
#define NT 16

typedef _Float16 f16;
typedef _Float16 half2f __attribute__((ext_vector_type(2)));
typedef _Float16 half4f __attribute__((ext_vector_type(4)));
typedef _Float16 half8f __attribute__((ext_vector_type(8)));
typedef float    floatx4 __attribute__((ext_vector_type(4)));

// ---- workspace layout (bytes) for the fast path ----
#define XPAD_OFF  0u                     // (512, 4488, 4) f16 = 18,382,848
#define HPAD0_OFF 18382848u              // (32, 66, 68, 8) f16 = 2,297,856
#define HPAD1_OFF 20680704u
#define CBUF_OFF  22978560u              // (32, 64, 64, 8) f32 = 4,194,304
#define WBQ_OFF   27172864u              // 4096 f16 = 8192
#define PART_OFF  27181056u              // 1024 float4 = 16384
#define WS_NEED   27197440u

// ---- step-kernel LDS (bytes): H 4x68x16 = 4352, X 4x68x8 = 2176, red 64 ----
#define H_OFF 0
#define X_OFF 4352
#define RED_OFF 6528
#define SMEM_BYTES 6592

__device__ __forceinline__ float hard_sigmoid(float v) {
    return fminf(fmaxf(fmaf(0.2f, v, 0.5f), 0.0f), 1.0f);
}
__device__ __forceinline__ float fast_tanh(float v) {
    float e = __builtin_amdgcn_exp2f(v * 2.8853900817779268f);
    return 1.0f - 2.0f * __builtin_amdgcn_rcpf(e + 1.0f);
}

// Weight-fragment entry (validated r11: permuted gate order -> shuffle-free
// epilogue; lane g4 gets acc0=[i,f,c,o] of filter g4, acc1 of filter g4+4).
__device__ __forceinline__ float wb_entry(int i, const float* Wx,
                                          const float* Wh, const float* bias) {
    int e = i & 7, l = (i >> 3) & 63, n = (i >> 9) & 1, j = i >> 10;
    int h = l >> 4;
    int rr = l & 15;
    int g = (rr & 3) * 8 + n * 4 + (rr >> 2);   // gate-type*8 + filter
    float wv = 0.f;
    if (j == 0) {
        wv = Wh[(h * 8 + e) * 32 + g];
    } else if (j == 1) {
        wv = Wh[((4 + h) * 8 + e) * 32 + g];
    } else if (j == 2 && h == 0) {
        wv = Wh[(64 + e) * 32 + g];
    } else if (j == 3 && h == 3) {
        wv = (e == 3) ? bias[g] : 0.f;          // bias rides const-1.0 x-ch3
    } else {
        int ty, txp;
        if (j == 2) { ty = (h == 3) ? 1 : 0; txp = (h == 2) ? 2 : 0; }
        else        { ty = (h == 0) ? 1 : 2; txp = (h == 1) ? 0 : 2; }
        int txq = txp + (e >> 2), c = e & 3;
        if (txq < 3 && c < 3)
            wv = Wx[((ty * 3 + txq) * 3 + c) * 32 + g];
    }
    return wv;
}

#define LDA(off) ({                                                        \
    half4f lo_ = *(const half4f*)(smem + (off));                           \
    half4f hi_ = *(const half4f*)(smem + (off) + 8);                       \
    __builtin_shufflevector(lo_, hi_, 0, 1, 2, 3, 4, 5, 6, 7); })

// 8 MFMA + gates, shuffle-free (permuted gate order, validated r11).
#define GATE_BODY(A0, A1, A2, A3, COLD0, COLD1, CC0, CC1, HH0, HH1)        \
    {                                                                      \
        floatx4 acc0 = {0.f, 0.f, 0.f, 0.f};                               \
        floatx4 acc1 = {0.f, 0.f, 0.f, 0.f};                               \
        acc0 = __builtin_amdgcn_mfma_f32_16x16x32_f16(B00, A0, acc0,0,0,0);\
        acc1 = __builtin_amdgcn_mfma_f32_16x16x32_f16(B01, A0, acc1,0,0,0);\
        acc0 = __builtin_amdgcn_mfma_f32_16x16x32_f16(B10, A1, acc0,0,0,0);\
        acc1 = __builtin_amdgcn_mfma_f32_16x16x32_f16(B11, A1, acc1,0,0,0);\
        acc0 = __builtin_amdgcn_mfma_f32_16x16x32_f16(B20, A2, acc0,0,0,0);\
        acc1 = __builtin_amdgcn_mfma_f32_16x16x32_f16(B21, A2, acc1,0,0,0);\
        acc0 = __builtin_amdgcn_mfma_f32_16x16x32_f16(B30, A3, acc0,0,0,0);\
        acc1 = __builtin_amdgcn_mfma_f32_16x16x32_f16(B31, A3, acc1,0,0,0);\
        float ig0 = hard_sigmoid(acc0[0]), fg0 = hard_sigmoid(acc0[1]);    \
        float cg0 = fast_tanh(acc0[2]),    og0 = hard_sigmoid(acc0[3]);    \
        CC0 = fmaf(fg0, COLD0, ig0 * cg0);                                 \
        HH0 = og0 * fast_tanh(CC0);                                        \
        float ig1 = hard_sigmoid(acc1[0]), fg1 = hard_sigmoid(acc1[1]);    \
        float cg1 = fast_tanh(acc1[2]),    og1 = hard_sigmoid(acc1[3]);    \
        CC1 = fmaf(fg1, COLD1, ig1 * cg1);                                 \
        HH1 = og1 * fast_tanh(CC1);                                        \
    }

// ---- prep kernel: x -> padded f16 (ch3=1); WB prepack; h border zeros ----
// grid (19, 512): bx<18 -> xpad elements of image bt; bx==18,bt<16 -> WB;
// bx==18,bt>=16 -> zero borders of both padded h buffers.
__global__ __launch_bounds__(256) void xprep(
    const float* __restrict__ x,     // (B,T,64,64,3)
    const float* __restrict__ Wx, const float* __restrict__ Wh,
    const float* __restrict__ bias,
    f16* __restrict__ xpad,          // (512, 66*68, 4)
    f16* __restrict__ hpad0, f16* __restrict__ hpad1,
    f16* __restrict__ WB)
{
    const int bt  = blockIdx.y;      // b*16 + t
    const int bx  = blockIdx.x;
    const int tid = threadIdx.x;
    if (bx < 18) {
        int i = bx * 256 + tid;      // 0..4607 over 66*68=4488
        if (i < 4488) {
            int rr = i / 68, cc = i - rr * 68;
            half4f v = {0, 0, 0, (f16)1.0f};
            if (rr >= 1 && rr < 65 && cc >= 1 && cc < 65) {
                const float* xp = x + ((size_t)bt * 4096 + (rr - 1) * 64 + (cc - 1)) * 3;
                v[0] = (f16)xp[0]; v[1] = (f16)xp[1]; v[2] = (f16)xp[2];
            }
            *(half4f*)(xpad + ((size_t)bt * 4488 + i) * 4) = v;
        }
    } else if (bt < 16) {
        WB[bt * 256 + tid] = (f16)wb_entry(bt * 256 + tid, Wx, Wh, bias);
    } else {
        int i2 = (bt - 16) * 256 + tid;          // border zeros: 2*32*392
        if (i2 < 25088) {
            int buf = i2 / 12544;
            int k = i2 - buf * 12544;
            int b = k / 392;
            int p = k - b * 392;
            int rr, cc;
            if (p < 136) { rr = (p < 68) ? 0 : 65; cc = p - ((p < 68) ? 0 : 68); }
            else { int q = p - 136; rr = 1 + (q >> 2); int m = q & 3;
                   cc = (m == 0) ? 0 : 64 + m; }
            f16* hp = buf ? hpad1 : hpad0;
            half8f zz = {0, 0, 0, 0, 0, 0, 0, 0};
            *(half8f*)(hp + ((size_t)(b * 66 + rr) * 68 + cc) * 8) = zz;
        }
    }
}

// ---- step kernel (fast path): padded contiguous staging, fused head@t=15 ----
__global__ __launch_bounds__(256, 4) void convlstm_step(
    const f16* __restrict__ xpad,    // (512, 4488, 4)
    const f16* __restrict__ WB,
    const f16* __restrict__ h_in,    // padded (32,66,68,8)
    f16* __restrict__ h_out,         // padded
    float* __restrict__ c_buf,       // (32,64,64,8) f32
    const float* __restrict__ Wout,  // (32768,4)
    float* __restrict__ partial,     // (1024,4)
    int t, int first, int do_head)
{
    __shared__ __attribute__((aligned(16))) char smem[SMEM_BYTES];

    const int bid = blockIdx.x;
    const int bi  = bid >> 5;
    const int r0  = (bid & 31) << 1;
    const int tid = threadIdx.x;
    const int w    = tid >> 6;
    const int lane = tid & 63;
    const int p16  = lane & 15;
    const int g4   = lane >> 4;
    const int pr   = w >> 1;
    const int wcol = (w & 1) << 5;

    // ---- staging: pure contiguous row copies (no math, no converts) ----
    if (first) {
        for (int i = tid; i < 272; i += 256) {
            half8f zz = {0, 0, 0, 0, 0, 0, 0, 0};
            *(half8f*)(smem + H_OFF + i * 16) = zz;
        }
    } else {
        const f16* hsrc = h_in + ((size_t)(bi * 66 + r0) * 68) * 8;
        for (int i = tid; i < 272; i += 256)
            *(half8f*)(smem + H_OFF + i * 16) = *(const half8f*)(hsrc + i * 8);
    }
    {
        const f16* xsrc = xpad + ((size_t)((bi * 16 + t) * 66 + r0) * 68) * 4;
        for (int i = tid; i < 136; i += 256)
            *(half8f*)(smem + X_OFF + i * 16) = *(const half8f*)(xsrc + i * 8);
    }

    // weight fragments
    const half8f* WBv = (const half8f*)WB;
    half8f B00 = WBv[0*64+lane], B01 = WBv[1*64+lane];
    half8f B10 = WBv[2*64+lane], B11 = WBv[3*64+lane];
    half8f B20 = WBv[4*64+lane], B21 = WBv[5*64+lane];
    half8f B30 = WBv[6*64+lane], B31 = WBv[7*64+lane];

    // c prefetch (overlaps staging/barrier)
    const size_t gp0 = (size_t)(bi * 4096 + (r0 + pr) * 64 + wcol + p16);
    const size_t gp1 = gp0 + 16;
    float c0a = 0.f, c0b = 0.f, c1a = 0.f, c1b = 0.f;
    if (!first) {
        c0a = c_buf[gp0 * 8 + g4]; c0b = c_buf[gp0 * 8 + g4 + 4];
        c1a = c_buf[gp1 * 8 + g4]; c1b = c_buf[gp1 * 8 + g4 + 4];
    }

    __syncthreads();

    // tap->LDS offsets (68-pitch, byte-identical to validated r8 geometry)
    const int ty0 = (g4 >= 3) ? 1 : 0, tx0 = g4 - 3 * ty0;
    const int ty1 = 1 + ((g4 >= 2) ? 1 : 0), tx1 = (g4 + 4) - 3 * ty1;
    const int ty2 = (g4 == 3) ? 1 : 0, tx2 = (g4 == 2) ? 2 : 0;
    const int ty3 = (g4 == 0) ? 1 : 2, tx3 = (g4 == 1) ? 0 : 2;
    const int inc2 = (g4 == 0) ? 256 : 128;
    int o0 = H_OFF + ((pr + ty0) * 68 + wcol + p16 + tx0) * 16;
    int o1 = H_OFF + ((pr + ty1) * 68 + wcol + p16 + tx1) * 16;
    int o2 = (g4 == 0) ? H_OFF + ((pr + 2) * 68 + wcol + p16 + 2) * 16
                       : X_OFF + ((pr + ty2) * 68 + wcol + p16 + tx2) * 8;
    int o3 = X_OFF + ((pr + ty3) * 68 + wcol + p16 + tx3) * 8;

    float ha0 = 0.f, ha1 = 0.f, ha2 = 0.f, ha3 = 0.f;   // head partial acc

    #pragma unroll
    for (int tt = 0; tt < 2; ++tt) {
        half8f a0 = LDA(o0), a1 = LDA(o1), a2 = LDA(o2), a3 = LDA(o3);
        float ca = tt ? c1a : c0a, cb2 = tt ? c1b : c0b;
        float cc0, cc1, hh0, hh1;
        GATE_BODY(a0, a1, a2, a3, ca, cb2, cc0, cc1, hh0, hh1);
        const size_t gp = tt ? gp1 : gp0;
        c_buf[gp * 8 + g4]     = cc0;
        c_buf[gp * 8 + g4 + 4] = cc1;
        const size_t hb = ((size_t)(bi * 66 + r0 + pr + 1) * 68
                           + 1 + wcol + tt * 16 + p16) * 8;
        h_out[hb + g4]     = (f16)hh0;
        h_out[hb + g4 + 4] = (f16)hh1;
        if (do_head) {
            int pix = (r0 + pr) * 64 + wcol + tt * 16 + p16;
            floatx4 wa  = *(const floatx4*)(Wout + (size_t)(pix * 8 + g4) * 4);
            floatx4 wb2 = *(const floatx4*)(Wout + (size_t)(pix * 8 + g4 + 4) * 4);
            ha0 = fmaf(hh0, wa[0], fmaf(hh1, wb2[0], ha0));
            ha1 = fmaf(hh0, wa[1], fmaf(hh1, wb2[1], ha1));
            ha2 = fmaf(hh0, wa[2], fmaf(hh1, wb2[2], ha2));
            ha3 = fmaf(hh0, wa[3], fmaf(hh1, wb2[3], ha3));
        }
        o0 += 256; o1 += 256; o2 += inc2; o3 += 128;
    }

    if (do_head) {
        #pragma unroll
        for (int off = 32; off >= 1; off >>= 1) {
            ha0 += __shfl_down(ha0, off, 64);
            ha1 += __shfl_down(ha1, off, 64);
            ha2 += __shfl_down(ha2, off, 64);
            ha3 += __shfl_down(ha3, off, 64);
        }
        if (lane == 0) {
            floatx4 v = {ha0, ha1, ha2, ha3};
            *(floatx4*)(smem + RED_OFF + w * 16) = v;
        }
        __syncthreads();
        if (tid == 0) {
            floatx4 s = {0.f, 0.f, 0.f, 0.f};
            #pragma unroll
            for (int k = 0; k < 4; ++k)
                s += *(const floatx4*)(smem + RED_OFF + k * 16);
            *(floatx4*)(partial + (size_t)bid * 4) = s;
        }
    }
}

__global__ __launch_bounds__(64) void head_finish(
    const float* __restrict__ partial,  // (1024,4): bid = bi*32+strip
    const float* __restrict__ bout,
    float* __restrict__ out)
{
    int b = threadIdx.x;
    if (b >= NB) return;
    float l0 = bout[0], l1 = bout[1], l2 = bout[2], l3 = bout[3];
    for (int s = 0; s < 32; ++s) {
        floatx4 p = *(const floatx4*)(partial + (size_t)(b * 32 + s) * 4);
        l0 += p[0]; l1 += p[1]; l2 += p[2]; l3 += p[3];
    }
    float m = fmaxf(fmaxf(l0, l1), fmaxf(l2, l3));
    float e0 = expf(l0 - m), e1 = expf(l1 - m);
    float e2 = expf(l2 - m), e3 = expf(l3 - m);
    float inv = 1.0f / (e0 + e1 + e2 + e3);
    out[b * 4 + 0] = e0 * inv;
    out[b * 4 + 1] = e1 * inv;
    out[b * 4 + 2] = e2 * inv;
    out[b * 4 + 3] = e3 * inv;
}

// =================== fallback (r8-style, unpadded; ws < 26 MB) ===================
#define FB_XOFF 4352
#define FB_SMEM 6528

__global__ __launch_bounds__(256) void prepack_fb(
    const float* __restrict__ Wx, const float* __restrict__ Wh,
    const float* __restrict__ bias, f16* __restrict__ WB)
{
    int i = blockIdx.x * 256 + threadIdx.x;
    if (i < 4096) WB[i] = (f16)wb_entry(i, Wx, Wh, bias);
}

__global__ __launch_bounds__(256, 4) void convlstm_step_fb(
    const float* __restrict__ x, const f16* __restrict__ WB,
    const f16* __restrict__ h_in, f16* __restrict__ h_out,
    float* __restrict__ c_buf, int t, int first)
{
    __shared__ __attribute__((aligned(16))) char smem[FB_SMEM];

    const int bid = blockIdx.x;
    const int bi  = bid >> 5;
    const int r0  = (bid & 31) << 1;
    const int tid = threadIdx.x;
    const int w    = tid >> 6;
    const int lane = tid & 63;
    const int p16  = lane & 15;
    const int g4   = lane >> 4;
    const int pr   = w >> 1;
    const int wcol = (w & 1) << 5;

    const float* xt = x + (((size_t)bi * NT + t) * 4096) * 3;

    for (int i = tid; i < 272; i += 256) {
        int lr = i / 68, lc = i - lr * 68;
        int gr = r0 - 1 + lr, gc = lc - 1;
        bool ok = ((unsigned)gr < 64u) && ((unsigned)gc < 64u);
        half4f xv = {0, 0, 0, (f16)1.0f};
        half8f hv = {0, 0, 0, 0, 0, 0, 0, 0};
        if (ok) {
            const float* xp = xt + (gr * 64 + gc) * 3;
            xv[0] = (f16)xp[0]; xv[1] = (f16)xp[1]; xv[2] = (f16)xp[2];
            if (!first)
                hv = *(const half8f*)(h_in + ((size_t)(bi * 4096 + gr * 64 + gc)) * 8);
        }
        *(half8f*)(smem + i * 16) = hv;
        *(half4f*)(smem + FB_XOFF + i * 8) = xv;
    }

    const half8f* WBv = (const half8f*)WB;
    half8f B00 = WBv[0*64+lane], B01 = WBv[1*64+lane];
    half8f B10 = WBv[2*64+lane], B11 = WBv[3*64+lane];
    half8f B20 = WBv[4*64+lane], B21 = WBv[5*64+lane];
    half8f B30 = WBv[6*64+lane], B31 = WBv[7*64+lane];

    const size_t gp0 = (size_t)(bi * 4096 + (r0 + pr) * 64 + wcol + p16);
    const size_t gp1 = gp0 + 16;
    float c0a = 0.f, c0b = 0.f, c1a = 0.f, c1b = 0.f;
    if (!first) {
        c0a = c_buf[gp0 * 8 + g4]; c0b = c_buf[gp0 * 8 + g4 + 4];
        c1a = c_buf[gp1 * 8 + g4]; c1b = c_buf[gp1 * 8 + g4 + 4];
    }

    __syncthreads();

    const int ty0 = (g4 >= 3) ? 1 : 0, tx0 = g4 - 3 * ty0;
    const int ty1 = 1 + ((g4 >= 2) ? 1 : 0), tx1 = (g4 + 4) - 3 * ty1;
    const int ty2 = (g4 == 3) ? 1 : 0, tx2 = (g4 == 2) ? 2 : 0;
    const int ty3 = (g4 == 0) ? 1 : 2, tx3 = (g4 == 1) ? 0 : 2;
    const int inc2 = (g4 == 0) ? 256 : 128;
    int o0 = ((pr + ty0) * 68 + wcol + p16 + tx0) * 16;
    int o1 = ((pr + ty1) * 68 + wcol + p16 + tx1) * 16;
    int o2 = (g4 == 0) ? ((pr + 2) * 68 + wcol + p16 + 2) * 16
                       : FB_XOFF + ((pr + ty2) * 68 + wcol + p16 + tx2) * 8;
    int o3 = FB_XOFF + ((pr + ty3) * 68 + wcol + p16 + tx3) * 8;

    #pragma unroll
    for (int tt = 0; tt < 2; ++tt) {
        half8f a0 = LDA(o0), a1 = LDA(o1), a2 = LDA(o2), a3 = LDA(o3);
        float ca = tt ? c1a : c0a, cb2 = tt ? c1b : c0b;
        float cc0, cc1, hh0, hh1;
        GATE_BODY(a0, a1, a2, a3, ca, cb2, cc0, cc1, hh0, hh1);
        const size_t gp = tt ? gp1 : gp0;
        c_buf[gp * 8 + g4]     = cc0;
        c_buf[gp * 8 + g4 + 4] = cc1;
        h_out[gp * 8 + g4]     = (f16)hh0;
        h_out[gp * 8 + g4 + 4] = (f16)hh1;
        o0 += 256; o1 += 256; o2 += inc2; o3 += 128;
    }
}

__global__ __launch_bounds__(256) void head_partial_fb(
    const f16* __restrict__ h, const float* __restrict__ Wout,
    float* __restrict__ partial)
{
    const int b = blockIdx.x >> 4;
    const int chunk = blockIdx.x & 15;
    const int tid = threadIdx.x;
    const f16* hb = h + (size_t)b * 32768 + chunk * 2048;
    const float* wb = Wout + (size_t)(chunk * 2048) * 4;

    float acc[4] = {0.f, 0.f, 0.f, 0.f};
    #pragma unroll
    for (int it = 0; it < 8; ++it) {
        int i = it * 256 + tid;
        float hv = (float)hb[i];
        float4 wv = *(const float4*)(wb + (size_t)i * 4);
        acc[0] = fmaf(hv, wv.x, acc[0]);
        acc[1] = fmaf(hv, wv.y, acc[1]);
        acc[2] = fmaf(hv, wv.z, acc[2]);
        acc[3] = fmaf(hv, wv.w, acc[3]);
    }
    #pragma unroll
    for (int j = 0; j < 4; ++j)
        #pragma unroll
        for (int off = 32; off >= 1; off >>= 1)
            acc[j] += __shfl_down(acc[j], off, 64);

    __shared__ float red[4][4];
    int lane = tid & 63, wv2 = tid >> 6;
    if (lane == 0) {
        #pragma unroll
        for (int j = 0; j < 4; ++j) red[wv2][j] = acc[j];
    }
    __syncthreads();
    if (tid == 0) {
        #pragma unroll
        for (int j = 0; j < 4; ++j)
            partial[(size_t)blockIdx.x * 4 + j] =
                red[0][j] + red[1][j] + red[2][j] + red[3][j];
    }
}

__global__ __launch_bounds__(64) void head_finish_fb(
    const float* __restrict__ partial, const float* __restrict__ bout,
    float* __restrict__ out)
{
    int b = threadIdx.x;
    if (b >= NB) return;
    float logit[4] = {bout[0], bout[1], bout[2], bout[3]};
    #pragma unroll
    for (int k = 0; k < 16; ++k) {
        const float* p = partial + (size_t)(b * 16 + k) * 4;
        logit[0] += p[0]; logit[1] += p[1]; logit[2] += p[2]; logit[3] += p[3];
    }
    float m = fmaxf(fmaxf(logit[0], logit[1]), fmaxf(logit[2], logit[3]));
    float e[4], s = 0.f;
    #pragma unroll
    for (int j = 0; j < 4; ++j) { e[j] = expf(logit[j] - m); s += e[j]; }
    float inv = 1.0f / s;
    #pragma unroll
    for (int j = 0; j < 4; ++j) out[b * 4 + j] = e[j] * inv;
}

extern "C" void kernel_launch(void* const* d_in, const int* in_sizes, int n_in,
                              void* d_out, int out_size, void* d_ws, size_t ws_size,
                              hipStream_t stream) {
    const float* x    = (const float*)d_in[0];
    const float* Wx   = (const float*)d_in[1];
    const float* Wh   = (const float*)d_in[2];
    const float* b    = (const float*)d_in[3];
    const float* Wout = (const float*)d_in[4];
    const float* bout = (const float*)d_in[5];
    float* out = (float*)d_out;
    char* ws = (char*)d_ws;

    if (ws_size >= WS_NEED) {
        f16*   xpad  = (f16*)(ws + XPAD_OFF);
        f16*   h0    = (f16*)(ws + HPAD0_OFF);
        f16*   h1    = (f16*)(ws + HPAD1_OFF);
        float* cb    = (float*)(ws + CBUF_OFF);
        f16*   WBq   = (f16*)(ws + WBQ_OFF);
        float* part  = (float*)(ws + PART_OFF);

        xprep<<<dim3(19, 512), 256, 0, stream>>>(x, Wx, Wh, b, xpad, h0, h1, WBq);

        for (int t = 0; t < NT; ++t) {
            const f16* hin = (t & 1) ? h1 : h0;   // t=0 ignores hin (first)
            f16*       hout = (t & 1) ? h0 : h1;
            convlstm_step<<<1024, 256, 0, stream>>>(
                xpad, WBq, hin, hout, cb, Wout, part,
                t, (t == 0) ? 1 : 0, (t == NT - 1) ? 1 : 0);
        }
        head_finish<<<1, 64, 0, stream>>>(part, bout, out);
    } else {
        f16*   hA      = (f16*)ws;                    // 2 MB
        f16*   hB      = (f16*)(ws + (1u << 21));     // 2 MB
        float* cb      = (float*)(ws + (1u << 22));   // 4 MB
        f16*   WBq     = (f16*)(ws + (1u << 23));     // 8 KB
        float* partial = (float*)(ws + (1u << 23) + 8192);

        prepack_fb<<<16, 256, 0, stream>>>(Wx, Wh, b, WBq);
        for (int t = 0; t < NT; ++t) {
            const f16* hin = (t & 1) ? hA : hB;
            f16*       hout = (t & 1) ? hB : hA;
            convlstm_step_fb<<<1024, 256, 0, stream>>>(x, WBq, hin, hout, cb,
                                                       t, (t == 0) ? 1 : 0);
        }
        head_partial_fb<<<512, 256, 0, stream>>>(hB, Wout, partial);
        head_finish_fb<<<1, 64, 0, stream>>>(partial, bout, out);
    }
}

// Round 13
// 112.255 us; speedup vs baseline: 5.7670x; 1.2663x over previous
//
#include <hip/hip_runtime.h>
#include <math.h>

#define NB 32
#define NT 16

typedef _Float16 f16;
typedef _Float16 half2f __attribute__((ext_vector_type(2)));
typedef _Float16 half4f __attribute__((ext_vector_type(4)));
typedef _Float16 half8f __attribute__((ext_vector_type(8)));
typedef float    floatx2 __attribute__((ext_vector_type(2)));
typedef float    floatx4 __attribute__((ext_vector_type(4)));

// ---- workspace layout (bytes) ----
#define XPAD_OFF  0u                     // (512, 66*68, 4) f16 = 18,382,848
#define HPAD0_OFF 18382848u              // (32, 66, 68, 8) f16 = 2,297,856
#define HPAD1_OFF 20680704u
#define CBUF_OFF  22978560u              // (32, 64, 64, 8) f32 = 4,194,304
#define WBQ_OFF   27172864u              // 4096 f16 = 8192
#define PART_OFF  27181056u              // 1024 float4 = 16384
#define WS_NEED   27197440u

__device__ __forceinline__ float hard_sigmoid(float v) {
    return fminf(fmaxf(fmaf(0.2f, v, 0.5f), 0.0f), 1.0f);
}
__device__ __forceinline__ float fast_tanh(float v) {
    float e = __builtin_amdgcn_exp2f(v * 2.8853900817779268f);
    return 1.0f - 2.0f * __builtin_amdgcn_rcpf(e + 1.0f);
}

// Weight-fragment entry. Validated K-map (r7-r12). Gate order permuted so
// D-row r of acc_n = gate-type r of filter (2*g4 + n): lane owns ADJACENT
// filters 2g4, 2g4+1 -> vector half2f/floatx2 stores, shuffle-free epilogue.
__device__ __forceinline__ float wb_entry(int i, const float* Wx,
                                          const float* Wh, const float* bias) {
    int e = i & 7, l = (i >> 3) & 63, n = (i >> 9) & 1, j = i >> 10;
    int h = l >> 4;
    int rr = l & 15;
    int g = (rr & 3) * 8 + 2 * (rr >> 2) + n;   // gate-type*8 + filter(2*q + n)
    float wv = 0.f;
    if (j == 0) {
        wv = Wh[(h * 8 + e) * 32 + g];
    } else if (j == 1) {
        wv = Wh[((4 + h) * 8 + e) * 32 + g];
    } else if (j == 2 && h == 0) {
        wv = Wh[(64 + e) * 32 + g];
    } else if (j == 3 && h == 3) {
        wv = (e == 3) ? bias[g] : 0.f;          // bias rides const-1.0 x-ch3
    } else {
        int ty, txp;
        if (j == 2) { ty = (h == 3) ? 1 : 0; txp = (h == 2) ? 2 : 0; }
        else        { ty = (h == 0) ? 1 : 2; txp = (h == 1) ? 0 : 2; }
        int txq = txp + (e >> 2), c = e & 3;
        if (txq < 3 && c < 3)
            wv = Wx[((ty * 3 + txq) * 3 + c) * 32 + g];
    }
    return wv;
}

#define LDX(base, off) ({                                                  \
    half4f lo_ = *(const half4f*)((base) + (off));                         \
    half4f hi_ = *(const half4f*)((base) + (off) + 8);                     \
    __builtin_shufflevector(lo_, hi_, 0, 1, 2, 3, 4, 5, 6, 7); })

// 8 MFMA + gates. acc0 = [i,f,c,o] of filter 2g4, acc1 = filter 2g4+1.
#define GATE_BODY(A0, A1, A2, A3, COLD0, COLD1, CC0, CC1, HH0, HH1)        \
    {                                                                      \
        floatx4 acc0 = {0.f, 0.f, 0.f, 0.f};                               \
        floatx4 acc1 = {0.f, 0.f, 0.f, 0.f};                               \
        acc0 = __builtin_amdgcn_mfma_f32_16x16x32_f16(B00, A0, acc0,0,0,0);\
        acc1 = __builtin_amdgcn_mfma_f32_16x16x32_f16(B01, A0, acc1,0,0,0);\
        acc0 = __builtin_amdgcn_mfma_f32_16x16x32_f16(B10, A1, acc0,0,0,0);\
        acc1 = __builtin_amdgcn_mfma_f32_16x16x32_f16(B11, A1, acc1,0,0,0);\
        acc0 = __builtin_amdgcn_mfma_f32_16x16x32_f16(B20, A2, acc0,0,0,0);\
        acc1 = __builtin_amdgcn_mfma_f32_16x16x32_f16(B21, A2, acc1,0,0,0);\
        acc0 = __builtin_amdgcn_mfma_f32_16x16x32_f16(B30, A3, acc0,0,0,0);\
        acc1 = __builtin_amdgcn_mfma_f32_16x16x32_f16(B31, A3, acc1,0,0,0);\
        float ig0 = hard_sigmoid(acc0[0]), fg0 = hard_sigmoid(acc0[1]);    \
        float cg0 = fast_tanh(acc0[2]),    og0 = hard_sigmoid(acc0[3]);    \
        CC0 = fmaf(fg0, COLD0, ig0 * cg0);                                 \
        HH0 = og0 * fast_tanh(CC0);                                        \
        float ig1 = hard_sigmoid(acc1[0]), fg1 = hard_sigmoid(acc1[1]);    \
        float cg1 = fast_tanh(acc1[2]),    og1 = hard_sigmoid(acc1[3]);    \
        CC1 = fmaf(fg1, COLD1, ig1 * cg1);                                 \
        HH1 = og1 * fast_tanh(CC1);                                        \
    }

// ---- prep: x -> padded f16 (ch3=1); WB prepack; h-buffer border zeros ----
__global__ __launch_bounds__(256) void xprep(
    const float* __restrict__ x,
    const float* __restrict__ Wx, const float* __restrict__ Wh,
    const float* __restrict__ bias,
    f16* __restrict__ xpad, f16* __restrict__ hpad0, f16* __restrict__ hpad1,
    f16* __restrict__ WB)
{
    const int bt  = blockIdx.y;
    const int bx  = blockIdx.x;
    const int tid = threadIdx.x;
    if (bx < 18) {
        int i = bx * 256 + tid;
        if (i < 4488) {
            int rr = i / 68, cc = i - rr * 68;
            half4f v = {0, 0, 0, (f16)1.0f};
            if (rr >= 1 && rr < 65 && cc >= 1 && cc < 65) {
                const float* xp = x + ((size_t)bt * 4096 + (rr - 1) * 64 + (cc - 1)) * 3;
                v[0] = (f16)xp[0]; v[1] = (f16)xp[1]; v[2] = (f16)xp[2];
            }
            *(half4f*)(xpad + ((size_t)bt * 4488 + i) * 4) = v;
        }
    } else if (bt < 16) {
        WB[bt * 256 + tid] = (f16)wb_entry(bt * 256 + tid, Wx, Wh, bias);
    } else {
        int i2 = (bt - 16) * 256 + tid;          // border zeros: 2*32*392
        if (i2 < 25088) {
            int buf = i2 / 12544;
            int k = i2 - buf * 12544;
            int b = k / 392;
            int p = k - b * 392;
            int rr, cc;
            if (p < 136) { rr = (p < 68) ? 0 : 65; cc = p - ((p < 68) ? 0 : 68); }
            else { int q = p - 136; rr = 1 + (q >> 2); int m = q & 3;
                   cc = (m == 0) ? 0 : 64 + m; }
            f16* hp = buf ? hpad1 : hpad0;
            half8f zz = {0, 0, 0, 0, 0, 0, 0, 0};
            *(half8f*)(hp + ((size_t)(b * 66 + rr) * 68 + cc) * 8) = zz;
        }
    }
}

// ---- step kernel: ZERO LDS staging, ZERO barriers (except t=15 head) ----
// Every A-fragment is a direct aligned global load from the padded buffers.
__global__ __launch_bounds__(256, 4) void convlstm_step(
    const f16* __restrict__ xpad,    // (512, 66*68, 4)
    const f16* __restrict__ WB,
    const f16* __restrict__ h_in,    // padded (32,66,68,8)
    f16* __restrict__ h_out,         // padded
    float* __restrict__ c_buf,       // (32,64,64,8) f32
    const float* __restrict__ Wout,  // (32768,4)
    float* __restrict__ partial,     // (1024,4)
    int t, int first, int do_head)
{
    __shared__ floatx4 red[4];

    const int bid = blockIdx.x;
    const int bi  = bid >> 5;
    const int r0  = (bid & 31) << 1;
    const int tid = threadIdx.x;
    const int w    = tid >> 6;
    const int lane = tid & 63;
    const int p16  = lane & 15;
    const int g4   = lane >> 4;
    const int pr   = w >> 1;
    const int wcol = (w & 1) << 5;
    const int colb = wcol + p16;

    const char* hp = (const char*)(h_in + ((size_t)(bi * 66 + r0)) * 68 * 8);
    const char* xp = (const char*)(xpad + ((size_t)((bi * 16 + t) * 66 + r0)) * 68 * 4);

    // weight fragments
    const half8f* WBv = (const half8f*)WB;
    half8f B00 = WBv[0*64+lane], B01 = WBv[1*64+lane];
    half8f B10 = WBv[2*64+lane], B11 = WBv[3*64+lane];
    half8f B20 = WBv[4*64+lane], B21 = WBv[5*64+lane];
    half8f B30 = WBv[6*64+lane], B31 = WBv[7*64+lane];

    // c prefetch (adjacent filters 2g4, 2g4+1 -> vector loads/stores)
    const int f0 = g4 << 1;
    const size_t gp0 = (size_t)(bi * 4096 + (r0 + pr) * 64 + colb);
    const size_t gp1 = gp0 + 16;
    floatx2 cold0 = {0.f, 0.f}, cold1 = {0.f, 0.f};
    if (!first) {
        cold0 = *(const floatx2*)(c_buf + gp0 * 8 + f0);
        cold1 = *(const floatx2*)(c_buf + gp1 * 8 + f0);
    }

    // tap->byte offsets (identical arithmetic to validated LDS geometry)
    const int ty0 = (g4 >= 3) ? 1 : 0, tx0 = g4 - 3 * ty0;
    const int ty1 = 1 + ((g4 >= 2) ? 1 : 0), tx1 = (g4 + 4) - 3 * ty1;
    const int ty2 = (g4 == 3) ? 1 : 0, tx2 = (g4 == 2) ? 2 : 0;
    const int ty3 = (g4 == 0) ? 1 : 2, tx3 = (g4 == 1) ? 0 : 2;
    const int inc2 = (g4 == 0) ? 256 : 128;
    int o0  = ((pr + ty0) * 68 + colb + tx0) * 16;
    int o1  = ((pr + ty1) * 68 + colb + tx1) * 16;
    int o2h = ((pr + 2)   * 68 + colb + 2)   * 16;
    int o2x = ((pr + ty2) * 68 + colb + tx2) * 8;
    int o3  = ((pr + ty3) * 68 + colb + tx3) * 8;

    const half8f z8 = {0, 0, 0, 0, 0, 0, 0, 0};
    float ha0 = 0.f, ha1 = 0.f, ha2 = 0.f, ha3 = 0.f;

    #pragma unroll
    for (int tt = 0; tt < 2; ++tt) {
        half8f a0 = first ? z8 : *(const half8f*)(hp + o0);
        half8f a1 = first ? z8 : *(const half8f*)(hp + o1);
        half8f a2;
        if (g4 == 0) a2 = first ? z8 : *(const half8f*)(hp + o2h);
        else         a2 = LDX(xp, o2x);
        half8f a3 = LDX(xp, o3);

        floatx2 cold = tt ? cold1 : cold0;
        float cc0, cc1, hh0, hh1;
        GATE_BODY(a0, a1, a2, a3, cold[0], cold[1], cc0, cc1, hh0, hh1);

        if (!do_head) {
            const size_t gp = tt ? gp1 : gp0;
            floatx2 cw = {cc0, cc1};
            *(floatx2*)(c_buf + gp * 8 + f0) = cw;
            const size_t hb = ((size_t)(bi * 66 + r0 + pr + 1) * 68
                               + 1 + colb + tt * 16) * 8 + f0;
            half2f hw = {(f16)hh0, (f16)hh1};
            *(half2f*)(h_out + hb) = hw;
        } else {
            // t=15: h,c are dead; fold the head partial instead
            int pix = (r0 + pr) * 64 + colb + tt * 16;
            floatx4 wa  = *(const floatx4*)(Wout + (size_t)(pix * 8 + f0) * 4);
            floatx4 wb2 = *(const floatx4*)(Wout + (size_t)(pix * 8 + f0 + 1) * 4);
            ha0 = fmaf(hh0, wa[0], fmaf(hh1, wb2[0], ha0));
            ha1 = fmaf(hh0, wa[1], fmaf(hh1, wb2[1], ha1));
            ha2 = fmaf(hh0, wa[2], fmaf(hh1, wb2[2], ha2));
            ha3 = fmaf(hh0, wa[3], fmaf(hh1, wb2[3], ha3));
        }
        o0 += 256; o1 += 256; o2h += 256; o2x += 128; o3 += 128;
    }

    if (do_head) {
        #pragma unroll
        for (int off = 32; off >= 1; off >>= 1) {
            ha0 += __shfl_down(ha0, off, 64);
            ha1 += __shfl_down(ha1, off, 64);
            ha2 += __shfl_down(ha2, off, 64);
            ha3 += __shfl_down(ha3, off, 64);
        }
        if (lane == 0) {
            floatx4 v = {ha0, ha1, ha2, ha3};
            red[w] = v;
        }
        __syncthreads();
        if (tid == 0) {
            floatx4 s = red[0] + red[1] + red[2] + red[3];
            *(floatx4*)(partial + (size_t)bid * 4) = s;
        }
    }
}

__global__ __launch_bounds__(64) void head_finish(
    const float* __restrict__ partial,  // (1024,4): bid = bi*32+strip
    const float* __restrict__ bout,
    float* __restrict__ out)
{
    int b = threadIdx.x;
    if (b >= NB) return;
    float l0 = bout[0], l1 = bout[1], l2 = bout[2], l3 = bout[3];
    for (int s = 0; s < 32; ++s) {
        floatx4 p = *(const floatx4*)(partial + (size_t)(b * 32 + s) * 4);
        l0 += p[0]; l1 += p[1]; l2 += p[2]; l3 += p[3];
    }
    float m = fmaxf(fmaxf(l0, l1), fmaxf(l2, l3));
    float e0 = expf(l0 - m), e1 = expf(l1 - m);
    float e2 = expf(l2 - m), e3 = expf(l3 - m);
    float inv = 1.0f / (e0 + e1 + e2 + e3);
    out[b * 4 + 0] = e0 * inv;
    out[b * 4 + 1] = e1 * inv;
    out[b * 4 + 2] = e2 * inv;
    out[b * 4 + 3] = e3 * inv;
}

// =================== fallback (ws too small): r8-style LDS path ===================
#define FB_XOFF 4352
#define FB_SMEM 6528

__global__ __launch_bounds__(256) void prepack_fb(
    const float* __restrict__ Wx, const float* __restrict__ Wh,
    const float* __restrict__ bias, f16* __restrict__ WB)
{
    int i = blockIdx.x * 256 + threadIdx.x;
    if (i < 4096) WB[i] = (f16)wb_entry(i, Wx, Wh, bias);
}

#define LDAS(off) ({                                                       \
    half4f lo_ = *(const half4f*)(smem + (off));                           \
    half4f hi_ = *(const half4f*)(smem + (off) + 8);                       \
    __builtin_shufflevector(lo_, hi_, 0, 1, 2, 3, 4, 5, 6, 7); })

__global__ __launch_bounds__(256, 4) void convlstm_step_fb(
    const float* __restrict__ x, const f16* __restrict__ WB,
    const f16* __restrict__ h_in, f16* __restrict__ h_out,
    float* __restrict__ c_buf, int t, int first)
{
    __shared__ __attribute__((aligned(16))) char smem[FB_SMEM];

    const int bid = blockIdx.x;
    const int bi  = bid >> 5;
    const int r0  = (bid & 31) << 1;
    const int tid = threadIdx.x;
    const int w    = tid >> 6;
    const int lane = tid & 63;
    const int p16  = lane & 15;
    const int g4   = lane >> 4;
    const int pr   = w >> 1;
    const int wcol = (w & 1) << 5;

    const float* xt = x + (((size_t)bi * NT + t) * 4096) * 3;

    for (int i = tid; i < 272; i += 256) {
        int lr = i / 68, lc = i - lr * 68;
        int gr = r0 - 1 + lr, gc = lc - 1;
        bool ok = ((unsigned)gr < 64u) && ((unsigned)gc < 64u);
        half4f xv = {0, 0, 0, (f16)1.0f};
        half8f hv = {0, 0, 0, 0, 0, 0, 0, 0};
        if (ok) {
            const float* xp = xt + (gr * 64 + gc) * 3;
            xv[0] = (f16)xp[0]; xv[1] = (f16)xp[1]; xv[2] = (f16)xp[2];
            if (!first)
                hv = *(const half8f*)(h_in + ((size_t)(bi * 4096 + gr * 64 + gc)) * 8);
        }
        *(half8f*)(smem + i * 16) = hv;
        *(half4f*)(smem + FB_XOFF + i * 8) = xv;
    }

    const half8f* WBv = (const half8f*)WB;
    half8f B00 = WBv[0*64+lane], B01 = WBv[1*64+lane];
    half8f B10 = WBv[2*64+lane], B11 = WBv[3*64+lane];
    half8f B20 = WBv[4*64+lane], B21 = WBv[5*64+lane];
    half8f B30 = WBv[6*64+lane], B31 = WBv[7*64+lane];

    const int f0 = g4 << 1;
    const size_t gp0 = (size_t)(bi * 4096 + (r0 + pr) * 64 + wcol + p16);
    const size_t gp1 = gp0 + 16;
    floatx2 cold0 = {0.f, 0.f}, cold1 = {0.f, 0.f};
    if (!first) {
        cold0 = *(const floatx2*)(c_buf + gp0 * 8 + f0);
        cold1 = *(const floatx2*)(c_buf + gp1 * 8 + f0);
    }

    __syncthreads();

    const int ty0 = (g4 >= 3) ? 1 : 0, tx0 = g4 - 3 * ty0;
    const int ty1 = 1 + ((g4 >= 2) ? 1 : 0), tx1 = (g4 + 4) - 3 * ty1;
    const int ty2 = (g4 == 3) ? 1 : 0, tx2 = (g4 == 2) ? 2 : 0;
    const int ty3 = (g4 == 0) ? 1 : 2, tx3 = (g4 == 1) ? 0 : 2;
    const int inc2 = (g4 == 0) ? 256 : 128;
    int o0 = ((pr + ty0) * 68 + wcol + p16 + tx0) * 16;
    int o1 = ((pr + ty1) * 68 + wcol + p16 + tx1) * 16;
    int o2 = (g4 == 0) ? ((pr + 2) * 68 + wcol + p16 + 2) * 16
                       : FB_XOFF + ((pr + ty2) * 68 + wcol + p16 + tx2) * 8;
    int o3 = FB_XOFF + ((pr + ty3) * 68 + wcol + p16 + tx3) * 8;

    #pragma unroll
    for (int tt = 0; tt < 2; ++tt) {
        half8f a0 = LDAS(o0), a1 = LDAS(o1), a2 = LDAS(o2), a3 = LDAS(o3);
        floatx2 cold = tt ? cold1 : cold0;
        float cc0, cc1, hh0, hh1;
        GATE_BODY(a0, a1, a2, a3, cold[0], cold[1], cc0, cc1, hh0, hh1);
        const size_t gp = tt ? gp1 : gp0;
        floatx2 cw = {cc0, cc1};
        *(floatx2*)(c_buf + gp * 8 + f0) = cw;
        half2f hw = {(f16)hh0, (f16)hh1};
        *(half2f*)(h_out + gp * 8 + f0) = hw;
        o0 += 256; o1 += 256; o2 += inc2; o3 += 128;
    }
}

__global__ __launch_bounds__(256) void head_partial_fb(
    const f16* __restrict__ h, const float* __restrict__ Wout,
    float* __restrict__ partial)
{
    const int b = blockIdx.x >> 4;
    const int chunk = blockIdx.x & 15;
    const int tid = threadIdx.x;
    const f16* hb = h + (size_t)b * 32768 + chunk * 2048;
    const float* wb = Wout + (size_t)(chunk * 2048) * 4;

    float acc[4] = {0.f, 0.f, 0.f, 0.f};
    #pragma unroll
    for (int it = 0; it < 8; ++it) {
        int i = it * 256 + tid;
        float hv = (float)hb[i];
        float4 wv = *(const float4*)(wb + (size_t)i * 4);
        acc[0] = fmaf(hv, wv.x, acc[0]);
        acc[1] = fmaf(hv, wv.y, acc[1]);
        acc[2] = fmaf(hv, wv.z, acc[2]);
        acc[3] = fmaf(hv, wv.w, acc[3]);
    }
    #pragma unroll
    for (int j = 0; j < 4; ++j)
        #pragma unroll
        for (int off = 32; off >= 1; off >>= 1)
            acc[j] += __shfl_down(acc[j], off, 64);

    __shared__ float red2[4][4];
    int lane = tid & 63, wv2 = tid >> 6;
    if (lane == 0) {
        #pragma unroll
        for (int j = 0; j < 4; ++j) red2[wv2][j] = acc[j];
    }
    __syncthreads();
    if (tid == 0) {
        #pragma unroll
        for (int j = 0; j < 4; ++j)
            partial[(size_t)blockIdx.x * 4 + j] =
                red2[0][j] + red2[1][j] + red2[2][j] + red2[3][j];
    }
}

__global__ __launch_bounds__(64) void head_finish_fb(
    const float* __restrict__ partial, const float* __restrict__ bout,
    float* __restrict__ out)
{
    int b = threadIdx.x;
    if (b >= NB) return;
    float logit[4] = {bout[0], bout[1], bout[2], bout[3]};
    #pragma unroll
    for (int k = 0; k < 16; ++k) {
        const float* p = partial + (size_t)(b * 16 + k) * 4;
        logit[0] += p[0]; logit[1] += p[1]; logit[2] += p[2]; logit[3] += p[3];
    }
    float m = fmaxf(fmaxf(logit[0], logit[1]), fmaxf(logit[2], logit[3]));
    float e[4], s = 0.f;
    #pragma unroll
    for (int j = 0; j < 4; ++j) { e[j] = expf(logit[j] - m); s += e[j]; }
    float inv = 1.0f / s;
    #pragma unroll
    for (int j = 0; j < 4; ++j) out[b * 4 + j] = e[j] * inv;
}

extern "C" void kernel_launch(void* const* d_in, const int* in_sizes, int n_in,
                              void* d_out, int out_size, void* d_ws, size_t ws_size,
                              hipStream_t stream) {
    const float* x    = (const float*)d_in[0];
    const float* Wx   = (const float*)d_in[1];
    const float* Wh   = (const float*)d_in[2];
    const float* b    = (const float*)d_in[3];
    const float* Wout = (const float*)d_in[4];
    const float* bout = (const float*)d_in[5];
    float* out = (float*)d_out;
    char* ws = (char*)d_ws;

    if (ws_size >= WS_NEED) {
        f16*   xpad  = (f16*)(ws + XPAD_OFF);
        f16*   h0    = (f16*)(ws + HPAD0_OFF);
        f16*   h1    = (f16*)(ws + HPAD1_OFF);
        float* cb    = (float*)(ws + CBUF_OFF);
        f16*   WBq   = (f16*)(ws + WBQ_OFF);
        float* part  = (float*)(ws + PART_OFF);

        xprep<<<dim3(19, 512), 256, 0, stream>>>(x, Wx, Wh, b, xpad, h0, h1, WBq);

        for (int t = 0; t < NT; ++t) {
            const f16* hin = (t & 1) ? h1 : h0;   // t=0 ignores hin (first)
            f16*       hout = (t & 1) ? h0 : h1;
            convlstm_step<<<1024, 256, 0, stream>>>(
                xpad, WBq, hin, hout, cb, Wout, part,
                t, (t == 0) ? 1 : 0, (t == NT - 1) ? 1 : 0);
        }
        head_finish<<<1, 64, 0, stream>>>(part, bout, out);
    } else {
        f16*   hA      = (f16*)ws;                    // 2 MB
        f16*   hB      = (f16*)(ws + (1u << 21));     // 2 MB
        float* cb      = (float*)(ws + (1u << 22));   // 4 MB
        f16*   WBq     = (f16*)(ws + (1u << 23));     // 8 KB
        float* partial = (float*)(ws + (1u << 23) + 8192);

        prepack_fb<<<16, 256, 0, stream>>>(Wx, Wh, b, WBq);
        for (int t = 0; t < NT; ++t) {
            const f16* hin = (t & 1) ? hA : hB;
            f16*       hout = (t & 1) ? hB : hA;
            convlstm_step_fb<<<1024, 256, 0, stream>>>(x, WBq, hin, hout, cb,
                                                       t, (t == 0) ? 1 : 0);
        }
        head_partial_fb<<<512, 256, 0, stream>>>(hB, Wout, partial);
        head_finish_fb<<<1, 64, 0, stream>>>(partial, bout, out);
    }
}

// Round 14
// 106.173 us; speedup vs baseline: 6.0974x; 1.0573x over previous
//
#include <hip/hip_runtime.h>
#include <math.h>

#define NB 32
#define NT 16

typedef _Float16 f16;
typedef _Float16 half2f __attribute__((ext_vector_type(2)));
typedef _Float16 half4f __attribute__((ext_vector_type(4)));
typedef _Float16 half8f __attribute__((ext_vector_type(8)));
typedef float    floatx2 __attribute__((ext_vector_type(2)));
typedef float    floatx4 __attribute__((ext_vector_type(4)));

// ---- workspace layout (bytes) ----
#define XPAD_OFF  0u                     // (512, 66*68, 4) f16 = 18,382,848
#define HPAD0_OFF 18382848u              // (32, 66, 68, 8) f16 = 2,297,856
#define HPAD1_OFF 20680704u
#define CBUF_OFF  22978560u              // (32, 64, 64, 8) f32 = 4,194,304
#define WBQ_OFF   27172864u              // 4096 f16 = 8192
#define PART_OFF  27181056u              // 1024 float4 = 16384
#define WS_NEED   27197440u

// ---- fused-kernel LDS (bytes): band 4x68x16 = 4352; cLDS 2x64x8 f32 = 4096 ----
#define CLDS_OFF 4352
#define REDF_OFF 8448
#define FUSED_SMEM 8512

__device__ __forceinline__ float hard_sigmoid(float v) {
    return fminf(fmaxf(fmaf(0.2f, v, 0.5f), 0.0f), 1.0f);
}
__device__ __forceinline__ float fast_tanh(float v) {
    float e = __builtin_amdgcn_exp2f(v * 2.8853900817779268f);
    return 1.0f - 2.0f * __builtin_amdgcn_rcpf(e + 1.0f);
}

// Weight-fragment entry (validated r12/r13): lane owns adjacent filters
// 2g4, 2g4+1; acc rows = [i,f,c,o].
__device__ __forceinline__ float wb_entry(int i, const float* Wx,
                                          const float* Wh, const float* bias) {
    int e = i & 7, l = (i >> 3) & 63, n = (i >> 9) & 1, j = i >> 10;
    int h = l >> 4;
    int rr = l & 15;
    int g = (rr & 3) * 8 + 2 * (rr >> 2) + n;
    float wv = 0.f;
    if (j == 0) {
        wv = Wh[(h * 8 + e) * 32 + g];
    } else if (j == 1) {
        wv = Wh[((4 + h) * 8 + e) * 32 + g];
    } else if (j == 2 && h == 0) {
        wv = Wh[(64 + e) * 32 + g];
    } else if (j == 3 && h == 3) {
        wv = (e == 3) ? bias[g] : 0.f;
    } else {
        int ty, txp;
        if (j == 2) { ty = (h == 3) ? 1 : 0; txp = (h == 2) ? 2 : 0; }
        else        { ty = (h == 0) ? 1 : 2; txp = (h == 1) ? 0 : 2; }
        int txq = txp + (e >> 2), c = e & 3;
        if (txq < 3 && c < 3)
            wv = Wx[((ty * 3 + txq) * 3 + c) * 32 + g];
    }
    return wv;
}

#define LDX(base, off) ({                                                  \
    half4f lo_ = *(const half4f*)((base) + (off));                         \
    half4f hi_ = *(const half4f*)((base) + (off) + 8);                     \
    __builtin_shufflevector(lo_, hi_, 0, 1, 2, 3, 4, 5, 6, 7); })

#define GATE_BODY(A0, A1, A2, A3, COLD0, COLD1, CC0, CC1, HH0, HH1)        \
    {                                                                      \
        floatx4 acc0 = {0.f, 0.f, 0.f, 0.f};                               \
        floatx4 acc1 = {0.f, 0.f, 0.f, 0.f};                               \
        acc0 = __builtin_amdgcn_mfma_f32_16x16x32_f16(B00, A0, acc0,0,0,0);\
        acc1 = __builtin_amdgcn_mfma_f32_16x16x32_f16(B01, A0, acc1,0,0,0);\
        acc0 = __builtin_amdgcn_mfma_f32_16x16x32_f16(B10, A1, acc0,0,0,0);\
        acc1 = __builtin_amdgcn_mfma_f32_16x16x32_f16(B11, A1, acc1,0,0,0);\
        acc0 = __builtin_amdgcn_mfma_f32_16x16x32_f16(B20, A2, acc0,0,0,0);\
        acc1 = __builtin_amdgcn_mfma_f32_16x16x32_f16(B21, A2, acc1,0,0,0);\
        acc0 = __builtin_amdgcn_mfma_f32_16x16x32_f16(B30, A3, acc0,0,0,0);\
        acc1 = __builtin_amdgcn_mfma_f32_16x16x32_f16(B31, A3, acc1,0,0,0);\
        float ig0 = hard_sigmoid(acc0[0]), fg0 = hard_sigmoid(acc0[1]);    \
        float cg0 = fast_tanh(acc0[2]),    og0 = hard_sigmoid(acc0[3]);    \
        CC0 = fmaf(fg0, COLD0, ig0 * cg0);                                 \
        HH0 = og0 * fast_tanh(CC0);                                        \
        float ig1 = hard_sigmoid(acc1[0]), fg1 = hard_sigmoid(acc1[1]);    \
        float cg1 = fast_tanh(acc1[2]),    og1 = hard_sigmoid(acc1[3]);    \
        CC1 = fmaf(fg1, COLD1, ig1 * cg1);                                 \
        HH1 = og1 * fast_tanh(CC1);                                        \
    }

// ---- prep: x -> padded f16 (ch3=1); WB prepack; h-buffer border zeros ----
__global__ __launch_bounds__(256) void xprep(
    const float* __restrict__ x,
    const float* __restrict__ Wx, const float* __restrict__ Wh,
    const float* __restrict__ bias,
    f16* __restrict__ xpad, f16* __restrict__ hpad0, f16* __restrict__ hpad1,
    f16* __restrict__ WB)
{
    const int bt  = blockIdx.y;
    const int bx  = blockIdx.x;
    const int tid = threadIdx.x;
    if (bx < 18) {
        int i = bx * 256 + tid;
        if (i < 4488) {
            int rr = i / 68, cc = i - rr * 68;
            half4f v = {0, 0, 0, (f16)1.0f};
            if (rr >= 1 && rr < 65 && cc >= 1 && cc < 65) {
                const float* xp = x + ((size_t)bt * 4096 + (rr - 1) * 64 + (cc - 1)) * 3;
                v[0] = (f16)xp[0]; v[1] = (f16)xp[1]; v[2] = (f16)xp[2];
            }
            *(half4f*)(xpad + ((size_t)bt * 4488 + i) * 4) = v;
        }
    } else if (bt < 16) {
        WB[bt * 256 + tid] = (f16)wb_entry(bt * 256 + tid, Wx, Wh, bias);
    } else {
        int i2 = (bt - 16) * 256 + tid;          // border zeros: 2*32*392
        if (i2 < 25088) {
            int buf = i2 / 12544;
            int k = i2 - buf * 12544;
            int b = k / 392;
            int p = k - b * 392;
            int rr, cc;
            if (p < 136) { rr = (p < 68) ? 0 : 65; cc = p - ((p < 68) ? 0 : 68); }
            else { int q = p - 136; rr = 1 + (q >> 2); int m = q & 3;
                   cc = (m == 0) ? 0 : 64 + m; }
            f16* hp = buf ? hpad1 : hpad0;
            half8f zz = {0, 0, 0, 0, 0, 0, 0, 0};
            *(half8f*)(hp + ((size_t)(b * 66 + rr) * 68 + cc) * 8) = zz;
        }
    }
}

// ---- fused 2-step kernel: step A (band, 4 rows) -> LDS -> step B (2 rows) ----
// Block = 256 threads (4 waves). Step A: wave w computes band row rA=r0-1+w
// (4 col-tiles) at time t via direct global loads from padded h/x; writes h(t)
// to the LDS band and c(t) (own rows only) to cLDS. ONE barrier. Step B: the
// validated 68-pitch LDS geometry produces rows r0..r0+1 at t+1.
__global__ __launch_bounds__(256, 4) void convlstm_fused2(
    const f16* __restrict__ xpad,    // (512, 66*68, 4)
    const f16* __restrict__ WB,
    const f16* __restrict__ h_in,    // padded (32,66,68,8): h(t-1)
    f16* __restrict__ h_out,         // padded: h(t+1)
    float* __restrict__ c_buf,       // (32,64,64,8) f32: in c(t-1), out c(t+1)
    const float* __restrict__ Wout,  // (32768,4)
    float* __restrict__ partial,     // (1024,4)
    int t, int first, int do_head)
{
    __shared__ __attribute__((aligned(16))) char smem[FUSED_SMEM];

    const int bid = blockIdx.x;
    const int bi  = bid >> 5;
    const int r0  = (bid & 31) << 1;
    const int tid = threadIdx.x;
    const int w    = tid >> 6;
    const int lane = tid & 63;
    const int p16  = lane & 15;
    const int g4   = lane >> 4;
    const int pr   = w >> 1;
    const int wcol = (w & 1) << 5;
    const int f0   = g4 << 1;

    // weight fragments
    const half8f* WBv = (const half8f*)WB;
    half8f B00 = WBv[0*64+lane], B01 = WBv[1*64+lane];
    half8f B10 = WBv[2*64+lane], B11 = WBv[3*64+lane];
    half8f B20 = WBv[4*64+lane], B21 = WBv[5*64+lane];
    half8f B30 = WBv[6*64+lane], B31 = WBv[7*64+lane];

    // tap->offset tables (validated r7-r13)
    const int ty0 = (g4 >= 3) ? 1 : 0, tx0 = g4 - 3 * ty0;
    const int ty1 = 1 + ((g4 >= 2) ? 1 : 0), tx1 = (g4 + 4) - 3 * ty1;
    const int ty2 = (g4 == 3) ? 1 : 0, tx2 = (g4 == 2) ? 2 : 0;
    const int ty3 = (g4 == 0) ? 1 : 2, tx3 = (g4 == 1) ? 0 : 2;

    const int rA = r0 - 1 + w;
    const bool validA = ((unsigned)rA < 64u);
    const half8f z8 = {0, 0, 0, 0, 0, 0, 0, 0};

    // c(t-1) prefetch for step A's band row
    floatx2 cA0 = {0.f,0.f}, cA1 = {0.f,0.f}, cA2 = {0.f,0.f}, cA3 = {0.f,0.f};
    if (!first && validA) {
        const float* cbp = c_buf + ((size_t)(bi * 4096 + rA * 64)) * 8;
        cA0 = *(const floatx2*)(cbp + (p16)      * 8 + f0);
        cA1 = *(const floatx2*)(cbp + (16 + p16) * 8 + f0);
        cA2 = *(const floatx2*)(cbp + (32 + p16) * 8 + f0);
        cA3 = *(const floatx2*)(cbp + (48 + p16) * 8 + f0);
    }

    // per-wave band border zeros (cols 0,65,66,67 of own row) - no cross-wave race
    if (lane < 4) {
        int bc = (lane == 0) ? 0 : 64 + lane;
        *(half8f*)(smem + (w * 68 + bc) * 16) = z8;
    }

    // ======== STEP A: band row rA, 4 col-tiles ========
    {
        const char* hpA = (const char*)(h_in + ((size_t)(bi * 66 + rA)) * 68 * 8);
        const char* xpA = (const char*)(xpad + ((size_t)((bi * 16 + t) * 66 + rA)) * 68 * 4);
        int oh0 = (ty0 * 68 + p16 + tx0) * 16;
        int oh1 = (ty1 * 68 + p16 + tx1) * 16;
        int oh2 = (2   * 68 + p16 + 2)   * 16;
        int ox2 = (ty2 * 68 + p16 + tx2) * 8;
        int ox3 = (ty3 * 68 + p16 + tx3) * 8;

        #pragma unroll
        for (int tt = 0; tt < 4; ++tt) {
            const int colA = tt * 16 + p16;
            float cc0 = 0.f, cc1 = 0.f, hh0 = 0.f, hh1 = 0.f;
            if (validA) {
                half8f a0 = first ? z8 : *(const half8f*)(hpA + oh0);
                half8f a1 = first ? z8 : *(const half8f*)(hpA + oh1);
                half8f a2;
                if (g4 == 0) a2 = first ? z8 : *(const half8f*)(hpA + oh2);
                else         a2 = LDX(xpA, ox2);
                half8f a3 = LDX(xpA, ox3);
                floatx2 cold = (tt == 0) ? cA0 : (tt == 1) ? cA1
                             : (tt == 2) ? cA2 : cA3;
                GATE_BODY(a0, a1, a2, a3, cold[0], cold[1], cc0, cc1, hh0, hh1);
            }
            // h(t) -> band LDS (row w, col 1+colA)
            half2f hw = {(f16)hh0, (f16)hh1};
            *(half2f*)(smem + (w * 68 + 1 + colA) * 16 + f0 * 2) = hw;
            // c(t) -> cLDS for own output rows (w==1 -> r0, w==2 -> r0+1)
            if (w == 1 || w == 2) {
                floatx2 cw = {cc0, cc1};
                *(floatx2*)(smem + CLDS_OFF + (((w - 1) * 64 + colA) * 8 + f0) * 4) = cw;
            }
            oh0 += 256; oh1 += 256; oh2 += 256; ox2 += 128; ox3 += 128;
        }
    }

    __syncthreads();   // band + cLDS ready

    // ======== STEP B: rows r0+pr, col half wcol, 2 tiles, time t+1 ========
    {
        const char* xpB = (const char*)(xpad + ((size_t)((bi * 16 + t + 1) * 66 + r0)) * 68 * 4);
        const int colb = wcol + p16;
        int o0 = ((pr + ty0) * 68 + colb + tx0) * 16;
        int o1 = ((pr + ty1) * 68 + colb + tx1) * 16;
        int o2h = ((pr + 2)  * 68 + colb + 2)   * 16;
        int o2x = ((pr + ty2) * 68 + colb + tx2) * 8;
        int o3  = ((pr + ty3) * 68 + colb + tx3) * 8;

        float ha0 = 0.f, ha1 = 0.f, ha2 = 0.f, ha3 = 0.f;

        #pragma unroll
        for (int tt = 0; tt < 2; ++tt) {
            const int colB = wcol + tt * 16 + p16;
            half8f a0 = *(const half8f*)(smem + o0);
            half8f a1 = *(const half8f*)(smem + o1);
            half8f a2;
            if (g4 == 0) a2 = *(const half8f*)(smem + o2h);
            else         a2 = LDX(xpB, o2x);
            half8f a3 = LDX(xpB, o3);

            floatx2 cold = *(const floatx2*)(smem + CLDS_OFF +
                               ((pr * 64 + colB) * 8 + f0) * 4);
            float cc0, cc1, hh0, hh1;
            GATE_BODY(a0, a1, a2, a3, cold[0], cold[1], cc0, cc1, hh0, hh1);

            if (!do_head) {
                const size_t gp = (size_t)(bi * 4096 + (r0 + pr) * 64 + colB);
                floatx2 cw = {cc0, cc1};
                *(floatx2*)(c_buf + gp * 8 + f0) = cw;
                const size_t hb = ((size_t)(bi * 66 + r0 + pr + 1) * 68
                                   + 1 + colB) * 8 + f0;
                half2f hw = {(f16)hh0, (f16)hh1};
                *(half2f*)(h_out + hb) = hw;
            } else {
                int pix = (r0 + pr) * 64 + colB;
                floatx4 wa  = *(const floatx4*)(Wout + (size_t)(pix * 8 + f0) * 4);
                floatx4 wb2 = *(const floatx4*)(Wout + (size_t)(pix * 8 + f0 + 1) * 4);
                ha0 = fmaf(hh0, wa[0], fmaf(hh1, wb2[0], ha0));
                ha1 = fmaf(hh0, wa[1], fmaf(hh1, wb2[1], ha1));
                ha2 = fmaf(hh0, wa[2], fmaf(hh1, wb2[2], ha2));
                ha3 = fmaf(hh0, wa[3], fmaf(hh1, wb2[3], ha3));
            }
            o0 += 256; o1 += 256; o2h += 256; o2x += 128; o3 += 128;
        }

        if (do_head) {
            #pragma unroll
            for (int off = 32; off >= 1; off >>= 1) {
                ha0 += __shfl_down(ha0, off, 64);
                ha1 += __shfl_down(ha1, off, 64);
                ha2 += __shfl_down(ha2, off, 64);
                ha3 += __shfl_down(ha3, off, 64);
            }
            if (lane == 0) {
                floatx4 v = {ha0, ha1, ha2, ha3};
                *(floatx4*)(smem + REDF_OFF + w * 16) = v;
            }
            __syncthreads();
            if (tid == 0) {
                floatx4 s = *(const floatx4*)(smem + REDF_OFF)
                          + *(const floatx4*)(smem + REDF_OFF + 16)
                          + *(const floatx4*)(smem + REDF_OFF + 32)
                          + *(const floatx4*)(smem + REDF_OFF + 48);
                *(floatx4*)(partial + (size_t)bid * 4) = s;
            }
        }
    }
}

__global__ __launch_bounds__(64) void head_finish(
    const float* __restrict__ partial,  // (1024,4): bid = bi*32+strip
    const float* __restrict__ bout,
    float* __restrict__ out)
{
    int b = threadIdx.x;
    if (b >= NB) return;
    float l0 = bout[0], l1 = bout[1], l2 = bout[2], l3 = bout[3];
    for (int s = 0; s < 32; ++s) {
        floatx4 p = *(const floatx4*)(partial + (size_t)(b * 32 + s) * 4);
        l0 += p[0]; l1 += p[1]; l2 += p[2]; l3 += p[3];
    }
    float m = fmaxf(fmaxf(l0, l1), fmaxf(l2, l3));
    float e0 = expf(l0 - m), e1 = expf(l1 - m);
    float e2 = expf(l2 - m), e3 = expf(l3 - m);
    float inv = 1.0f / (e0 + e1 + e2 + e3);
    out[b * 4 + 0] = e0 * inv;
    out[b * 4 + 1] = e1 * inv;
    out[b * 4 + 2] = e2 * inv;
    out[b * 4 + 3] = e3 * inv;
}

// ========== fallback (ws too small): r13 direct-global per-step path ==========
__global__ __launch_bounds__(256) void prepack_fb(
    const float* __restrict__ Wx, const float* __restrict__ Wh,
    const float* __restrict__ bias, f16* __restrict__ WB)
{
    int i = blockIdx.x * 256 + threadIdx.x;
    if (i < 4096) WB[i] = (f16)wb_entry(i, Wx, Wh, bias);
}

#define FB_XOFF 4352
#define FB_SMEM 6528

#define LDAS(off) ({                                                       \
    half4f lo_ = *(const half4f*)(smem + (off));                           \
    half4f hi_ = *(const half4f*)(smem + (off) + 8);                       \
    __builtin_shufflevector(lo_, hi_, 0, 1, 2, 3, 4, 5, 6, 7); })

__global__ __launch_bounds__(256, 4) void convlstm_step_fb(
    const float* __restrict__ x, const f16* __restrict__ WB,
    const f16* __restrict__ h_in, f16* __restrict__ h_out,
    float* __restrict__ c_buf, int t, int first)
{
    __shared__ __attribute__((aligned(16))) char smem[FB_SMEM];

    const int bid = blockIdx.x;
    const int bi  = bid >> 5;
    const int r0  = (bid & 31) << 1;
    const int tid = threadIdx.x;
    const int w    = tid >> 6;
    const int lane = tid & 63;
    const int p16  = lane & 15;
    const int g4   = lane >> 4;
    const int pr   = w >> 1;
    const int wcol = (w & 1) << 5;

    const float* xt = x + (((size_t)bi * NT + t) * 4096) * 3;

    for (int i = tid; i < 272; i += 256) {
        int lr = i / 68, lc = i - lr * 68;
        int gr = r0 - 1 + lr, gc = lc - 1;
        bool ok = ((unsigned)gr < 64u) && ((unsigned)gc < 64u);
        half4f xv = {0, 0, 0, (f16)1.0f};
        half8f hv = {0, 0, 0, 0, 0, 0, 0, 0};
        if (ok) {
            const float* xp = xt + (gr * 64 + gc) * 3;
            xv[0] = (f16)xp[0]; xv[1] = (f16)xp[1]; xv[2] = (f16)xp[2];
            if (!first)
                hv = *(const half8f*)(h_in + ((size_t)(bi * 4096 + gr * 64 + gc)) * 8);
        }
        *(half8f*)(smem + i * 16) = hv;
        *(half4f*)(smem + FB_XOFF + i * 8) = xv;
    }

    const half8f* WBv = (const half8f*)WB;
    half8f B00 = WBv[0*64+lane], B01 = WBv[1*64+lane];
    half8f B10 = WBv[2*64+lane], B11 = WBv[3*64+lane];
    half8f B20 = WBv[4*64+lane], B21 = WBv[5*64+lane];
    half8f B30 = WBv[6*64+lane], B31 = WBv[7*64+lane];

    const int f0 = g4 << 1;
    const size_t gp0 = (size_t)(bi * 4096 + (r0 + pr) * 64 + wcol + p16);
    const size_t gp1 = gp0 + 16;
    floatx2 cold0 = {0.f, 0.f}, cold1 = {0.f, 0.f};
    if (!first) {
        cold0 = *(const floatx2*)(c_buf + gp0 * 8 + f0);
        cold1 = *(const floatx2*)(c_buf + gp1 * 8 + f0);
    }

    __syncthreads();

    const int ty0 = (g4 >= 3) ? 1 : 0, tx0 = g4 - 3 * ty0;
    const int ty1 = 1 + ((g4 >= 2) ? 1 : 0), tx1 = (g4 + 4) - 3 * ty1;
    const int ty2 = (g4 == 3) ? 1 : 0, tx2 = (g4 == 2) ? 2 : 0;
    const int ty3 = (g4 == 0) ? 1 : 2, tx3 = (g4 == 1) ? 0 : 2;
    const int inc2 = (g4 == 0) ? 256 : 128;
    int o0 = ((pr + ty0) * 68 + wcol + p16 + tx0) * 16;
    int o1 = ((pr + ty1) * 68 + wcol + p16 + tx1) * 16;
    int o2 = (g4 == 0) ? ((pr + 2) * 68 + wcol + p16 + 2) * 16
                       : FB_XOFF + ((pr + ty2) * 68 + wcol + p16 + tx2) * 8;
    int o3 = FB_XOFF + ((pr + ty3) * 68 + wcol + p16 + tx3) * 8;

    #pragma unroll
    for (int tt = 0; tt < 2; ++tt) {
        half8f a0 = LDAS(o0), a1 = LDAS(o1), a2 = LDAS(o2), a3 = LDAS(o3);
        floatx2 cold = tt ? cold1 : cold0;
        float cc0, cc1, hh0, hh1;
        GATE_BODY(a0, a1, a2, a3, cold[0], cold[1], cc0, cc1, hh0, hh1);
        const size_t gp = tt ? gp1 : gp0;
        floatx2 cw = {cc0, cc1};
        *(floatx2*)(c_buf + gp * 8 + f0) = cw;
        half2f hw = {(f16)hh0, (f16)hh1};
        *(half2f*)(h_out + gp * 8 + f0) = hw;
        o0 += 256; o1 += 256; o2 += inc2; o3 += 128;
    }
}

__global__ __launch_bounds__(256) void head_partial_fb(
    const f16* __restrict__ h, const float* __restrict__ Wout,
    float* __restrict__ partial)
{
    const int b = blockIdx.x >> 4;
    const int chunk = blockIdx.x & 15;
    const int tid = threadIdx.x;
    const f16* hb = h + (size_t)b * 32768 + chunk * 2048;
    const float* wb = Wout + (size_t)(chunk * 2048) * 4;

    float acc[4] = {0.f, 0.f, 0.f, 0.f};
    #pragma unroll
    for (int it = 0; it < 8; ++it) {
        int i = it * 256 + tid;
        float hv = (float)hb[i];
        float4 wv = *(const float4*)(wb + (size_t)i * 4);
        acc[0] = fmaf(hv, wv.x, acc[0]);
        acc[1] = fmaf(hv, wv.y, acc[1]);
        acc[2] = fmaf(hv, wv.z, acc[2]);
        acc[3] = fmaf(hv, wv.w, acc[3]);
    }
    #pragma unroll
    for (int j = 0; j < 4; ++j)
        #pragma unroll
        for (int off = 32; off >= 1; off >>= 1)
            acc[j] += __shfl_down(acc[j], off, 64);

    __shared__ float red2[4][4];
    int lane = tid & 63, wv2 = tid >> 6;
    if (lane == 0) {
        #pragma unroll
        for (int j = 0; j < 4; ++j) red2[wv2][j] = acc[j];
    }
    __syncthreads();
    if (tid == 0) {
        #pragma unroll
        for (int j = 0; j < 4; ++j)
            partial[(size_t)blockIdx.x * 4 + j] =
                red2[0][j] + red2[1][j] + red2[2][j] + red2[3][j];
    }
}

__global__ __launch_bounds__(64) void head_finish_fb(
    const float* __restrict__ partial, const float* __restrict__ bout,
    float* __restrict__ out)
{
    int b = threadIdx.x;
    if (b >= NB) return;
    float logit[4] = {bout[0], bout[1], bout[2], bout[3]};
    #pragma unroll
    for (int k = 0; k < 16; ++k) {
        const float* p = partial + (size_t)(b * 16 + k) * 4;
        logit[0] += p[0]; logit[1] += p[1]; logit[2] += p[2]; logit[3] += p[3];
    }
    float m = fmaxf(fmaxf(logit[0], logit[1]), fmaxf(logit[2], logit[3]));
    float e[4], s = 0.f;
    #pragma unroll
    for (int j = 0; j < 4; ++j) { e[j] = expf(logit[j] - m); s += e[j]; }
    float inv = 1.0f / s;
    #pragma unroll
    for (int j = 0; j < 4; ++j) out[b * 4 + j] = e[j] * inv;
}

extern "C" void kernel_launch(void* const* d_in, const int* in_sizes, int n_in,
                              void* d_out, int out_size, void* d_ws, size_t ws_size,
                              hipStream_t stream) {
    const float* x    = (const float*)d_in[0];
    const float* Wx   = (const float*)d_in[1];
    const float* Wh   = (const float*)d_in[2];
    const float* b    = (const float*)d_in[3];
    const float* Wout = (const float*)d_in[4];
    const float* bout = (const float*)d_in[5];
    float* out = (float*)d_out;
    char* ws = (char*)d_ws;

    if (ws_size >= WS_NEED) {
        f16*   xpad  = (f16*)(ws + XPAD_OFF);
        f16*   h0    = (f16*)(ws + HPAD0_OFF);
        f16*   h1    = (f16*)(ws + HPAD1_OFF);
        float* cb    = (float*)(ws + CBUF_OFF);
        f16*   WBq   = (f16*)(ws + WBQ_OFF);
        float* part  = (float*)(ws + PART_OFF);

        xprep<<<dim3(19, 512), 256, 0, stream>>>(x, Wx, Wh, b, xpad, h0, h1, WBq);

        // fused kernel k covers t = 2k, 2k+1. Reads h(2k-1), writes h(2k+1).
        for (int k = 0; k < 8; ++k) {
            const f16* hin  = (k & 1) ? h0 : h1;   // k=0: h1 (unused, first)
            f16*       hout = (k & 1) ? h1 : h0;   // k=0 writes h0; k=1 reads h0
            convlstm_fused2<<<1024, 256, 0, stream>>>(
                xpad, WBq, hin, hout, cb, Wout, part,
                2 * k, (k == 0) ? 1 : 0, (k == 7) ? 1 : 0);
        }
        head_finish<<<1, 64, 0, stream>>>(part, bout, out);
    } else {
        f16*   hA      = (f16*)ws;                    // 2 MB
        f16*   hB      = (f16*)(ws + (1u << 21));     // 2 MB
        float* cb      = (float*)(ws + (1u << 22));   // 4 MB
        f16*   WBq     = (f16*)(ws + (1u << 23));     // 8 KB
        float* partial = (float*)(ws + (1u << 23) + 8192);

        prepack_fb<<<16, 256, 0, stream>>>(Wx, Wh, b, WBq);
        for (int t = 0; t < NT; ++t) {
            const f16* hin = (t & 1) ? hA : hB;
            f16*       hout = (t & 1) ? hB : hA;
            convlstm_step_fb<<<1024, 256, 0, stream>>>(x, WBq, hin, hout, cb,
                                                       t, (t == 0) ? 1 : 0);
        }
        head_partial_fb<<<512, 256, 0, stream>>>(hB, Wout, partial);
        head_finish_fb<<<1, 64, 0, stream>>>(partial, bout, out);
    }
}

// Round 15
// 86.364 us; speedup vs baseline: 7.4959x; 1.2294x over previous
//
#include <hip/hip_runtime.h>
#include <math.h>

#define NB 32
#define NT 16

typedef _Float16 f16;
typedef _Float16 half2f __attribute__((ext_vector_type(2)));
typedef _Float16 half4f __attribute__((ext_vector_type(4)));
typedef _Float16 half8f __attribute__((ext_vector_type(8)));
typedef float    floatx2 __attribute__((ext_vector_type(2)));
typedef float    floatx4 __attribute__((ext_vector_type(4)));

// ---- workspace layout (bytes) ----
#define XPAD_OFF  0u                     // (512, 66*68, 4) f16 = 18,382,848
#define HPAD0_OFF 18382848u              // (32, 66, 68, 8) f16 = 2,297,856
#define HPAD1_OFF 20680704u
#define CBUF_OFF  22978560u              // (32, 64, 64, 8) f32 = 4,194,304
#define WBQ_OFF   27172864u              // 4096 f16 = 8192
#define PART_OFF  27181056u              // 512 float4 = 8192
#define WS_NEED   27197440u

// ---- fused-kernel LDS (bytes): band 6x68x16 = 6528; cLDS 4x64x8 f32 = 8192 ----
#define CLDS_OFF 6528
#define REDF_OFF 14720
#define FUSED_SMEM 14848

__device__ __forceinline__ float hard_sigmoid(float v) {
    return fminf(fmaxf(fmaf(0.2f, v, 0.5f), 0.0f), 1.0f);
}
__device__ __forceinline__ float fast_tanh(float v) {
    float e = __builtin_amdgcn_exp2f(v * 2.8853900817779268f);
    return 1.0f - 2.0f * __builtin_amdgcn_rcpf(e + 1.0f);
}

// Weight-fragment entry (validated r12-r14): lane owns adjacent filters
// 2g4, 2g4+1; acc rows = [i,f,c,o].
__device__ __forceinline__ float wb_entry(int i, const float* Wx,
                                          const float* Wh, const float* bias) {
    int e = i & 7, l = (i >> 3) & 63, n = (i >> 9) & 1, j = i >> 10;
    int h = l >> 4;
    int rr = l & 15;
    int g = (rr & 3) * 8 + 2 * (rr >> 2) + n;
    float wv = 0.f;
    if (j == 0) {
        wv = Wh[(h * 8 + e) * 32 + g];
    } else if (j == 1) {
        wv = Wh[((4 + h) * 8 + e) * 32 + g];
    } else if (j == 2 && h == 0) {
        wv = Wh[(64 + e) * 32 + g];
    } else if (j == 3 && h == 3) {
        wv = (e == 3) ? bias[g] : 0.f;
    } else {
        int ty, txp;
        if (j == 2) { ty = (h == 3) ? 1 : 0; txp = (h == 2) ? 2 : 0; }
        else        { ty = (h == 0) ? 1 : 2; txp = (h == 1) ? 0 : 2; }
        int txq = txp + (e >> 2), c = e & 3;
        if (txq < 3 && c < 3)
            wv = Wx[((ty * 3 + txq) * 3 + c) * 32 + g];
    }
    return wv;
}

#define LDX(base, off) ({                                                  \
    half4f lo_ = *(const half4f*)((base) + (off));                         \
    half4f hi_ = *(const half4f*)((base) + (off) + 8);                     \
    __builtin_shufflevector(lo_, hi_, 0, 1, 2, 3, 4, 5, 6, 7); })

#define GATE_BODY(A0, A1, A2, A3, COLD0, COLD1, CC0, CC1, HH0, HH1)        \
    {                                                                      \
        floatx4 acc0 = {0.f, 0.f, 0.f, 0.f};                               \
        floatx4 acc1 = {0.f, 0.f, 0.f, 0.f};                               \
        acc0 = __builtin_amdgcn_mfma_f32_16x16x32_f16(B00, A0, acc0,0,0,0);\
        acc1 = __builtin_amdgcn_mfma_f32_16x16x32_f16(B01, A0, acc1,0,0,0);\
        acc0 = __builtin_amdgcn_mfma_f32_16x16x32_f16(B10, A1, acc0,0,0,0);\
        acc1 = __builtin_amdgcn_mfma_f32_16x16x32_f16(B11, A1, acc1,0,0,0);\
        acc0 = __builtin_amdgcn_mfma_f32_16x16x32_f16(B20, A2, acc0,0,0,0);\
        acc1 = __builtin_amdgcn_mfma_f32_16x16x32_f16(B21, A2, acc1,0,0,0);\
        acc0 = __builtin_amdgcn_mfma_f32_16x16x32_f16(B30, A3, acc0,0,0,0);\
        acc1 = __builtin_amdgcn_mfma_f32_16x16x32_f16(B31, A3, acc1,0,0,0);\
        float ig0 = hard_sigmoid(acc0[0]), fg0 = hard_sigmoid(acc0[1]);    \
        float cg0 = fast_tanh(acc0[2]),    og0 = hard_sigmoid(acc0[3]);    \
        CC0 = fmaf(fg0, COLD0, ig0 * cg0);                                 \
        HH0 = og0 * fast_tanh(CC0);                                        \
        float ig1 = hard_sigmoid(acc1[0]), fg1 = hard_sigmoid(acc1[1]);    \
        float cg1 = fast_tanh(acc1[2]),    og1 = hard_sigmoid(acc1[3]);    \
        CC1 = fmaf(fg1, COLD1, ig1 * cg1);                                 \
        HH1 = og1 * fast_tanh(CC1);                                        \
    }

// ---- init: xpad borders (all 512 images) + h borders + WB + x slices 0,1 ----
__global__ __launch_bounds__(256) void init_all(
    const float* __restrict__ x,
    const float* __restrict__ Wx, const float* __restrict__ Wh,
    const float* __restrict__ bias,
    f16* __restrict__ xpad, f16* __restrict__ h0, f16* __restrict__ h1,
    f16* __restrict__ WB)
{
    int i = blockIdx.x * 256 + threadIdx.x;
    if (i < 200704) {                      // xpad borders: 512 x 392
        int bt = i / 392, p = i - bt * 392;
        int rr, cc;
        if (p < 136) { rr = (p < 68) ? 0 : 65; cc = p - ((p < 68) ? 0 : 68); }
        else { int q = p - 136; rr = 1 + (q >> 2); int m = q & 3;
               cc = (m == 0) ? 0 : 64 + m; }
        half4f v = {0, 0, 0, (f16)1.0f};
        *(half4f*)(xpad + ((size_t)(bt * 66 + rr) * 68 + cc) * 4) = v;
    } else if (i < 225792) {               // h borders: 2 x 32 x 392
        int k = i - 200704;
        int buf = k / 12544; k -= buf * 12544;
        int b = k / 392, p = k - b * 392;
        int rr, cc;
        if (p < 136) { rr = (p < 68) ? 0 : 65; cc = p - ((p < 68) ? 0 : 68); }
        else { int q = p - 136; rr = 1 + (q >> 2); int m = q & 3;
               cc = (m == 0) ? 0 : 64 + m; }
        f16* hp = buf ? h1 : h0;
        half8f zz = {0, 0, 0, 0, 0, 0, 0, 0};
        *(half8f*)(hp + ((size_t)(b * 66 + rr) * 68 + cc) * 8) = zz;
    } else if (i < 229888) {               // WB: 4096
        int k = i - 225792;
        WB[k] = (f16)wb_entry(k, Wx, Wh, bias);
    } else if (i < 492032) {               // x slices 0,1: 32 x 2 x 4096
        int j = i - 229888;
        int b = j >> 13;
        int rem = j & 8191;
        int s = rem >> 12, px = rem & 4095;
        const float* xp = x + ((size_t)(b * 16 + s) * 4096 + px) * 3;
        half4f v = {(f16)xp[0], (f16)xp[1], (f16)xp[2], (f16)1.0f};
        int gr = px >> 6, gc = px & 63;
        *(half4f*)(xpad + ((size_t)((b * 16 + s) * 66 + gr + 1) * 68 + gc + 1) * 4) = v;
    }
}

// ---- fused 2-step, R=4 strips: step A (6-row band) -> LDS -> step B (4 rows).
// Block = 512 threads (8 waves). Grid = 32 x 16 = 512. Also converts x slices
// t+2, t+3 for the NEXT kernel (kernel-boundary makes the halo safe).
__global__ __launch_bounds__(512, 4) void convlstm_fused2(
    const float* __restrict__ x,     // raw input (for next-slice conversion)
    f16* __restrict__ xpad,          // (512, 66*68, 4)
    const f16* __restrict__ WB,
    const f16* __restrict__ h_in,    // padded (32,66,68,8): h(t-1)
    f16* __restrict__ h_out,         // padded: h(t+1)
    float* __restrict__ c_buf,       // (32,64,64,8) f32: in c(t-1), out c(t+1)
    const float* __restrict__ Wout,  // (32768,4)
    float* __restrict__ partial,     // (512,4)
    int t, int first, int do_head)
{
    __shared__ __attribute__((aligned(16))) char smem[FUSED_SMEM];

    const int bid = blockIdx.x;
    const int bi  = bid >> 4;
    const int r0  = (bid & 15) << 2;
    const int tid = threadIdx.x;
    const int w    = __builtin_amdgcn_readfirstlane(tid >> 6);  // 0..7
    const int lane = tid & 63;
    const int p16  = lane & 15;
    const int g4   = lane >> 4;
    const int f0   = g4 << 1;

    // weight fragments
    const half8f* WBv = (const half8f*)WB;
    half8f B00 = WBv[0*64+lane], B01 = WBv[1*64+lane];
    half8f B10 = WBv[2*64+lane], B11 = WBv[3*64+lane];
    half8f B20 = WBv[4*64+lane], B21 = WBv[5*64+lane];
    half8f B30 = WBv[6*64+lane], B31 = WBv[7*64+lane];

    // tap->offset tables (validated r7-r14)
    const int ty0 = (g4 >= 3) ? 1 : 0, tx0 = g4 - 3 * ty0;
    const int ty1 = 1 + ((g4 >= 2) ? 1 : 0), tx1 = (g4 + 4) - 3 * ty1;
    const int ty2 = (g4 == 3) ? 1 : 0, tx2 = (g4 == 2) ? 2 : 0;
    const int ty3 = (g4 == 0) ? 1 : 2, tx3 = (g4 == 1) ? 0 : 2;

    const half8f z8 = {0, 0, 0, 0, 0, 0, 0, 0};

    // band border zeros (cols 0,65,66,67 of all 6 rows)
    if (tid < 24) {
        int row = tid >> 2, b = tid & 3;
        int col = (b == 0) ? 0 : 64 + b;
        *(half8f*)(smem + (row * 68 + col) * 16) = z8;
    }

    // ======== STEP A: 24 tiles over 6 band rows x 4 col-tiles; 3 per wave ====
    #pragma unroll
    for (int k = 0; k < 3; ++k) {
        const int tau = w * 3 + k;
        const int row = tau >> 2, ct = tau & 3;
        const int rA  = r0 - 1 + row;
        const bool vA = ((unsigned)rA < 64u);
        const int colA = ct * 16 + p16;

        float cc0 = 0.f, cc1 = 0.f, hh0 = 0.f, hh1 = 0.f;
        if (vA) {
            floatx2 cold = {0.f, 0.f};
            if (!first)
                cold = *(const floatx2*)(c_buf +
                           ((size_t)(bi * 4096 + rA * 64 + colA)) * 8 + f0);
            const char* hpA = (const char*)(h_in + ((size_t)(bi * 66 + rA)) * 68 * 8);
            const char* xpA = (const char*)(xpad + ((size_t)((bi * 16 + t) * 66 + rA)) * 68 * 4);
            half8f a0 = first ? z8 : *(const half8f*)(hpA + (ty0 * 68 + colA + tx0) * 16);
            half8f a1 = first ? z8 : *(const half8f*)(hpA + (ty1 * 68 + colA + tx1) * 16);
            half8f a2;
            if (g4 == 0) a2 = first ? z8 : *(const half8f*)(hpA + (2 * 68 + colA + 2) * 16);
            else         a2 = LDX(xpA, (ty2 * 68 + colA + tx2) * 8);
            half8f a3 = LDX(xpA, (ty3 * 68 + colA + tx3) * 8);
            GATE_BODY(a0, a1, a2, a3, cold[0], cold[1], cc0, cc1, hh0, hh1);
        }
        half2f hw = {(f16)hh0, (f16)hh1};
        *(half2f*)(smem + (row * 68 + 1 + colA) * 16 + f0 * 2) = hw;
        if (row >= 1 && row <= 4) {
            floatx2 cw = {cc0, cc1};
            *(floatx2*)(smem + CLDS_OFF + (((row - 1) * 64 + colA) * 8 + f0) * 4) = cw;
        }
    }

    __syncthreads();   // band h(t) + cLDS c(t) ready

    // ======== STEP B: 4 rows x 64 cols at t+1; wave w -> row r0+(w>>1) ======
    {
        const int pr   = w >> 1;            // 0..3
        const int wcol = (w & 1) << 5;
        const char* xpB = (const char*)(xpad + ((size_t)((bi * 16 + t + 1) * 66 + r0)) * 68 * 4);
        const int colb = wcol + p16;
        int o0  = ((pr + ty0) * 68 + colb + tx0) * 16;
        int o1  = ((pr + ty1) * 68 + colb + tx1) * 16;
        int o2h = ((pr + 2)   * 68 + colb + 2)   * 16;
        int o2x = ((pr + ty2) * 68 + colb + tx2) * 8;
        int o3  = ((pr + ty3) * 68 + colb + tx3) * 8;

        float ha0 = 0.f, ha1 = 0.f, ha2 = 0.f, ha3 = 0.f;

        #pragma unroll
        for (int tt = 0; tt < 2; ++tt) {
            const int colB = wcol + tt * 16 + p16;
            half8f a0 = *(const half8f*)(smem + o0);
            half8f a1 = *(const half8f*)(smem + o1);
            half8f a2;
            if (g4 == 0) a2 = *(const half8f*)(smem + o2h);
            else         a2 = LDX(xpB, o2x);
            half8f a3 = LDX(xpB, o3);

            floatx2 cold = *(const floatx2*)(smem + CLDS_OFF +
                               ((pr * 64 + colB) * 8 + f0) * 4);
            float cc0, cc1, hh0, hh1;
            GATE_BODY(a0, a1, a2, a3, cold[0], cold[1], cc0, cc1, hh0, hh1);

            if (!do_head) {
                const size_t gp = (size_t)(bi * 4096 + (r0 + pr) * 64 + colB);
                floatx2 cw = {cc0, cc1};
                *(floatx2*)(c_buf + gp * 8 + f0) = cw;
                const size_t hb = ((size_t)(bi * 66 + r0 + pr + 1) * 68
                                   + 1 + colB) * 8 + f0;
                half2f hw = {(f16)hh0, (f16)hh1};
                *(half2f*)(h_out + hb) = hw;
            } else {
                int pix = (r0 + pr) * 64 + colB;
                floatx4 wa  = *(const floatx4*)(Wout + (size_t)(pix * 8 + f0) * 4);
                floatx4 wb2 = *(const floatx4*)(Wout + (size_t)(pix * 8 + f0 + 1) * 4);
                ha0 = fmaf(hh0, wa[0], fmaf(hh1, wb2[0], ha0));
                ha1 = fmaf(hh0, wa[1], fmaf(hh1, wb2[1], ha1));
                ha2 = fmaf(hh0, wa[2], fmaf(hh1, wb2[2], ha2));
                ha3 = fmaf(hh0, wa[3], fmaf(hh1, wb2[3], ha3));
            }
            o0 += 256; o1 += 256; o2h += 256; o2x += 128; o3 += 128;
        }

        if (do_head) {
            #pragma unroll
            for (int off = 32; off >= 1; off >>= 1) {
                ha0 += __shfl_down(ha0, off, 64);
                ha1 += __shfl_down(ha1, off, 64);
                ha2 += __shfl_down(ha2, off, 64);
                ha3 += __shfl_down(ha3, off, 64);
            }
            if (lane == 0) {
                floatx4 v = {ha0, ha1, ha2, ha3};
                *(floatx4*)(smem + REDF_OFF + w * 16) = v;
            }
            __syncthreads();
            if (tid == 0) {
                floatx4 s = {0.f, 0.f, 0.f, 0.f};
                #pragma unroll
                for (int k = 0; k < 8; ++k)
                    s += *(const floatx4*)(smem + REDF_OFF + k * 16);
                *(floatx4*)(partial + (size_t)bid * 4) = s;
            }
        }
    }

    // ---- convert x slices t+2, t+3 (own 4 rows) for the NEXT kernel ----
    {
        int slice = t + 2 + (tid >> 8);      // tid<256 -> t+2, else t+3
        if (slice < NT) {
            int px = tid & 255;
            int gr = r0 + (px >> 6), gc = px & 63;
            const float* xp = x + ((size_t)(bi * NT + slice) * 4096 + gr * 64 + gc) * 3;
            half4f v = {(f16)xp[0], (f16)xp[1], (f16)xp[2], (f16)1.0f};
            *(half4f*)(xpad + ((size_t)((bi * 16 + slice) * 66 + gr + 1) * 68 + gc + 1) * 4) = v;
        }
    }
}

__global__ __launch_bounds__(64) void head_finish(
    const float* __restrict__ partial,  // (512,4): bid = bi*16+strip
    const float* __restrict__ bout,
    float* __restrict__ out)
{
    int b = threadIdx.x;
    if (b >= NB) return;
    float l0 = bout[0], l1 = bout[1], l2 = bout[2], l3 = bout[3];
    for (int s = 0; s < 16; ++s) {
        floatx4 p = *(const floatx4*)(partial + (size_t)(b * 16 + s) * 4);
        l0 += p[0]; l1 += p[1]; l2 += p[2]; l3 += p[3];
    }
    float m = fmaxf(fmaxf(l0, l1), fmaxf(l2, l3));
    float e0 = expf(l0 - m), e1 = expf(l1 - m);
    float e2 = expf(l2 - m), e3 = expf(l3 - m);
    float inv = 1.0f / (e0 + e1 + e2 + e3);
    out[b * 4 + 0] = e0 * inv;
    out[b * 4 + 1] = e1 * inv;
    out[b * 4 + 2] = e2 * inv;
    out[b * 4 + 3] = e3 * inv;
}

// ========== fallback (ws too small): r8-style LDS per-step path ==========
__global__ __launch_bounds__(256) void prepack_fb(
    const float* __restrict__ Wx, const float* __restrict__ Wh,
    const float* __restrict__ bias, f16* __restrict__ WB)
{
    int i = blockIdx.x * 256 + threadIdx.x;
    if (i < 4096) WB[i] = (f16)wb_entry(i, Wx, Wh, bias);
}

#define FB_XOFF 4352
#define FB_SMEM 6528

#define LDAS(off) ({                                                       \
    half4f lo_ = *(const half4f*)(smem + (off));                           \
    half4f hi_ = *(const half4f*)(smem + (off) + 8);                       \
    __builtin_shufflevector(lo_, hi_, 0, 1, 2, 3, 4, 5, 6, 7); })

__global__ __launch_bounds__(256, 4) void convlstm_step_fb(
    const float* __restrict__ x, const f16* __restrict__ WB,
    const f16* __restrict__ h_in, f16* __restrict__ h_out,
    float* __restrict__ c_buf, int t, int first)
{
    __shared__ __attribute__((aligned(16))) char smem[FB_SMEM];

    const int bid = blockIdx.x;
    const int bi  = bid >> 5;
    const int r0  = (bid & 31) << 1;
    const int tid = threadIdx.x;
    const int w    = tid >> 6;
    const int lane = tid & 63;
    const int p16  = lane & 15;
    const int g4   = lane >> 4;
    const int pr   = w >> 1;
    const int wcol = (w & 1) << 5;

    const float* xt = x + (((size_t)bi * NT + t) * 4096) * 3;

    for (int i = tid; i < 272; i += 256) {
        int lr = i / 68, lc = i - lr * 68;
        int gr = r0 - 1 + lr, gc = lc - 1;
        bool ok = ((unsigned)gr < 64u) && ((unsigned)gc < 64u);
        half4f xv = {0, 0, 0, (f16)1.0f};
        half8f hv = {0, 0, 0, 0, 0, 0, 0, 0};
        if (ok) {
            const float* xp = xt + (gr * 64 + gc) * 3;
            xv[0] = (f16)xp[0]; xv[1] = (f16)xp[1]; xv[2] = (f16)xp[2];
            if (!first)
                hv = *(const half8f*)(h_in + ((size_t)(bi * 4096 + gr * 64 + gc)) * 8);
        }
        *(half8f*)(smem + i * 16) = hv;
        *(half4f*)(smem + FB_XOFF + i * 8) = xv;
    }

    const half8f* WBv = (const half8f*)WB;
    half8f B00 = WBv[0*64+lane], B01 = WBv[1*64+lane];
    half8f B10 = WBv[2*64+lane], B11 = WBv[3*64+lane];
    half8f B20 = WBv[4*64+lane], B21 = WBv[5*64+lane];
    half8f B30 = WBv[6*64+lane], B31 = WBv[7*64+lane];

    const int f0 = g4 << 1;
    const size_t gp0 = (size_t)(bi * 4096 + (r0 + pr) * 64 + wcol + p16);
    const size_t gp1 = gp0 + 16;
    floatx2 cold0 = {0.f, 0.f}, cold1 = {0.f, 0.f};
    if (!first) {
        cold0 = *(const floatx2*)(c_buf + gp0 * 8 + f0);
        cold1 = *(const floatx2*)(c_buf + gp1 * 8 + f0);
    }

    __syncthreads();

    const int ty0 = (g4 >= 3) ? 1 : 0, tx0 = g4 - 3 * ty0;
    const int ty1 = 1 + ((g4 >= 2) ? 1 : 0), tx1 = (g4 + 4) - 3 * ty1;
    const int ty2 = (g4 == 3) ? 1 : 0, tx2 = (g4 == 2) ? 2 : 0;
    const int ty3 = (g4 == 0) ? 1 : 2, tx3 = (g4 == 1) ? 0 : 2;
    const int inc2 = (g4 == 0) ? 256 : 128;
    int o0 = ((pr + ty0) * 68 + wcol + p16 + tx0) * 16;
    int o1 = ((pr + ty1) * 68 + wcol + p16 + tx1) * 16;
    int o2 = (g4 == 0) ? ((pr + 2) * 68 + wcol + p16 + 2) * 16
                       : FB_XOFF + ((pr + ty2) * 68 + wcol + p16 + tx2) * 8;
    int o3 = FB_XOFF + ((pr + ty3) * 68 + wcol + p16 + tx3) * 8;

    #pragma unroll
    for (int tt = 0; tt < 2; ++tt) {
        half8f a0 = LDAS(o0), a1 = LDAS(o1), a2 = LDAS(o2), a3 = LDAS(o3);
        floatx2 cold = tt ? cold1 : cold0;
        float cc0, cc1, hh0, hh1;
        GATE_BODY(a0, a1, a2, a3, cold[0], cold[1], cc0, cc1, hh0, hh1);
        const size_t gp = tt ? gp1 : gp0;
        floatx2 cw = {cc0, cc1};
        *(floatx2*)(c_buf + gp * 8 + f0) = cw;
        half2f hw = {(f16)hh0, (f16)hh1};
        *(half2f*)(h_out + gp * 8 + f0) = hw;
        o0 += 256; o1 += 256; o2 += inc2; o3 += 128;
    }
}

__global__ __launch_bounds__(256) void head_partial_fb(
    const f16* __restrict__ h, const float* __restrict__ Wout,
    float* __restrict__ partial)
{
    const int b = blockIdx.x >> 4;
    const int chunk = blockIdx.x & 15;
    const int tid = threadIdx.x;
    const f16* hb = h + (size_t)b * 32768 + chunk * 2048;
    const float* wb = Wout + (size_t)(chunk * 2048) * 4;

    float acc[4] = {0.f, 0.f, 0.f, 0.f};
    #pragma unroll
    for (int it = 0; it < 8; ++it) {
        int i = it * 256 + tid;
        float hv = (float)hb[i];
        float4 wv = *(const float4*)(wb + (size_t)i * 4);
        acc[0] = fmaf(hv, wv.x, acc[0]);
        acc[1] = fmaf(hv, wv.y, acc[1]);
        acc[2] = fmaf(hv, wv.z, acc[2]);
        acc[3] = fmaf(hv, wv.w, acc[3]);
    }
    #pragma unroll
    for (int j = 0; j < 4; ++j)
        #pragma unroll
        for (int off = 32; off >= 1; off >>= 1)
            acc[j] += __shfl_down(acc[j], off, 64);

    __shared__ float red2[4][4];
    int lane = tid & 63, wv2 = tid >> 6;
    if (lane == 0) {
        #pragma unroll
        for (int j = 0; j < 4; ++j) red2[wv2][j] = acc[j];
    }
    __syncthreads();
    if (tid == 0) {
        #pragma unroll
        for (int j = 0; j < 4; ++j)
            partial[(size_t)blockIdx.x * 4 + j] =
                red2[0][j] + red2[1][j] + red2[2][j] + red2[3][j];
    }
}

__global__ __launch_bounds__(64) void head_finish_fb(
    const float* __restrict__ partial, const float* __restrict__ bout,
    float* __restrict__ out)
{
    int b = threadIdx.x;
    if (b >= NB) return;
    float logit[4] = {bout[0], bout[1], bout[2], bout[3]};
    #pragma unroll
    for (int k = 0; k < 16; ++k) {
        const float* p = partial + (size_t)(b * 16 + k) * 4;
        logit[0] += p[0]; logit[1] += p[1]; logit[2] += p[2]; logit[3] += p[3];
    }
    float m = fmaxf(fmaxf(logit[0], logit[1]), fmaxf(logit[2], logit[3]));
    float e[4], s = 0.f;
    #pragma unroll
    for (int j = 0; j < 4; ++j) { e[j] = expf(logit[j] - m); s += e[j]; }
    float inv = 1.0f / s;
    #pragma unroll
    for (int j = 0; j < 4; ++j) out[b * 4 + j] = e[j] * inv;
}

extern "C" void kernel_launch(void* const* d_in, const int* in_sizes, int n_in,
                              void* d_out, int out_size, void* d_ws, size_t ws_size,
                              hipStream_t stream) {
    const float* x    = (const float*)d_in[0];
    const float* Wx   = (const float*)d_in[1];
    const float* Wh   = (const float*)d_in[2];
    const float* b    = (const float*)d_in[3];
    const float* Wout = (const float*)d_in[4];
    const float* bout = (const float*)d_in[5];
    float* out = (float*)d_out;
    char* ws = (char*)d_ws;

    if (ws_size >= WS_NEED) {
        f16*   xpad  = (f16*)(ws + XPAD_OFF);
        f16*   h0    = (f16*)(ws + HPAD0_OFF);
        f16*   h1    = (f16*)(ws + HPAD1_OFF);
        float* cb    = (float*)(ws + CBUF_OFF);
        f16*   WBq   = (f16*)(ws + WBQ_OFF);
        float* part  = (float*)(ws + PART_OFF);

        init_all<<<1922, 256, 0, stream>>>(x, Wx, Wh, b, xpad, h0, h1, WBq);

        // fused kernel k covers t = 2k, 2k+1; converts x slices 2k+2, 2k+3.
        for (int k = 0; k < 8; ++k) {
            const f16* hin  = (k & 1) ? h0 : h1;   // k=0: h1 (unused, first)
            f16*       hout = (k & 1) ? h1 : h0;
            convlstm_fused2<<<512, 512, 0, stream>>>(
                x, xpad, WBq, hin, hout, cb, Wout, part,
                2 * k, (k == 0) ? 1 : 0, (k == 7) ? 1 : 0);
        }
        head_finish<<<1, 64, 0, stream>>>(part, bout, out);
    } else {
        f16*   hA      = (f16*)ws;                    // 2 MB
        f16*   hB      = (f16*)(ws + (1u << 21));     // 2 MB
        float* cb      = (float*)(ws + (1u << 22));   // 4 MB
        f16*   WBq     = (f16*)(ws + (1u << 23));     // 8 KB
        float* partial = (float*)(ws + (1u << 23) + 8192);

        prepack_fb<<<16, 256, 0, stream>>>(Wx, Wh, b, WBq);
        for (int t = 0; t < NT; ++t) {
            const f16* hin = (t & 1) ? hA : hB;
            f16*       hout = (t & 1) ? hB : hA;
            convlstm_step_fb<<<1024, 256, 0, stream>>>(x, WBq, hin, hout, cb,
                                                       t, (t == 0) ? 1 : 0);
        }
        head_partial_fb<<<512, 256, 0, stream>>>(hB, Wout, partial);
        head_finish_fb<<<1, 64, 0, stream>>>(partial, bout, out);
    }
}

// Round 16
// 77.921 us; speedup vs baseline: 8.3082x; 1.1084x over previous
//
#include <hip/hip_runtime.h>
#include <math.h>

#define NB 32
#define NT 16

typedef _Float16 f16;
typedef _Float16 half2f __attribute__((ext_vector_type(2)));
typedef _Float16 half4f __attribute__((ext_vector_type(4)));
typedef _Float16 half8f __attribute__((ext_vector_type(8)));
typedef float    floatx2 __attribute__((ext_vector_type(2)));
typedef float    floatx4 __attribute__((ext_vector_type(4)));

// ---- workspace layout (bytes) ----
#define XPAD_OFF  0u                     // (512, 66*68, 4) f16 = 18,382,848
#define HPAD0_OFF 18382848u              // (32, 66, 68, 8) f16 = 2,297,856
#define HPAD1_OFF 20680704u
#define CBUF_OFF  22978560u              // (32, 64, 64, 8) f32 = 4,194,304
#define WBQ_OFF   27172864u              // 4096 f16 = 8192
#define PART_OFF  27181056u              // 512 float4 = 8192
#define WS_NEED   27197440u

// ---- fused-kernel LDS (bytes): band 6x68x16 = 6528; cLDS 4x64x8 f32 = 8192 ----
#define CLDS_OFF 6528
#define REDF_OFF 14720
#define FUSED_SMEM 14848

__device__ __forceinline__ float hard_sigmoid(float v) {
    return fminf(fmaxf(fmaf(0.2f, v, 0.5f), 0.0f), 1.0f);
}
__device__ __forceinline__ float fast_tanh(float v) {
    float e = __builtin_amdgcn_exp2f(v * 2.8853900817779268f);
    return 1.0f - 2.0f * __builtin_amdgcn_rcpf(e + 1.0f);
}

// Weight-fragment entry (validated r12-r15): lane owns adjacent filters
// 2g4, 2g4+1; acc rows = [i,f,c,o].
__device__ __forceinline__ float wb_entry(int i, const float* Wx,
                                          const float* Wh, const float* bias) {
    int e = i & 7, l = (i >> 3) & 63, n = (i >> 9) & 1, j = i >> 10;
    int h = l >> 4;
    int rr = l & 15;
    int g = (rr & 3) * 8 + 2 * (rr >> 2) + n;
    float wv = 0.f;
    if (j == 0) {
        wv = Wh[(h * 8 + e) * 32 + g];
    } else if (j == 1) {
        wv = Wh[((4 + h) * 8 + e) * 32 + g];
    } else if (j == 2 && h == 0) {
        wv = Wh[(64 + e) * 32 + g];
    } else if (j == 3 && h == 3) {
        wv = (e == 3) ? bias[g] : 0.f;
    } else {
        int ty, txp;
        if (j == 2) { ty = (h == 3) ? 1 : 0; txp = (h == 2) ? 2 : 0; }
        else        { ty = (h == 0) ? 1 : 2; txp = (h == 1) ? 0 : 2; }
        int txq = txp + (e >> 2), c = e & 3;
        if (txq < 3 && c < 3)
            wv = Wx[((ty * 3 + txq) * 3 + c) * 32 + g];
    }
    return wv;
}

#define LDX(base, off) ({                                                  \
    half4f lo_ = *(const half4f*)((base) + (off));                         \
    half4f hi_ = *(const half4f*)((base) + (off) + 8);                     \
    __builtin_shufflevector(lo_, hi_, 0, 1, 2, 3, 4, 5, 6, 7); })

#define GATE_BODY(A0, A1, A2, A3, COLD0, COLD1, CC0, CC1, HH0, HH1)        \
    {                                                                      \
        floatx4 acc0 = {0.f, 0.f, 0.f, 0.f};                               \
        floatx4 acc1 = {0.f, 0.f, 0.f, 0.f};                               \
        acc0 = __builtin_amdgcn_mfma_f32_16x16x32_f16(B00, A0, acc0,0,0,0);\
        acc1 = __builtin_amdgcn_mfma_f32_16x16x32_f16(B01, A0, acc1,0,0,0);\
        acc0 = __builtin_amdgcn_mfma_f32_16x16x32_f16(B10, A1, acc0,0,0,0);\
        acc1 = __builtin_amdgcn_mfma_f32_16x16x32_f16(B11, A1, acc1,0,0,0);\
        acc0 = __builtin_amdgcn_mfma_f32_16x16x32_f16(B20, A2, acc0,0,0,0);\
        acc1 = __builtin_amdgcn_mfma_f32_16x16x32_f16(B21, A2, acc1,0,0,0);\
        acc0 = __builtin_amdgcn_mfma_f32_16x16x32_f16(B30, A3, acc0,0,0,0);\
        acc1 = __builtin_amdgcn_mfma_f32_16x16x32_f16(B31, A3, acc1,0,0,0);\
        float ig0 = hard_sigmoid(acc0[0]), fg0 = hard_sigmoid(acc0[1]);    \
        float cg0 = fast_tanh(acc0[2]),    og0 = hard_sigmoid(acc0[3]);    \
        CC0 = fmaf(fg0, COLD0, ig0 * cg0);                                 \
        HH0 = og0 * fast_tanh(CC0);                                        \
        float ig1 = hard_sigmoid(acc1[0]), fg1 = hard_sigmoid(acc1[1]);    \
        float cg1 = fast_tanh(acc1[2]),    og1 = hard_sigmoid(acc1[3]);    \
        CC1 = fmaf(fg1, COLD1, ig1 * cg1);                                 \
        HH1 = og1 * fast_tanh(CC1);                                        \
    }

// ---- init: xpad borders (all 512 images) + h borders + WB + x slices 0,1 ----
__global__ __launch_bounds__(256) void init_all(
    const float* __restrict__ x,
    const float* __restrict__ Wx, const float* __restrict__ Wh,
    const float* __restrict__ bias,
    f16* __restrict__ xpad, f16* __restrict__ h0, f16* __restrict__ h1,
    f16* __restrict__ WB)
{
    int i = blockIdx.x * 256 + threadIdx.x;
    if (i < 200704) {                      // xpad borders: 512 x 392
        int bt = i / 392, p = i - bt * 392;
        int rr, cc;
        if (p < 136) { rr = (p < 68) ? 0 : 65; cc = p - ((p < 68) ? 0 : 68); }
        else { int q = p - 136; rr = 1 + (q >> 2); int m = q & 3;
               cc = (m == 0) ? 0 : 64 + m; }
        half4f v = {0, 0, 0, (f16)1.0f};
        *(half4f*)(xpad + ((size_t)(bt * 66 + rr) * 68 + cc) * 4) = v;
    } else if (i < 225792) {               // h borders: 2 x 32 x 392
        int k = i - 200704;
        int buf = k / 12544; k -= buf * 12544;
        int b = k / 392, p = k - b * 392;
        int rr, cc;
        if (p < 136) { rr = (p < 68) ? 0 : 65; cc = p - ((p < 68) ? 0 : 68); }
        else { int q = p - 136; rr = 1 + (q >> 2); int m = q & 3;
               cc = (m == 0) ? 0 : 64 + m; }
        f16* hp = buf ? h1 : h0;
        half8f zz = {0, 0, 0, 0, 0, 0, 0, 0};
        *(half8f*)(hp + ((size_t)(b * 66 + rr) * 68 + cc) * 8) = zz;
    } else if (i < 229888) {               // WB: 4096
        int k = i - 225792;
        WB[k] = (f16)wb_entry(k, Wx, Wh, bias);
    } else if (i < 492032) {               // x slices 0,1: 32 x 2 x 4096
        int j = i - 229888;
        int b = j >> 13;
        int rem = j & 8191;
        int s = rem >> 12, px = rem & 4095;
        const float* xp = x + ((size_t)(b * 16 + s) * 4096 + px) * 3;
        half4f v = {(f16)xp[0], (f16)xp[1], (f16)xp[2], (f16)1.0f};
        int gr = px >> 6, gc = px & 63;
        *(half4f*)(xpad + ((size_t)((b * 16 + s) * 66 + gr + 1) * 68 + gc + 1) * 4) = v;
    }
}

// ---- fused 2-step, R=4 strips (r15 structure) + three latency levers:
//  (1) XCD-contiguous bid swizzle: each XCD owns 4 whole batches -> h-halo
//      reads hit the local L2.
//  (2) step-B x-operand loads issued BEFORE the barrier (compiler cannot
//      hoist loads across __syncthreads).
//  (3) x-convert source loads issued at kernel start; stores at the end.
__global__ __launch_bounds__(512, 4) void convlstm_fused2(
    const float* __restrict__ x,     // raw input (for next-slice conversion)
    f16* __restrict__ xpad,          // (512, 66*68, 4)
    const f16* __restrict__ WB,
    const f16* __restrict__ h_in,    // padded (32,66,68,8): h(t-1)
    f16* __restrict__ h_out,         // padded: h(t+1)
    float* __restrict__ c_buf,       // (32,64,64,8) f32: in c(t-1), out c(t+1)
    const float* __restrict__ Wout,  // (32768,4)
    float* __restrict__ partial,     // (512,4)
    int t, int first, int do_head)
{
    __shared__ __attribute__((aligned(16))) char smem[FUSED_SMEM];

    // (1) bijective XCD swizzle: hw%8 = XCD -> logical chunk of 64 blocks
    const int bid0 = blockIdx.x;
    const int bid  = ((bid0 & 7) << 6) | (bid0 >> 3);
    const int bi  = bid >> 4;
    const int r0  = (bid & 15) << 2;
    const int tid = threadIdx.x;
    const int w    = __builtin_amdgcn_readfirstlane(tid >> 6);  // 0..7
    const int lane = tid & 63;
    const int p16  = lane & 15;
    const int g4   = lane >> 4;
    const int f0   = g4 << 1;

    // (3) early x-convert source loads (slices t+2 / t+3), fully independent
    const int cslice = t + 2 + (tid >> 8);      // tid<256 -> t+2, else t+3
    const bool cvalid = (cslice < NT);
    const int cpx = tid & 255;
    const int cgr = r0 + (cpx >> 6), cgc = cpx & 63;
    const float* cxp = x + ((size_t)(bi * NT + (cvalid ? cslice : 0)) * 4096
                            + cgr * 64 + cgc) * 3;
    const float cx0 = cxp[0], cx1 = cxp[1], cx2 = cxp[2];

    // weight fragments
    const half8f* WBv = (const half8f*)WB;
    half8f B00 = WBv[0*64+lane], B01 = WBv[1*64+lane];
    half8f B10 = WBv[2*64+lane], B11 = WBv[3*64+lane];
    half8f B20 = WBv[4*64+lane], B21 = WBv[5*64+lane];
    half8f B30 = WBv[6*64+lane], B31 = WBv[7*64+lane];

    // tap->offset tables (validated r7-r15)
    const int ty0 = (g4 >= 3) ? 1 : 0, tx0 = g4 - 3 * ty0;
    const int ty1 = 1 + ((g4 >= 2) ? 1 : 0), tx1 = (g4 + 4) - 3 * ty1;
    const int ty2 = (g4 == 3) ? 1 : 0, tx2 = (g4 == 2) ? 2 : 0;
    const int ty3 = (g4 == 0) ? 1 : 2, tx3 = (g4 == 1) ? 0 : 2;

    const half8f z8 = {0, 0, 0, 0, 0, 0, 0, 0};

    // (2) early step-B x-operand loads (slice t+1): independent of this
    // kernel's LDS and stores; ready when the barrier exits.
    const int prB  = w >> 1;            // 0..3
    const int wcolB = (w & 1) << 5;
    const int colbB = wcolB + p16;
    const char* xpB = (const char*)(xpad +
        ((size_t)((bi * 16 + t + 1) * 66 + r0)) * 68 * 4);
    const int o2xB = ((prB + ty2) * 68 + colbB + tx2) * 8;
    const int o3B  = ((prB + ty3) * 68 + colbB + tx3) * 8;
    half8f xbA2_0 = LDX(xpB, o2xB);
    half8f xbA3_0 = LDX(xpB, o3B);
    half8f xbA2_1 = LDX(xpB, o2xB + 128);
    half8f xbA3_1 = LDX(xpB, o3B + 128);

    // band border zeros (cols 0,65,66,67 of all 6 rows)
    if (tid < 24) {
        int row = tid >> 2, b = tid & 3;
        int col = (b == 0) ? 0 : 64 + b;
        *(half8f*)(smem + (row * 68 + col) * 16) = z8;
    }

    // ======== STEP A: 24 tiles over 6 band rows x 4 col-tiles; 3 per wave ====
    #pragma unroll
    for (int k = 0; k < 3; ++k) {
        const int tau = w * 3 + k;
        const int row = tau >> 2, ct = tau & 3;
        const int rA  = r0 - 1 + row;
        const bool vA = ((unsigned)rA < 64u);
        const int colA = ct * 16 + p16;

        float cc0 = 0.f, cc1 = 0.f, hh0 = 0.f, hh1 = 0.f;
        if (vA) {
            floatx2 cold = {0.f, 0.f};
            if (!first)
                cold = *(const floatx2*)(c_buf +
                           ((size_t)(bi * 4096 + rA * 64 + colA)) * 8 + f0);
            const char* hpA = (const char*)(h_in + ((size_t)(bi * 66 + rA)) * 68 * 8);
            const char* xpA = (const char*)(xpad + ((size_t)((bi * 16 + t) * 66 + rA)) * 68 * 4);
            half8f a0 = first ? z8 : *(const half8f*)(hpA + (ty0 * 68 + colA + tx0) * 16);
            half8f a1 = first ? z8 : *(const half8f*)(hpA + (ty1 * 68 + colA + tx1) * 16);
            half8f a2;
            if (g4 == 0) a2 = first ? z8 : *(const half8f*)(hpA + (2 * 68 + colA + 2) * 16);
            else         a2 = LDX(xpA, (ty2 * 68 + colA + tx2) * 8);
            half8f a3 = LDX(xpA, (ty3 * 68 + colA + tx3) * 8);
            GATE_BODY(a0, a1, a2, a3, cold[0], cold[1], cc0, cc1, hh0, hh1);
        }
        half2f hw = {(f16)hh0, (f16)hh1};
        *(half2f*)(smem + (row * 68 + 1 + colA) * 16 + f0 * 2) = hw;
        if (row >= 1 && row <= 4) {
            floatx2 cw = {cc0, cc1};
            *(floatx2*)(smem + CLDS_OFF + (((row - 1) * 64 + colA) * 8 + f0) * 4) = cw;
        }
    }

    __syncthreads();   // band h(t) + cLDS c(t) ready

    // ======== STEP B: 4 rows x 64 cols at t+1; wave w -> row r0+(w>>1) ======
    {
        int o0  = ((prB + ty0) * 68 + colbB + tx0) * 16;
        int o1  = ((prB + ty1) * 68 + colbB + tx1) * 16;
        int o2h = ((prB + 2)   * 68 + colbB + 2)   * 16;

        float ha0 = 0.f, ha1 = 0.f, ha2 = 0.f, ha3 = 0.f;

        #pragma unroll
        for (int tt = 0; tt < 2; ++tt) {
            const int colB = wcolB + tt * 16 + p16;
            half8f a0 = *(const half8f*)(smem + o0);
            half8f a1 = *(const half8f*)(smem + o1);
            half8f a2;
            if (g4 == 0) a2 = *(const half8f*)(smem + o2h);
            else         a2 = tt ? xbA2_1 : xbA2_0;
            half8f a3 = tt ? xbA3_1 : xbA3_0;

            floatx2 cold = *(const floatx2*)(smem + CLDS_OFF +
                               ((prB * 64 + colB) * 8 + f0) * 4);
            float cc0, cc1, hh0, hh1;
            GATE_BODY(a0, a1, a2, a3, cold[0], cold[1], cc0, cc1, hh0, hh1);

            if (!do_head) {
                const size_t gp = (size_t)(bi * 4096 + (r0 + prB) * 64 + colB);
                floatx2 cw = {cc0, cc1};
                *(floatx2*)(c_buf + gp * 8 + f0) = cw;
                const size_t hb = ((size_t)(bi * 66 + r0 + prB + 1) * 68
                                   + 1 + colB) * 8 + f0;
                half2f hw = {(f16)hh0, (f16)hh1};
                *(half2f*)(h_out + hb) = hw;
            } else {
                int pix = (r0 + prB) * 64 + colB;
                floatx4 wa  = *(const floatx4*)(Wout + (size_t)(pix * 8 + f0) * 4);
                floatx4 wb2 = *(const floatx4*)(Wout + (size_t)(pix * 8 + f0 + 1) * 4);
                ha0 = fmaf(hh0, wa[0], fmaf(hh1, wb2[0], ha0));
                ha1 = fmaf(hh0, wa[1], fmaf(hh1, wb2[1], ha1));
                ha2 = fmaf(hh0, wa[2], fmaf(hh1, wb2[2], ha2));
                ha3 = fmaf(hh0, wa[3], fmaf(hh1, wb2[3], ha3));
            }
            o0 += 256; o1 += 256; o2h += 256;
        }

        if (do_head) {
            #pragma unroll
            for (int off = 32; off >= 1; off >>= 1) {
                ha0 += __shfl_down(ha0, off, 64);
                ha1 += __shfl_down(ha1, off, 64);
                ha2 += __shfl_down(ha2, off, 64);
                ha3 += __shfl_down(ha3, off, 64);
            }
            if (lane == 0) {
                floatx4 v = {ha0, ha1, ha2, ha3};
                *(floatx4*)(smem + REDF_OFF + w * 16) = v;
            }
            __syncthreads();
            if (tid == 0) {
                floatx4 s = {0.f, 0.f, 0.f, 0.f};
                #pragma unroll
                for (int k = 0; k < 8; ++k)
                    s += *(const floatx4*)(smem + REDF_OFF + k * 16);
                *(floatx4*)(partial + (size_t)bid * 4) = s;
            }
        }
    }

    // (3) x-convert stores (loads were issued at kernel start)
    if (cvalid) {
        half4f v = {(f16)cx0, (f16)cx1, (f16)cx2, (f16)1.0f};
        *(half4f*)(xpad + ((size_t)((bi * 16 + cslice) * 66 + cgr + 1) * 68
                           + cgc + 1) * 4) = v;
    }
}

__global__ __launch_bounds__(64) void head_finish(
    const float* __restrict__ partial,  // (512,4): bid = bi*16+strip
    const float* __restrict__ bout,
    float* __restrict__ out)
{
    int b = threadIdx.x;
    if (b >= NB) return;
    float l0 = bout[0], l1 = bout[1], l2 = bout[2], l3 = bout[3];
    for (int s = 0; s < 16; ++s) {
        floatx4 p = *(const floatx4*)(partial + (size_t)(b * 16 + s) * 4);
        l0 += p[0]; l1 += p[1]; l2 += p[2]; l3 += p[3];
    }
    float m = fmaxf(fmaxf(l0, l1), fmaxf(l2, l3));
    float e0 = expf(l0 - m), e1 = expf(l1 - m);
    float e2 = expf(l2 - m), e3 = expf(l3 - m);
    float inv = 1.0f / (e0 + e1 + e2 + e3);
    out[b * 4 + 0] = e0 * inv;
    out[b * 4 + 1] = e1 * inv;
    out[b * 4 + 2] = e2 * inv;
    out[b * 4 + 3] = e3 * inv;
}

// ========== fallback (ws too small): r8-style LDS per-step path ==========
__global__ __launch_bounds__(256) void prepack_fb(
    const float* __restrict__ Wx, const float* __restrict__ Wh,
    const float* __restrict__ bias, f16* __restrict__ WB)
{
    int i = blockIdx.x * 256 + threadIdx.x;
    if (i < 4096) WB[i] = (f16)wb_entry(i, Wx, Wh, bias);
}

#define FB_XOFF 4352
#define FB_SMEM 6528

#define LDAS(off) ({                                                       \
    half4f lo_ = *(const half4f*)(smem + (off));                           \
    half4f hi_ = *(const half4f*)(smem + (off) + 8);                       \
    __builtin_shufflevector(lo_, hi_, 0, 1, 2, 3, 4, 5, 6, 7); })

__global__ __launch_bounds__(256, 4) void convlstm_step_fb(
    const float* __restrict__ x, const f16* __restrict__ WB,
    const f16* __restrict__ h_in, f16* __restrict__ h_out,
    float* __restrict__ c_buf, int t, int first)
{
    __shared__ __attribute__((aligned(16))) char smem[FB_SMEM];

    const int bid = blockIdx.x;
    const int bi  = bid >> 5;
    const int r0  = (bid & 31) << 1;
    const int tid = threadIdx.x;
    const int w    = tid >> 6;
    const int lane = tid & 63;
    const int p16  = lane & 15;
    const int g4   = lane >> 4;
    const int pr   = w >> 1;
    const int wcol = (w & 1) << 5;

    const float* xt = x + (((size_t)bi * NT + t) * 4096) * 3;

    for (int i = tid; i < 272; i += 256) {
        int lr = i / 68, lc = i - lr * 68;
        int gr = r0 - 1 + lr, gc = lc - 1;
        bool ok = ((unsigned)gr < 64u) && ((unsigned)gc < 64u);
        half4f xv = {0, 0, 0, (f16)1.0f};
        half8f hv = {0, 0, 0, 0, 0, 0, 0, 0};
        if (ok) {
            const float* xp = xt + (gr * 64 + gc) * 3;
            xv[0] = (f16)xp[0]; xv[1] = (f16)xp[1]; xv[2] = (f16)xp[2];
            if (!first)
                hv = *(const half8f*)(h_in + ((size_t)(bi * 4096 + gr * 64 + gc)) * 8);
        }
        *(half8f*)(smem + i * 16) = hv;
        *(half4f*)(smem + FB_XOFF + i * 8) = xv;
    }

    const half8f* WBv = (const half8f*)WB;
    half8f B00 = WBv[0*64+lane], B01 = WBv[1*64+lane];
    half8f B10 = WBv[2*64+lane], B11 = WBv[3*64+lane];
    half8f B20 = WBv[4*64+lane], B21 = WBv[5*64+lane];
    half8f B30 = WBv[6*64+lane], B31 = WBv[7*64+lane];

    const int f0 = g4 << 1;
    const size_t gp0 = (size_t)(bi * 4096 + (r0 + pr) * 64 + wcol + p16);
    const size_t gp1 = gp0 + 16;
    floatx2 cold0 = {0.f, 0.f}, cold1 = {0.f, 0.f};
    if (!first) {
        cold0 = *(const floatx2*)(c_buf + gp0 * 8 + f0);
        cold1 = *(const floatx2*)(c_buf + gp1 * 8 + f0);
    }

    __syncthreads();

    const int ty0 = (g4 >= 3) ? 1 : 0, tx0 = g4 - 3 * ty0;
    const int ty1 = 1 + ((g4 >= 2) ? 1 : 0), tx1 = (g4 + 4) - 3 * ty1;
    const int ty2 = (g4 == 3) ? 1 : 0, tx2 = (g4 == 2) ? 2 : 0;
    const int ty3 = (g4 == 0) ? 1 : 2, tx3 = (g4 == 1) ? 0 : 2;
    const int inc2 = (g4 == 0) ? 256 : 128;
    int o0 = ((pr + ty0) * 68 + wcol + p16 + tx0) * 16;
    int o1 = ((pr + ty1) * 68 + wcol + p16 + tx1) * 16;
    int o2 = (g4 == 0) ? ((pr + 2) * 68 + wcol + p16 + 2) * 16
                       : FB_XOFF + ((pr + ty2) * 68 + wcol + p16 + tx2) * 8;
    int o3 = FB_XOFF + ((pr + ty3) * 68 + wcol + p16 + tx3) * 8;

    #pragma unroll
    for (int tt = 0; tt < 2; ++tt) {
        half8f a0 = LDAS(o0), a1 = LDAS(o1), a2 = LDAS(o2), a3 = LDAS(o3);
        floatx2 cold = tt ? cold1 : cold0;
        float cc0, cc1, hh0, hh1;
        GATE_BODY(a0, a1, a2, a3, cold[0], cold[1], cc0, cc1, hh0, hh1);
        const size_t gp = tt ? gp1 : gp0;
        floatx2 cw = {cc0, cc1};
        *(floatx2*)(c_buf + gp * 8 + f0) = cw;
        half2f hw = {(f16)hh0, (f16)hh1};
        *(half2f*)(h_out + gp * 8 + f0) = hw;
        o0 += 256; o1 += 256; o2 += inc2; o3 += 128;
    }
}

__global__ __launch_bounds__(256) void head_partial_fb(
    const f16* __restrict__ h, const float* __restrict__ Wout,
    float* __restrict__ partial)
{
    const int b = blockIdx.x >> 4;
    const int chunk = blockIdx.x & 15;
    const int tid = threadIdx.x;
    const f16* hb = h + (size_t)b * 32768 + chunk * 2048;
    const float* wb = Wout + (size_t)(chunk * 2048) * 4;

    float acc[4] = {0.f, 0.f, 0.f, 0.f};
    #pragma unroll
    for (int it = 0; it < 8; ++it) {
        int i = it * 256 + tid;
        float hv = (float)hb[i];
        float4 wv = *(const float4*)(wb + (size_t)i * 4);
        acc[0] = fmaf(hv, wv.x, acc[0]);
        acc[1] = fmaf(hv, wv.y, acc[1]);
        acc[2] = fmaf(hv, wv.z, acc[2]);
        acc[3] = fmaf(hv, wv.w, acc[3]);
    }
    #pragma unroll
    for (int j = 0; j < 4; ++j)
        #pragma unroll
        for (int off = 32; off >= 1; off >>= 1)
            acc[j] += __shfl_down(acc[j], off, 64);

    __shared__ float red2[4][4];
    int lane = tid & 63, wv2 = tid >> 6;
    if (lane == 0) {
        #pragma unroll
        for (int j = 0; j < 4; ++j) red2[wv2][j] = acc[j];
    }
    __syncthreads();
    if (tid == 0) {
        #pragma unroll
        for (int j = 0; j < 4; ++j)
            partial[(size_t)blockIdx.x * 4 + j] =
                red2[0][j] + red2[1][j] + red2[2][j] + red2[3][j];
    }
}

__global__ __launch_bounds__(64) void head_finish_fb(
    const float* __restrict__ partial, const float* __restrict__ bout,
    float* __restrict__ out)
{
    int b = threadIdx.x;
    if (b >= NB) return;
    float logit[4] = {bout[0], bout[1], bout[2], bout[3]};
    #pragma unroll
    for (int k = 0; k < 16; ++k) {
        const float* p = partial + (size_t)(b * 16 + k) * 4;
        logit[0] += p[0]; logit[1] += p[1]; logit[2] += p[2]; logit[3] += p[3];
    }
    float m = fmaxf(fmaxf(logit[0], logit[1]), fmaxf(logit[2], logit[3]));
    float e[4], s = 0.f;
    #pragma unroll
    for (int j = 0; j < 4; ++j) { e[j] = expf(logit[j] - m); s += e[j]; }
    float inv = 1.0f / s;
    #pragma unroll
    for (int j = 0; j < 4; ++j) out[b * 4 + j] = e[j] * inv;
}

extern "C" void kernel_launch(void* const* d_in, const int* in_sizes, int n_in,
                              void* d_out, int out_size, void* d_ws, size_t ws_size,
                              hipStream_t stream) {
    const float* x    = (const float*)d_in[0];
    const float* Wx   = (const float*)d_in[1];
    const float* Wh   = (const float*)d_in[2];
    const float* b    = (const float*)d_in[3];
    const float* Wout = (const float*)d_in[4];
    const float* bout = (const float*)d_in[5];
    float* out = (float*)d_out;
    char* ws = (char*)d_ws;

    if (ws_size >= WS_NEED) {
        f16*   xpad  = (f16*)(ws + XPAD_OFF);
        f16*   h0    = (f16*)(ws + HPAD0_OFF);
        f16*   h1    = (f16*)(ws + HPAD1_OFF);
        float* cb    = (float*)(ws + CBUF_OFF);
        f16*   WBq   = (f16*)(ws + WBQ_OFF);
        float* part  = (float*)(ws + PART_OFF);

        init_all<<<1922, 256, 0, stream>>>(x, Wx, Wh, b, xpad, h0, h1, WBq);

        // fused kernel k covers t = 2k, 2k+1; converts x slices 2k+2, 2k+3.
        for (int k = 0; k < 8; ++k) {
            const f16* hin  = (k & 1) ? h0 : h1;   // k=0: h1 (unused, first)
            f16*       hout = (k & 1) ? h1 : h0;
            convlstm_fused2<<<512, 512, 0, stream>>>(
                x, xpad, WBq, hin, hout, cb, Wout, part,
                2 * k, (k == 0) ? 1 : 0, (k == 7) ? 1 : 0);
        }
        head_finish<<<1, 64, 0, stream>>>(part, bout, out);
    } else {
        f16*   hA      = (f16*)ws;                    // 2 MB
        f16*   hB      = (f16*)(ws + (1u << 21));     // 2 MB
        float* cb      = (float*)(ws + (1u << 22));   // 4 MB
        f16*   WBq     = (f16*)(ws + (1u << 23));     // 8 KB
        float* partial = (float*)(ws + (1u << 23) + 8192);

        prepack_fb<<<16, 256, 0, stream>>>(Wx, Wh, b, WBq);
        for (int t = 0; t < NT; ++t) {
            const f16* hin = (t & 1) ? hA : hB;
            f16*       hout = (t & 1) ? hB : hA;
            convlstm_step_fb<<<1024, 256, 0, stream>>>(x, WBq, hin, hout, cb,
                                                       t, (t == 0) ? 1 : 0);
        }
        head_partial_fb<<<512, 256, 0, stream>>>(hB, Wout, partial);
        head_finish_fb<<<1, 64, 0, stream>>>(partial, bout, out);
    }
}

// Round 17
// 77.338 us; speedup vs baseline: 8.3708x; 1.0075x over previous
//
#include <hip/hip_runtime.h>
#include <math.h>

#define NB 32
#define NT 16

typedef _Float16 f16;
typedef _Float16 half2f __attribute__((ext_vector_type(2)));
typedef _Float16 half4f __attribute__((ext_vector_type(4)));
typedef _Float16 half8f __attribute__((ext_vector_type(8)));
typedef float    floatx2 __attribute__((ext_vector_type(2)));
typedef float    floatx4 __attribute__((ext_vector_type(4)));

// ---- workspace layout (bytes) ----
#define XPAD_OFF  0u                     // (512, 66*68, 4) f16 = 18,382,848
#define HPAD0_OFF 18382848u              // (32, 66, 68, 8) f16 = 2,297,856
#define HPAD1_OFF 20680704u
#define CBUF_OFF  22978560u              // (32, 64, 64, 8) f32 = 4,194,304
#define WBQ_OFF   27172864u              // 4096 f16 = 8192
#define PART_OFF  27181056u              // 512 float4 = 8192
#define WS_NEED   27197440u

// ---- fused-4 kernel LDS (bytes) ----
// band0/band1: 10 rows x 68 x 16B (8ch f16)  = 10,880 each
// cLDS: 8 rows x 64 x 8ch f32                = 16,384
#define BAND0   0
#define BAND1   10880
#define CLDS_OFF 21760
#define REDF_OFF 38144
#define SMEM4    38272

__device__ __forceinline__ float hard_sigmoid(float v) {
    return fminf(fmaxf(fmaf(0.2f, v, 0.5f), 0.0f), 1.0f);
}
__device__ __forceinline__ float fast_tanh(float v) {
    float e = __builtin_amdgcn_exp2f(v * 2.8853900817779268f);
    return 1.0f - 2.0f * __builtin_amdgcn_rcpf(e + 1.0f);
}

// Weight-fragment entry (validated r12-r16): lane owns adjacent filters
// 2g4, 2g4+1; acc rows = [i,f,c,o].
__device__ __forceinline__ float wb_entry(int i, const float* Wx,
                                          const float* Wh, const float* bias) {
    int e = i & 7, l = (i >> 3) & 63, n = (i >> 9) & 1, j = i >> 10;
    int h = l >> 4;
    int rr = l & 15;
    int g = (rr & 3) * 8 + 2 * (rr >> 2) + n;
    float wv = 0.f;
    if (j == 0) {
        wv = Wh[(h * 8 + e) * 32 + g];
    } else if (j == 1) {
        wv = Wh[((4 + h) * 8 + e) * 32 + g];
    } else if (j == 2 && h == 0) {
        wv = Wh[(64 + e) * 32 + g];
    } else if (j == 3 && h == 3) {
        wv = (e == 3) ? bias[g] : 0.f;
    } else {
        int ty, txp;
        if (j == 2) { ty = (h == 3) ? 1 : 0; txp = (h == 2) ? 2 : 0; }
        else        { ty = (h == 0) ? 1 : 2; txp = (h == 1) ? 0 : 2; }
        int txq = txp + (e >> 2), c = e & 3;
        if (txq < 3 && c < 3)
            wv = Wx[((ty * 3 + txq) * 3 + c) * 32 + g];
    }
    return wv;
}

#define LDX(base, off) ({                                                  \
    half4f lo_ = *(const half4f*)((base) + (off));                         \
    half4f hi_ = *(const half4f*)((base) + (off) + 8);                     \
    __builtin_shufflevector(lo_, hi_, 0, 1, 2, 3, 4, 5, 6, 7); })

#define GATE_BODY(A0, A1, A2, A3, COLD0, COLD1, CC0, CC1, HH0, HH1)        \
    {                                                                      \
        floatx4 acc0 = {0.f, 0.f, 0.f, 0.f};                               \
        floatx4 acc1 = {0.f, 0.f, 0.f, 0.f};                               \
        acc0 = __builtin_amdgcn_mfma_f32_16x16x32_f16(B00, A0, acc0,0,0,0);\
        acc1 = __builtin_amdgcn_mfma_f32_16x16x32_f16(B01, A0, acc1,0,0,0);\
        acc0 = __builtin_amdgcn_mfma_f32_16x16x32_f16(B10, A1, acc0,0,0,0);\
        acc1 = __builtin_amdgcn_mfma_f32_16x16x32_f16(B11, A1, acc1,0,0,0);\
        acc0 = __builtin_amdgcn_mfma_f32_16x16x32_f16(B20, A2, acc0,0,0,0);\
        acc1 = __builtin_amdgcn_mfma_f32_16x16x32_f16(B21, A2, acc1,0,0,0);\
        acc0 = __builtin_amdgcn_mfma_f32_16x16x32_f16(B30, A3, acc0,0,0,0);\
        acc1 = __builtin_amdgcn_mfma_f32_16x16x32_f16(B31, A3, acc1,0,0,0);\
        float ig0 = hard_sigmoid(acc0[0]), fg0 = hard_sigmoid(acc0[1]);    \
        float cg0 = fast_tanh(acc0[2]),    og0 = hard_sigmoid(acc0[3]);    \
        CC0 = fmaf(fg0, COLD0, ig0 * cg0);                                 \
        HH0 = og0 * fast_tanh(CC0);                                        \
        float ig1 = hard_sigmoid(acc1[0]), fg1 = hard_sigmoid(acc1[1]);    \
        float cg1 = fast_tanh(acc1[2]),    og1 = hard_sigmoid(acc1[3]);    \
        CC1 = fmaf(fg1, COLD1, ig1 * cg1);                                 \
        HH1 = og1 * fast_tanh(CC1);                                        \
    }

// ---- init: xpad borders + h borders + WB + x slices 0..3 ----
__global__ __launch_bounds__(256) void init_all(
    const float* __restrict__ x,
    const float* __restrict__ Wx, const float* __restrict__ Wh,
    const float* __restrict__ bias,
    f16* __restrict__ xpad, f16* __restrict__ h0, f16* __restrict__ h1,
    f16* __restrict__ WB)
{
    int i = blockIdx.x * 256 + threadIdx.x;
    if (i < 200704) {                      // xpad borders: 512 x 392
        int bt = i / 392, p = i - bt * 392;
        int rr, cc;
        if (p < 136) { rr = (p < 68) ? 0 : 65; cc = p - ((p < 68) ? 0 : 68); }
        else { int q = p - 136; rr = 1 + (q >> 2); int m = q & 3;
               cc = (m == 0) ? 0 : 64 + m; }
        half4f v = {0, 0, 0, (f16)1.0f};
        *(half4f*)(xpad + ((size_t)(bt * 66 + rr) * 68 + cc) * 4) = v;
    } else if (i < 225792) {               // h borders: 2 x 32 x 392
        int k = i - 200704;
        int buf = k / 12544; k -= buf * 12544;
        int b = k / 392, p = k - b * 392;
        int rr, cc;
        if (p < 136) { rr = (p < 68) ? 0 : 65; cc = p - ((p < 68) ? 0 : 68); }
        else { int q = p - 136; rr = 1 + (q >> 2); int m = q & 3;
               cc = (m == 0) ? 0 : 64 + m; }
        f16* hp = buf ? h1 : h0;
        half8f zz = {0, 0, 0, 0, 0, 0, 0, 0};
        *(half8f*)(hp + ((size_t)(b * 66 + rr) * 68 + cc) * 8) = zz;
    } else if (i < 229888) {               // WB: 4096
        int k = i - 225792;
        WB[k] = (f16)wb_entry(k, Wx, Wh, bias);
    } else if (i < 754176) {               // x slices 0..3: 32 x 4 x 4096
        int j = i - 229888;
        int b = j >> 14;
        int rem = j & 16383;
        int s = rem >> 12, px = rem & 4095;
        const float* xp = x + ((size_t)(b * 16 + s) * 4096 + px) * 3;
        half4f v = {(f16)xp[0], (f16)xp[1], (f16)xp[2], (f16)1.0f};
        int gr = px >> 6, gc = px & 63;
        *(half4f*)(xpad + ((size_t)((b * 16 + s) * 66 + gr + 1) * 68 + gc + 1) * 4) = v;
    }
}

// ---- fused 4-step kernel: phases compute 10/8/6/4 band rows at t..t+3.
// Intermediate h bands double-buffered in LDS; intermediate c in LDS f32.
// Only h(t+3)/c(t+3) touch global (or fold head at t+3==15).
// Grid 512 (XCD-swizzled), block 512 (8 waves), LDS 38,272 B -> 2 blocks/CU.
__global__ __launch_bounds__(512, 4) void convlstm_fused4(
    const float* __restrict__ x,     // raw input (for next-slice conversion)
    f16* __restrict__ xpad,          // (512, 66*68, 4)
    const f16* __restrict__ WB,
    const f16* __restrict__ h_in,    // padded (32,66,68,8): h(t-1)
    f16* __restrict__ h_out,         // padded: h(t+3)
    float* __restrict__ c_buf,       // (32,64,64,8) f32: in c(t-1), out c(t+3)
    const float* __restrict__ Wout,  // (32768,4)
    float* __restrict__ partial,     // (512,4)
    int t, int first, int do_head)
{
    __shared__ __attribute__((aligned(16))) char smem[SMEM4];

    const int bid0 = blockIdx.x;
    const int bid  = ((bid0 & 7) << 6) | (bid0 >> 3);   // XCD-contiguous
    const int bi  = bid >> 4;
    const int r0  = (bid & 15) << 2;
    const int tid = threadIdx.x;
    const int w    = __builtin_amdgcn_readfirstlane(tid >> 6);  // 0..7
    const int lane = tid & 63;
    const int p16  = lane & 15;
    const int g4   = lane >> 4;
    const int f0   = g4 << 1;

    // early x-convert source loads: slices t+4..t+7, 2 px/thread
    const int c0s = t + 4 + (tid >> 8);         // px block 0
    const int c1s = c0s + 2;                    // px block 1
    const bool c0v = (c0s < NT), c1v = (c1s < NT);
    const int c0p = tid & 255, c1p = c0p;       // same px index, diff slice
    const int c0r = r0 + (c0p >> 6), c0c = c0p & 63;
    float c0x0 = 0.f, c0x1 = 0.f, c0x2 = 0.f;
    float c1x0 = 0.f, c1x1 = 0.f, c1x2 = 0.f;
    if (c0v) {
        const float* p = x + ((size_t)(bi * NT + c0s) * 4096 + c0r * 64 + c0c) * 3;
        c0x0 = p[0]; c0x1 = p[1]; c0x2 = p[2];
    }
    if (c1v) {
        const float* p = x + ((size_t)(bi * NT + c1s) * 4096 + c0r * 64 + c0c) * 3;
        c1x0 = p[0]; c1x1 = p[1]; c1x2 = p[2];
    }

    // weight fragments
    const half8f* WBv = (const half8f*)WB;
    half8f B00 = WBv[0*64+lane], B01 = WBv[1*64+lane];
    half8f B10 = WBv[2*64+lane], B11 = WBv[3*64+lane];
    half8f B20 = WBv[4*64+lane], B21 = WBv[5*64+lane];
    half8f B30 = WBv[6*64+lane], B31 = WBv[7*64+lane];

    // tap->offset tables (validated r7-r16)
    const int ty0 = (g4 >= 3) ? 1 : 0, tx0 = g4 - 3 * ty0;
    const int ty1 = 1 + ((g4 >= 2) ? 1 : 0), tx1 = (g4 + 4) - 3 * ty1;
    const int ty2 = (g4 == 3) ? 1 : 0, tx2 = (g4 == 2) ? 2 : 0;
    const int ty3 = (g4 == 0) ? 1 : 2, tx3 = (g4 == 1) ? 0 : 2;

    const half8f z8 = {0, 0, 0, 0, 0, 0, 0, 0};

    // zero border cols (0 and 65) of all 10 rows, both band buffers
    if (tid < 40) {
        int buf = tid / 20;
        int rr  = (tid % 20) >> 1;
        int cc  = (tid & 1) ? 65 : 0;
        *(half8f*)(smem + (buf ? BAND1 : BAND0) + (rr * 68 + cc) * 16) = z8;
    }

    // ======== PHASE 0: rows r0-3..r0+6 (10), global h/c -> band0/cLDS ========
    {
        #pragma unroll
        for (int k = 0; k < 5; ++k) {
            const int tau = w * 5 + k;
            const int rowl = tau >> 2, ct = tau & 3;
            const int row = r0 - 3 + rowl;
            const bool vA = ((unsigned)row < 64u);
            const int colA = ct * 16 + p16;
            float cc0 = 0.f, cc1 = 0.f, hh0 = 0.f, hh1 = 0.f;
            if (vA) {
                floatx2 cold = {0.f, 0.f};
                if (!first)
                    cold = *(const floatx2*)(c_buf +
                               ((size_t)(bi * 4096 + row * 64 + colA)) * 8 + f0);
                const char* hpA = (const char*)(h_in + ((size_t)(bi * 66 + row)) * 68 * 8);
                const char* xpA = (const char*)(xpad +
                    ((size_t)((bi * 16 + t) * 66 + row)) * 68 * 4);
                half8f a0 = first ? z8 : *(const half8f*)(hpA + (ty0 * 68 + colA + tx0) * 16);
                half8f a1 = first ? z8 : *(const half8f*)(hpA + (ty1 * 68 + colA + tx1) * 16);
                half8f a2;
                if (g4 == 0) a2 = first ? z8 : *(const half8f*)(hpA + (2 * 68 + colA + 2) * 16);
                else         a2 = LDX(xpA, (ty2 * 68 + colA + tx2) * 8);
                half8f a3 = LDX(xpA, (ty3 * 68 + colA + tx3) * 8);
                GATE_BODY(a0, a1, a2, a3, cold[0], cold[1], cc0, cc1, hh0, hh1);
            }
            half2f hw = {(f16)hh0, (f16)hh1};
            *(half2f*)(smem + BAND0 + (rowl * 68 + 1 + colA) * 16 + f0 * 2) = hw;
            if (rowl >= 1 && rowl <= 8) {
                floatx2 cw = {cc0, cc1};
                *(floatx2*)(smem + CLDS_OFF + (((rowl - 1) * 64 + colA) * 8 + f0) * 4) = cw;
            }
        }
    }
    __syncthreads();

    // ======== PHASE 1: rows r0-2..r0+5 (8), band0 -> band1, c in-place ======
    {
        #pragma unroll
        for (int k = 0; k < 4; ++k) {
            const int tau = w * 4 + k;
            const int rowl = tau >> 2, ct = tau & 3;
            const int row = r0 - 2 + rowl;
            const bool vA = ((unsigned)row < 64u);
            const int colA = ct * 16 + p16;
            const int cidx = rowl;                     // row-(r0-2)
            float cc0 = 0.f, cc1 = 0.f, hh0 = 0.f, hh1 = 0.f;
            if (vA) {
                floatx2 cold = *(const floatx2*)(smem + CLDS_OFF +
                                   ((cidx * 64 + colA) * 8 + f0) * 4);
                const char* xpA = (const char*)(xpad +
                    ((size_t)((bi * 16 + t + 1) * 66 + row)) * 68 * 4);
                half8f a0 = *(const half8f*)(smem + BAND0 + ((rowl + ty0) * 68 + colA + tx0) * 16);
                half8f a1 = *(const half8f*)(smem + BAND0 + ((rowl + ty1) * 68 + colA + tx1) * 16);
                half8f a2;
                if (g4 == 0) a2 = *(const half8f*)(smem + BAND0 + ((rowl + 2) * 68 + colA + 2) * 16);
                else         a2 = LDX(xpA, (ty2 * 68 + colA + tx2) * 8);
                half8f a3 = LDX(xpA, (ty3 * 68 + colA + tx3) * 8);
                GATE_BODY(a0, a1, a2, a3, cold[0], cold[1], cc0, cc1, hh0, hh1);
            }
            half2f hw = {(f16)hh0, (f16)hh1};
            *(half2f*)(smem + BAND1 + ((rowl + 1) * 68 + 1 + colA) * 16 + f0 * 2) = hw;
            floatx2 cw = {cc0, cc1};
            *(floatx2*)(smem + CLDS_OFF + ((cidx * 64 + colA) * 8 + f0) * 4) = cw;
        }
    }
    __syncthreads();

    // ======== PHASE 2: rows r0-1..r0+4 (6), band1 -> band0, c in-place ======
    {
        #pragma unroll
        for (int k = 0; k < 3; ++k) {
            const int tau = w * 3 + k;
            const int rowl = tau >> 2, ct = tau & 3;
            const int row = r0 - 1 + rowl;
            const bool vA = ((unsigned)row < 64u);
            const int colA = ct * 16 + p16;
            const int cidx = rowl + 1;                 // row-(r0-2)
            float cc0 = 0.f, cc1 = 0.f, hh0 = 0.f, hh1 = 0.f;
            if (vA) {
                floatx2 cold = *(const floatx2*)(smem + CLDS_OFF +
                                   ((cidx * 64 + colA) * 8 + f0) * 4);
                const char* xpA = (const char*)(xpad +
                    ((size_t)((bi * 16 + t + 2) * 66 + row)) * 68 * 4);
                half8f a0 = *(const half8f*)(smem + BAND1 + ((rowl + 1 + ty0) * 68 + colA + tx0) * 16);
                half8f a1 = *(const half8f*)(smem + BAND1 + ((rowl + 1 + ty1) * 68 + colA + tx1) * 16);
                half8f a2;
                if (g4 == 0) a2 = *(const half8f*)(smem + BAND1 + ((rowl + 3) * 68 + colA + 2) * 16);
                else         a2 = LDX(xpA, (ty2 * 68 + colA + tx2) * 8);
                half8f a3 = LDX(xpA, (ty3 * 68 + colA + tx3) * 8);
                GATE_BODY(a0, a1, a2, a3, cold[0], cold[1], cc0, cc1, hh0, hh1);
            }
            half2f hw = {(f16)hh0, (f16)hh1};
            *(half2f*)(smem + BAND0 + ((rowl + 2) * 68 + 1 + colA) * 16 + f0 * 2) = hw;
            floatx2 cw = {cc0, cc1};
            *(floatx2*)(smem + CLDS_OFF + ((cidx * 64 + colA) * 8 + f0) * 4) = cw;
        }
    }
    __syncthreads();

    // ======== PHASE 3: rows r0..r0+3 (4), band0 -> global (or head) =========
    {
        float ha0 = 0.f, ha1 = 0.f, ha2 = 0.f, ha3 = 0.f;
        #pragma unroll
        for (int k = 0; k < 2; ++k) {
            const int tau = w * 2 + k;
            const int rowl = tau >> 2, ct = tau & 3;
            const int row = r0 + rowl;                 // always valid
            const int colA = ct * 16 + p16;
            const int cidx = rowl + 2;
            floatx2 cold = *(const floatx2*)(smem + CLDS_OFF +
                               ((cidx * 64 + colA) * 8 + f0) * 4);
            const char* xpA = (const char*)(xpad +
                ((size_t)((bi * 16 + t + 3) * 66 + row)) * 68 * 4);
            half8f a0 = *(const half8f*)(smem + BAND0 + ((rowl + 2 + ty0) * 68 + colA + tx0) * 16);
            half8f a1 = *(const half8f*)(smem + BAND0 + ((rowl + 2 + ty1) * 68 + colA + tx1) * 16);
            half8f a2;
            if (g4 == 0) a2 = *(const half8f*)(smem + BAND0 + ((rowl + 4) * 68 + colA + 2) * 16);
            else         a2 = LDX(xpA, (ty2 * 68 + colA + tx2) * 8);
            half8f a3 = LDX(xpA, (ty3 * 68 + colA + tx3) * 8);
            float cc0, cc1, hh0, hh1;
            GATE_BODY(a0, a1, a2, a3, cold[0], cold[1], cc0, cc1, hh0, hh1);

            if (!do_head) {
                const size_t gp = (size_t)(bi * 4096 + row * 64 + colA);
                floatx2 cw = {cc0, cc1};
                *(floatx2*)(c_buf + gp * 8 + f0) = cw;
                const size_t hb = ((size_t)(bi * 66 + row + 1) * 68 + 1 + colA) * 8 + f0;
                half2f hw = {(f16)hh0, (f16)hh1};
                *(half2f*)(h_out + hb) = hw;
            } else {
                int pix = row * 64 + colA;
                floatx4 wa  = *(const floatx4*)(Wout + (size_t)(pix * 8 + f0) * 4);
                floatx4 wb2 = *(const floatx4*)(Wout + (size_t)(pix * 8 + f0 + 1) * 4);
                ha0 = fmaf(hh0, wa[0], fmaf(hh1, wb2[0], ha0));
                ha1 = fmaf(hh0, wa[1], fmaf(hh1, wb2[1], ha1));
                ha2 = fmaf(hh0, wa[2], fmaf(hh1, wb2[2], ha2));
                ha3 = fmaf(hh0, wa[3], fmaf(hh1, wb2[3], ha3));
            }
        }

        if (do_head) {
            #pragma unroll
            for (int off = 32; off >= 1; off >>= 1) {
                ha0 += __shfl_down(ha0, off, 64);
                ha1 += __shfl_down(ha1, off, 64);
                ha2 += __shfl_down(ha2, off, 64);
                ha3 += __shfl_down(ha3, off, 64);
            }
            if (lane == 0) {
                floatx4 v = {ha0, ha1, ha2, ha3};
                *(floatx4*)(smem + REDF_OFF + w * 16) = v;
            }
            __syncthreads();
            if (tid == 0) {
                floatx4 s = {0.f, 0.f, 0.f, 0.f};
                #pragma unroll
                for (int k = 0; k < 8; ++k)
                    s += *(const floatx4*)(smem + REDF_OFF + k * 16);
                *(floatx4*)(partial + (size_t)bid * 4) = s;
            }
        }
    }

    // x-convert stores (loads issued at kernel start)
    if (c0v) {
        half4f v = {(f16)c0x0, (f16)c0x1, (f16)c0x2, (f16)1.0f};
        *(half4f*)(xpad + ((size_t)((bi * 16 + c0s) * 66 + c0r + 1) * 68 + c0c + 1) * 4) = v;
    }
    if (c1v) {
        half4f v = {(f16)c1x0, (f16)c1x1, (f16)c1x2, (f16)1.0f};
        *(half4f*)(xpad + ((size_t)((bi * 16 + c1s) * 66 + c0r + 1) * 68 + c0c + 1) * 4) = v;
    }
}

__global__ __launch_bounds__(64) void head_finish(
    const float* __restrict__ partial,  // (512,4): bid = bi*16+strip
    const float* __restrict__ bout,
    float* __restrict__ out)
{
    int b = threadIdx.x;
    if (b >= NB) return;
    float l0 = bout[0], l1 = bout[1], l2 = bout[2], l3 = bout[3];
    for (int s = 0; s < 16; ++s) {
        floatx4 p = *(const floatx4*)(partial + (size_t)(b * 16 + s) * 4);
        l0 += p[0]; l1 += p[1]; l2 += p[2]; l3 += p[3];
    }
    float m = fmaxf(fmaxf(l0, l1), fmaxf(l2, l3));
    float e0 = expf(l0 - m), e1 = expf(l1 - m);
    float e2 = expf(l2 - m), e3 = expf(l3 - m);
    float inv = 1.0f / (e0 + e1 + e2 + e3);
    out[b * 4 + 0] = e0 * inv;
    out[b * 4 + 1] = e1 * inv;
    out[b * 4 + 2] = e2 * inv;
    out[b * 4 + 3] = e3 * inv;
}

// ========== fallback (ws too small): r8-style LDS per-step path ==========
__global__ __launch_bounds__(256) void prepack_fb(
    const float* __restrict__ Wx, const float* __restrict__ Wh,
    const float* __restrict__ bias, f16* __restrict__ WB)
{
    int i = blockIdx.x * 256 + threadIdx.x;
    if (i < 4096) WB[i] = (f16)wb_entry(i, Wx, Wh, bias);
}

#define FB_XOFF 4352
#define FB_SMEM 6528

#define LDAS(off) ({                                                       \
    half4f lo_ = *(const half4f*)(smem + (off));                           \
    half4f hi_ = *(const half4f*)(smem + (off) + 8);                       \
    __builtin_shufflevector(lo_, hi_, 0, 1, 2, 3, 4, 5, 6, 7); })

__global__ __launch_bounds__(256, 4) void convlstm_step_fb(
    const float* __restrict__ x, const f16* __restrict__ WB,
    const f16* __restrict__ h_in, f16* __restrict__ h_out,
    float* __restrict__ c_buf, int t, int first)
{
    __shared__ __attribute__((aligned(16))) char smem[FB_SMEM];

    const int bid = blockIdx.x;
    const int bi  = bid >> 5;
    const int r0  = (bid & 31) << 1;
    const int tid = threadIdx.x;
    const int w    = tid >> 6;
    const int lane = tid & 63;
    const int p16  = lane & 15;
    const int g4   = lane >> 4;
    const int pr   = w >> 1;
    const int wcol = (w & 1) << 5;

    const float* xt = x + (((size_t)bi * NT + t) * 4096) * 3;

    for (int i = tid; i < 272; i += 256) {
        int lr = i / 68, lc = i - lr * 68;
        int gr = r0 - 1 + lr, gc = lc - 1;
        bool ok = ((unsigned)gr < 64u) && ((unsigned)gc < 64u);
        half4f xv = {0, 0, 0, (f16)1.0f};
        half8f hv = {0, 0, 0, 0, 0, 0, 0, 0};
        if (ok) {
            const float* xp = xt + (gr * 64 + gc) * 3;
            xv[0] = (f16)xp[0]; xv[1] = (f16)xp[1]; xv[2] = (f16)xp[2];
            if (!first)
                hv = *(const half8f*)(h_in + ((size_t)(bi * 4096 + gr * 64 + gc)) * 8);
        }
        *(half8f*)(smem + i * 16) = hv;
        *(half4f*)(smem + FB_XOFF + i * 8) = xv;
    }

    const half8f* WBv = (const half8f*)WB;
    half8f B00 = WBv[0*64+lane], B01 = WBv[1*64+lane];
    half8f B10 = WBv[2*64+lane], B11 = WBv[3*64+lane];
    half8f B20 = WBv[4*64+lane], B21 = WBv[5*64+lane];
    half8f B30 = WBv[6*64+lane], B31 = WBv[7*64+lane];

    const int f0 = g4 << 1;
    const size_t gp0 = (size_t)(bi * 4096 + (r0 + pr) * 64 + wcol + p16);
    const size_t gp1 = gp0 + 16;
    floatx2 cold0 = {0.f, 0.f}, cold1 = {0.f, 0.f};
    if (!first) {
        cold0 = *(const floatx2*)(c_buf + gp0 * 8 + f0);
        cold1 = *(const floatx2*)(c_buf + gp1 * 8 + f0);
    }

    __syncthreads();

    const int ty0 = (g4 >= 3) ? 1 : 0, tx0 = g4 - 3 * ty0;
    const int ty1 = 1 + ((g4 >= 2) ? 1 : 0), tx1 = (g4 + 4) - 3 * ty1;
    const int ty2 = (g4 == 3) ? 1 : 0, tx2 = (g4 == 2) ? 2 : 0;
    const int ty3 = (g4 == 0) ? 1 : 2, tx3 = (g4 == 1) ? 0 : 2;
    const int inc2 = (g4 == 0) ? 256 : 128;
    int o0 = ((pr + ty0) * 68 + wcol + p16 + tx0) * 16;
    int o1 = ((pr + ty1) * 68 + wcol + p16 + tx1) * 16;
    int o2 = (g4 == 0) ? ((pr + 2) * 68 + wcol + p16 + 2) * 16
                       : FB_XOFF + ((pr + ty2) * 68 + wcol + p16 + tx2) * 8;
    int o3 = FB_XOFF + ((pr + ty3) * 68 + wcol + p16 + tx3) * 8;

    #pragma unroll
    for (int tt = 0; tt < 2; ++tt) {
        half8f a0 = LDAS(o0), a1 = LDAS(o1), a2 = LDAS(o2), a3 = LDAS(o3);
        floatx2 cold = tt ? cold1 : cold0;
        float cc0, cc1, hh0, hh1;
        GATE_BODY(a0, a1, a2, a3, cold[0], cold[1], cc0, cc1, hh0, hh1);
        const size_t gp = tt ? gp1 : gp0;
        floatx2 cw = {cc0, cc1};
        *(floatx2*)(c_buf + gp * 8 + f0) = cw;
        half2f hw = {(f16)hh0, (f16)hh1};
        *(half2f*)(h_out + gp * 8 + f0) = hw;
        o0 += 256; o1 += 256; o2 += inc2; o3 += 128;
    }
}

__global__ __launch_bounds__(256) void head_partial_fb(
    const f16* __restrict__ h, const float* __restrict__ Wout,
    float* __restrict__ partial)
{
    const int b = blockIdx.x >> 4;
    const int chunk = blockIdx.x & 15;
    const int tid = threadIdx.x;
    const f16* hb = h + (size_t)b * 32768 + chunk * 2048;
    const float* wb = Wout + (size_t)(chunk * 2048) * 4;

    float acc[4] = {0.f, 0.f, 0.f, 0.f};
    #pragma unroll
    for (int it = 0; it < 8; ++it) {
        int i = it * 256 + tid;
        float hv = (float)hb[i];
        float4 wv = *(const float4*)(wb + (size_t)i * 4);
        acc[0] = fmaf(hv, wv.x, acc[0]);
        acc[1] = fmaf(hv, wv.y, acc[1]);
        acc[2] = fmaf(hv, wv.z, acc[2]);
        acc[3] = fmaf(hv, wv.w, acc[3]);
    }
    #pragma unroll
    for (int j = 0; j < 4; ++j)
        #pragma unroll
        for (int off = 32; off >= 1; off >>= 1)
            acc[j] += __shfl_down(acc[j], off, 64);

    __shared__ float red2[4][4];
    int lane = tid & 63, wv2 = tid >> 6;
    if (lane == 0) {
        #pragma unroll
        for (int j = 0; j < 4; ++j) red2[wv2][j] = acc[j];
    }
    __syncthreads();
    if (tid == 0) {
        #pragma unroll
        for (int j = 0; j < 4; ++j)
            partial[(size_t)blockIdx.x * 4 + j] =
                red2[0][j] + red2[1][j] + red2[2][j] + red2[3][j];
    }
}

__global__ __launch_bounds__(64) void head_finish_fb(
    const float* __restrict__ partial, const float* __restrict__ bout,
    float* __restrict__ out)
{
    int b = threadIdx.x;
    if (b >= NB) return;
    float logit[4] = {bout[0], bout[1], bout[2], bout[3]};
    #pragma unroll
    for (int k = 0; k < 16; ++k) {
        const float* p = partial + (size_t)(b * 16 + k) * 4;
        logit[0] += p[0]; logit[1] += p[1]; logit[2] += p[2]; logit[3] += p[3];
    }
    float m = fmaxf(fmaxf(logit[0], logit[1]), fmaxf(logit[2], logit[3]));
    float e[4], s = 0.f;
    #pragma unroll
    for (int j = 0; j < 4; ++j) { e[j] = expf(logit[j] - m); s += e[j]; }
    float inv = 1.0f / s;
    #pragma unroll
    for (int j = 0; j < 4; ++j) out[b * 4 + j] = e[j] * inv;
}

extern "C" void kernel_launch(void* const* d_in, const int* in_sizes, int n_in,
                              void* d_out, int out_size, void* d_ws, size_t ws_size,
                              hipStream_t stream) {
    const float* x    = (const float*)d_in[0];
    const float* Wx   = (const float*)d_in[1];
    const float* Wh   = (const float*)d_in[2];
    const float* b    = (const float*)d_in[3];
    const float* Wout = (const float*)d_in[4];
    const float* bout = (const float*)d_in[5];
    float* out = (float*)d_out;
    char* ws = (char*)d_ws;

    if (ws_size >= WS_NEED) {
        f16*   xpad  = (f16*)(ws + XPAD_OFF);
        f16*   h0    = (f16*)(ws + HPAD0_OFF);
        f16*   h1    = (f16*)(ws + HPAD1_OFF);
        float* cb    = (float*)(ws + CBUF_OFF);
        f16*   WBq   = (f16*)(ws + WBQ_OFF);
        float* part  = (float*)(ws + PART_OFF);

        init_all<<<2946, 256, 0, stream>>>(x, Wx, Wh, b, xpad, h0, h1, WBq);

        // fused kernel k covers t = 4k..4k+3; converts x slices 4k+4..4k+7.
        for (int k = 0; k < 4; ++k) {
            const f16* hin  = (k & 1) ? h0 : h1;   // k=0: h1 (unused, first)
            f16*       hout = (k & 1) ? h1 : h0;
            convlstm_fused4<<<512, 512, 0, stream>>>(
                x, xpad, WBq, hin, hout, cb, Wout, part,
                4 * k, (k == 0) ? 1 : 0, (k == 3) ? 1 : 0);
        }
        head_finish<<<1, 64, 0, stream>>>(part, bout, out);
    } else {
        f16*   hA      = (f16*)ws;                    // 2 MB
        f16*   hB      = (f16*)(ws + (1u << 21));     // 2 MB
        float* cb      = (float*)(ws + (1u << 22));   // 4 MB
        f16*   WBq     = (f16*)(ws + (1u << 23));     // 8 KB
        float* partial = (float*)(ws + (1u << 23) + 8192);

        prepack_fb<<<16, 256, 0, stream>>>(Wx, Wh, b, WBq);
        for (int t = 0; t < NT; ++t) {
            const f16* hin = (t & 1) ? hA : hB;
            f16*       hout = (t & 1) ? hB : hA;
            convlstm_step_fb<<<1024, 256, 0, stream>>>(x, WBq, hin, hout, cb,
                                                       t, (t == 0) ? 1 : 0);
        }
        head_partial_fb<<<512, 256, 0, stream>>>(hB, Wout, partial);
        head_finish_fb<<<1, 64, 0, stream>>>(partial, bout, out);
    }
}

// Round 18
// 65.766 us; speedup vs baseline: 9.8436x; 1.1760x over previous
//
#include <hip/hip_runtime.h>
#include <math.h>

#define NB 32
#define NT 16

typedef _Float16 f16;
typedef _Float16 half2f __attribute__((ext_vector_type(2)));
typedef _Float16 half4f __attribute__((ext_vector_type(4)));
typedef _Float16 half8f __attribute__((ext_vector_type(8)));
typedef float    floatx2 __attribute__((ext_vector_type(2)));
typedef float    floatx4 __attribute__((ext_vector_type(4)));

// ---- workspace layout (bytes) ----
#define XPAD_OFF  0u                     // (512, 66*68, 4) f16 = 18,382,848
#define HPAD0_OFF 18382848u              // (32, 66, 68, 8) f16 = 2,297,856
#define HPAD1_OFF 20680704u
#define CBUF_OFF  22978560u              // (32, 64, 64, 8) f32 = 4,194,304
#define WBQ_OFF   27172864u              // 4096 f16 = 8192
#define PART_OFF  27181056u              // 256 float4 = 4096
#define WS_NEED   27197440u

// ---- fused-4 R=8 kernel LDS (bytes) ----
// BANDA/BANDB: 14 rows x 68 x 16B (8ch f16) = 15,232 each
// CLDS: 12 rows x 64 x 8ch f32              = 24,576
#define BANDA   0
#define BANDB   15232
#define CLDS4   30464
#define REDF4   55040
#define SMEM5   55296

__device__ __forceinline__ float hard_sigmoid(float v) {
    return fminf(fmaxf(fmaf(0.2f, v, 0.5f), 0.0f), 1.0f);
}
__device__ __forceinline__ float fast_tanh(float v) {
    float e = __builtin_amdgcn_exp2f(v * 2.8853900817779268f);
    return 1.0f - 2.0f * __builtin_amdgcn_rcpf(e + 1.0f);
}

// Weight-fragment entry (validated r12-r17): lane owns adjacent filters
// 2g4, 2g4+1; acc rows = [i,f,c,o].
__device__ __forceinline__ float wb_entry(int i, const float* Wx,
                                          const float* Wh, const float* bias) {
    int e = i & 7, l = (i >> 3) & 63, n = (i >> 9) & 1, j = i >> 10;
    int h = l >> 4;
    int rr = l & 15;
    int g = (rr & 3) * 8 + 2 * (rr >> 2) + n;
    float wv = 0.f;
    if (j == 0) {
        wv = Wh[(h * 8 + e) * 32 + g];
    } else if (j == 1) {
        wv = Wh[((4 + h) * 8 + e) * 32 + g];
    } else if (j == 2 && h == 0) {
        wv = Wh[(64 + e) * 32 + g];
    } else if (j == 3 && h == 3) {
        wv = (e == 3) ? bias[g] : 0.f;
    } else {
        int ty, txp;
        if (j == 2) { ty = (h == 3) ? 1 : 0; txp = (h == 2) ? 2 : 0; }
        else        { ty = (h == 0) ? 1 : 2; txp = (h == 1) ? 0 : 2; }
        int txq = txp + (e >> 2), c = e & 3;
        if (txq < 3 && c < 3)
            wv = Wx[((ty * 3 + txq) * 3 + c) * 32 + g];
    }
    return wv;
}

#define LDX(base, off) ({                                                  \
    half4f lo_ = *(const half4f*)((base) + (off));                         \
    half4f hi_ = *(const half4f*)((base) + (off) + 8);                     \
    __builtin_shufflevector(lo_, hi_, 0, 1, 2, 3, 4, 5, 6, 7); })

#define GATE_BODY(A0, A1, A2, A3, COLD0, COLD1, CC0, CC1, HH0, HH1)        \
    {                                                                      \
        floatx4 acc0 = {0.f, 0.f, 0.f, 0.f};                               \
        floatx4 acc1 = {0.f, 0.f, 0.f, 0.f};                               \
        acc0 = __builtin_amdgcn_mfma_f32_16x16x32_f16(B00, A0, acc0,0,0,0);\
        acc1 = __builtin_amdgcn_mfma_f32_16x16x32_f16(B01, A0, acc1,0,0,0);\
        acc0 = __builtin_amdgcn_mfma_f32_16x16x32_f16(B10, A1, acc0,0,0,0);\
        acc1 = __builtin_amdgcn_mfma_f32_16x16x32_f16(B11, A1, acc1,0,0,0);\
        acc0 = __builtin_amdgcn_mfma_f32_16x16x32_f16(B20, A2, acc0,0,0,0);\
        acc1 = __builtin_amdgcn_mfma_f32_16x16x32_f16(B21, A2, acc1,0,0,0);\
        acc0 = __builtin_amdgcn_mfma_f32_16x16x32_f16(B30, A3, acc0,0,0,0);\
        acc1 = __builtin_amdgcn_mfma_f32_16x16x32_f16(B31, A3, acc1,0,0,0);\
        float ig0 = hard_sigmoid(acc0[0]), fg0 = hard_sigmoid(acc0[1]);    \
        float cg0 = fast_tanh(acc0[2]),    og0 = hard_sigmoid(acc0[3]);    \
        CC0 = fmaf(fg0, COLD0, ig0 * cg0);                                 \
        HH0 = og0 * fast_tanh(CC0);                                        \
        float ig1 = hard_sigmoid(acc1[0]), fg1 = hard_sigmoid(acc1[1]);    \
        float cg1 = fast_tanh(acc1[2]),    og1 = hard_sigmoid(acc1[3]);    \
        CC1 = fmaf(fg1, COLD1, ig1 * cg1);                                 \
        HH1 = og1 * fast_tanh(CC1);                                        \
    }

// ---- init: xpad borders + h borders + WB + x slices 0..3 ----
__global__ __launch_bounds__(256) void init_all(
    const float* __restrict__ x,
    const float* __restrict__ Wx, const float* __restrict__ Wh,
    const float* __restrict__ bias,
    f16* __restrict__ xpad, f16* __restrict__ h0, f16* __restrict__ h1,
    f16* __restrict__ WB)
{
    int i = blockIdx.x * 256 + threadIdx.x;
    if (i < 200704) {                      // xpad borders: 512 x 392
        int bt = i / 392, p = i - bt * 392;
        int rr, cc;
        if (p < 136) { rr = (p < 68) ? 0 : 65; cc = p - ((p < 68) ? 0 : 68); }
        else { int q = p - 136; rr = 1 + (q >> 2); int m = q & 3;
               cc = (m == 0) ? 0 : 64 + m; }
        half4f v = {0, 0, 0, (f16)1.0f};
        *(half4f*)(xpad + ((size_t)(bt * 66 + rr) * 68 + cc) * 4) = v;
    } else if (i < 225792) {               // h borders: 2 x 32 x 392
        int k = i - 200704;
        int buf = k / 12544; k -= buf * 12544;
        int b = k / 392, p = k - b * 392;
        int rr, cc;
        if (p < 136) { rr = (p < 68) ? 0 : 65; cc = p - ((p < 68) ? 0 : 68); }
        else { int q = p - 136; rr = 1 + (q >> 2); int m = q & 3;
               cc = (m == 0) ? 0 : 64 + m; }
        f16* hp = buf ? h1 : h0;
        half8f zz = {0, 0, 0, 0, 0, 0, 0, 0};
        *(half8f*)(hp + ((size_t)(b * 66 + rr) * 68 + cc) * 8) = zz;
    } else if (i < 229888) {               // WB: 4096
        int k = i - 225792;
        WB[k] = (f16)wb_entry(k, Wx, Wh, bias);
    } else if (i < 754176) {               // x slices 0..3: 32 x 4 x 4096
        int j = i - 229888;
        int b = j >> 14;
        int rem = j & 16383;
        int s = rem >> 12, px = rem & 4095;
        const float* xp = x + ((size_t)(b * 16 + s) * 4096 + px) * 3;
        half4f v = {(f16)xp[0], (f16)xp[1], (f16)xp[2], (f16)1.0f};
        int gr = px >> 6, gc = px & 63;
        *(half4f*)(xpad + ((size_t)((b * 16 + s) * 66 + gr + 1) * 68 + gc + 1) * 4) = v;
    }
}

// ---- fused 4-step, R=8 strips: phases compute 14/12/10/8 band rows at
// t..t+3. Grid 256 (XCD-swizzled, 1 block/CU), block 1024 (16 waves) — same
// 16 waves/CU as r17 but recompute factor 1.375x instead of 1.75x.
// Band local row bl = row - (r0-3), bl in 0..13. cLDS idx = bl-1 (0..11).
__global__ __launch_bounds__(1024, 4) void convlstm_fused4w(
    const float* __restrict__ x,     // raw input (for next-slice conversion)
    f16* __restrict__ xpad,          // (512, 66*68, 4)
    const f16* __restrict__ WB,
    const f16* __restrict__ h_in,    // padded (32,66,68,8): h(t-1)
    f16* __restrict__ h_out,         // padded: h(t+3)
    float* __restrict__ c_buf,       // (32,64,64,8) f32: in c(t-1), out c(t+3)
    const float* __restrict__ Wout,  // (32768,4)
    float* __restrict__ partial,     // (256,4)
    int t, int first, int do_head)
{
    __shared__ __attribute__((aligned(16))) char smem[SMEM5];

    const int bid0 = blockIdx.x;
    const int bid  = ((bid0 & 7) << 5) | (bid0 >> 3);   // XCD-contiguous
    const int bi  = bid >> 3;
    const int r0  = (bid & 7) << 3;
    const int tid = threadIdx.x;
    const int w    = __builtin_amdgcn_readfirstlane(tid >> 6);  // 0..15
    const int lane = tid & 63;
    const int p16  = lane & 15;
    const int g4   = lane >> 4;
    const int f0   = g4 << 1;

    // early x-convert source loads: slices t+4..t+7; 2 adjacent px/thread
    const int csl = t + 4 + (tid >> 8);         // 0..3 slice groups
    const bool cv = (csl < NT);
    const int cpb = (tid & 255) << 1;           // 0..510 even
    const int cgr = r0 + (cpb >> 6), cgc = cpb & 63;
    float cxa0 = 0.f, cxa1 = 0.f, cxa2 = 0.f;
    float cxb0 = 0.f, cxb1 = 0.f, cxb2 = 0.f;
    if (cv) {
        const float* p = x + ((size_t)(bi * NT + csl) * 4096 + cgr * 64 + cgc) * 3;
        cxa0 = p[0]; cxa1 = p[1]; cxa2 = p[2];
        cxb0 = p[3]; cxb1 = p[4]; cxb2 = p[5];
    }

    // weight fragments
    const half8f* WBv = (const half8f*)WB;
    half8f B00 = WBv[0*64+lane], B01 = WBv[1*64+lane];
    half8f B10 = WBv[2*64+lane], B11 = WBv[3*64+lane];
    half8f B20 = WBv[4*64+lane], B21 = WBv[5*64+lane];
    half8f B30 = WBv[6*64+lane], B31 = WBv[7*64+lane];

    // tap->offset tables (validated r7-r17)
    const int ty0 = (g4 >= 3) ? 1 : 0, tx0 = g4 - 3 * ty0;
    const int ty1 = 1 + ((g4 >= 2) ? 1 : 0), tx1 = (g4 + 4) - 3 * ty1;
    const int ty2 = (g4 == 3) ? 1 : 0, tx2 = (g4 == 2) ? 2 : 0;
    const int ty3 = (g4 == 0) ? 1 : 2, tx3 = (g4 == 1) ? 0 : 2;

    const half8f z8 = {0, 0, 0, 0, 0, 0, 0, 0};

    // border cols (0, 65) of all 14 rows, both bands: 56 stores
    if (tid < 56) {
        int buf = tid / 28;
        int r2  = (tid % 28) >> 1;
        int cc  = (tid & 1) ? 65 : 0;
        *(half8f*)(smem + (buf ? BANDB : BANDA) + (r2 * 68 + cc) * 16) = z8;
    }

    // ======== PHASE 0: bl 0..13 (56 tiles), global h/c -> BANDA/cLDS ========
    #pragma unroll
    for (int k = 0; k < 4; ++k) {
        const int tau = k * 16 + w;
        if (tau < 56) {
            const int bl = tau >> 2, ct = tau & 3;
            const int row = r0 - 3 + bl;
            const bool vA = ((unsigned)row < 64u);
            const int colA = ct * 16 + p16;
            float cc0 = 0.f, cc1 = 0.f, hh0 = 0.f, hh1 = 0.f;
            if (vA) {
                floatx2 cold = {0.f, 0.f};
                if (!first)
                    cold = *(const floatx2*)(c_buf +
                               ((size_t)(bi * 4096 + row * 64 + colA)) * 8 + f0);
                const char* hpA = (const char*)(h_in + ((size_t)(bi * 66 + row)) * 68 * 8);
                const char* xpA = (const char*)(xpad +
                    ((size_t)((bi * 16 + t) * 66 + row)) * 68 * 4);
                half8f a0 = first ? z8 : *(const half8f*)(hpA + (ty0 * 68 + colA + tx0) * 16);
                half8f a1 = first ? z8 : *(const half8f*)(hpA + (ty1 * 68 + colA + tx1) * 16);
                half8f a2;
                if (g4 == 0) a2 = first ? z8 : *(const half8f*)(hpA + (2 * 68 + colA + 2) * 16);
                else         a2 = LDX(xpA, (ty2 * 68 + colA + tx2) * 8);
                half8f a3 = LDX(xpA, (ty3 * 68 + colA + tx3) * 8);
                GATE_BODY(a0, a1, a2, a3, cold[0], cold[1], cc0, cc1, hh0, hh1);
            }
            half2f hw = {(f16)hh0, (f16)hh1};
            *(half2f*)(smem + BANDA + (bl * 68 + 1 + colA) * 16 + f0 * 2) = hw;
            if (bl >= 1 && bl <= 12) {
                floatx2 cw = {cc0, cc1};
                *(floatx2*)(smem + CLDS4 + (((bl - 1) * 64 + colA) * 8 + f0) * 4) = cw;
            }
        }
    }
    __syncthreads();

    // ======== PHASE 1: bl 1..12 (48 tiles), BANDA -> BANDB ========
    #pragma unroll
    for (int k = 0; k < 3; ++k) {
        const int tau = k * 16 + w;
        const int bl = 1 + (tau >> 2), ct = tau & 3;
        const int row = r0 - 3 + bl;
        const bool vA = ((unsigned)row < 64u);
        const int colA = ct * 16 + p16;
        float cc0 = 0.f, cc1 = 0.f, hh0 = 0.f, hh1 = 0.f;
        if (vA) {
            floatx2 cold = *(const floatx2*)(smem + CLDS4 +
                               (((bl - 1) * 64 + colA) * 8 + f0) * 4);
            const char* xpA = (const char*)(xpad +
                ((size_t)((bi * 16 + t + 1) * 66 + row)) * 68 * 4);
            half8f a0 = *(const half8f*)(smem + BANDA + ((bl - 1 + ty0) * 68 + colA + tx0) * 16);
            half8f a1 = *(const half8f*)(smem + BANDA + ((bl - 1 + ty1) * 68 + colA + tx1) * 16);
            half8f a2;
            if (g4 == 0) a2 = *(const half8f*)(smem + BANDA + ((bl + 1) * 68 + colA + 2) * 16);
            else         a2 = LDX(xpA, (ty2 * 68 + colA + tx2) * 8);
            half8f a3 = LDX(xpA, (ty3 * 68 + colA + tx3) * 8);
            GATE_BODY(a0, a1, a2, a3, cold[0], cold[1], cc0, cc1, hh0, hh1);
        }
        half2f hw = {(f16)hh0, (f16)hh1};
        *(half2f*)(smem + BANDB + (bl * 68 + 1 + colA) * 16 + f0 * 2) = hw;
        floatx2 cw = {cc0, cc1};
        *(floatx2*)(smem + CLDS4 + (((bl - 1) * 64 + colA) * 8 + f0) * 4) = cw;
    }
    __syncthreads();

    // ======== PHASE 2: bl 2..11 (40 tiles), BANDB -> BANDA ========
    #pragma unroll
    for (int k = 0; k < 3; ++k) {
        const int tau = k * 16 + w;
        if (tau < 40) {
            const int bl = 2 + (tau >> 2), ct = tau & 3;
            const int row = r0 - 3 + bl;
            const bool vA = ((unsigned)row < 64u);
            const int colA = ct * 16 + p16;
            float cc0 = 0.f, cc1 = 0.f, hh0 = 0.f, hh1 = 0.f;
            if (vA) {
                floatx2 cold = *(const floatx2*)(smem + CLDS4 +
                                   (((bl - 1) * 64 + colA) * 8 + f0) * 4);
                const char* xpA = (const char*)(xpad +
                    ((size_t)((bi * 16 + t + 2) * 66 + row)) * 68 * 4);
                half8f a0 = *(const half8f*)(smem + BANDB + ((bl - 1 + ty0) * 68 + colA + tx0) * 16);
                half8f a1 = *(const half8f*)(smem + BANDB + ((bl - 1 + ty1) * 68 + colA + tx1) * 16);
                half8f a2;
                if (g4 == 0) a2 = *(const half8f*)(smem + BANDB + ((bl + 1) * 68 + colA + 2) * 16);
                else         a2 = LDX(xpA, (ty2 * 68 + colA + tx2) * 8);
                half8f a3 = LDX(xpA, (ty3 * 68 + colA + tx3) * 8);
                GATE_BODY(a0, a1, a2, a3, cold[0], cold[1], cc0, cc1, hh0, hh1);
            }
            half2f hw = {(f16)hh0, (f16)hh1};
            *(half2f*)(smem + BANDA + (bl * 68 + 1 + colA) * 16 + f0 * 2) = hw;
            floatx2 cw = {cc0, cc1};
            *(floatx2*)(smem + CLDS4 + (((bl - 1) * 64 + colA) * 8 + f0) * 4) = cw;
        }
    }
    __syncthreads();

    // ======== PHASE 3: bl 3..10 (32 tiles), BANDA -> global / head ========
    {
        float ha0 = 0.f, ha1 = 0.f, ha2 = 0.f, ha3 = 0.f;
        #pragma unroll
        for (int k = 0; k < 2; ++k) {
            const int tau = k * 16 + w;
            const int bl = 3 + (tau >> 2), ct = tau & 3;
            const int row = r0 - 3 + bl;                 // r0..r0+7, valid
            const int colA = ct * 16 + p16;
            floatx2 cold = *(const floatx2*)(smem + CLDS4 +
                               (((bl - 1) * 64 + colA) * 8 + f0) * 4);
            const char* xpA = (const char*)(xpad +
                ((size_t)((bi * 16 + t + 3) * 66 + row)) * 68 * 4);
            half8f a0 = *(const half8f*)(smem + BANDA + ((bl - 1 + ty0) * 68 + colA + tx0) * 16);
            half8f a1 = *(const half8f*)(smem + BANDA + ((bl - 1 + ty1) * 68 + colA + tx1) * 16);
            half8f a2;
            if (g4 == 0) a2 = *(const half8f*)(smem + BANDA + ((bl + 1) * 68 + colA + 2) * 16);
            else         a2 = LDX(xpA, (ty2 * 68 + colA + tx2) * 8);
            half8f a3 = LDX(xpA, (ty3 * 68 + colA + tx3) * 8);
            float cc0, cc1, hh0, hh1;
            GATE_BODY(a0, a1, a2, a3, cold[0], cold[1], cc0, cc1, hh0, hh1);

            if (!do_head) {
                const size_t gp = (size_t)(bi * 4096 + row * 64 + colA);
                floatx2 cw = {cc0, cc1};
                *(floatx2*)(c_buf + gp * 8 + f0) = cw;
                const size_t hb = ((size_t)(bi * 66 + row + 1) * 68 + 1 + colA) * 8 + f0;
                half2f hw = {(f16)hh0, (f16)hh1};
                *(half2f*)(h_out + hb) = hw;
            } else {
                int pix = row * 64 + colA;
                floatx4 wa  = *(const floatx4*)(Wout + (size_t)(pix * 8 + f0) * 4);
                floatx4 wb2 = *(const floatx4*)(Wout + (size_t)(pix * 8 + f0 + 1) * 4);
                ha0 = fmaf(hh0, wa[0], fmaf(hh1, wb2[0], ha0));
                ha1 = fmaf(hh0, wa[1], fmaf(hh1, wb2[1], ha1));
                ha2 = fmaf(hh0, wa[2], fmaf(hh1, wb2[2], ha2));
                ha3 = fmaf(hh0, wa[3], fmaf(hh1, wb2[3], ha3));
            }
        }

        if (do_head) {
            #pragma unroll
            for (int off = 32; off >= 1; off >>= 1) {
                ha0 += __shfl_down(ha0, off, 64);
                ha1 += __shfl_down(ha1, off, 64);
                ha2 += __shfl_down(ha2, off, 64);
                ha3 += __shfl_down(ha3, off, 64);
            }
            if (lane == 0) {
                floatx4 v = {ha0, ha1, ha2, ha3};
                *(floatx4*)(smem + REDF4 + w * 16) = v;
            }
            __syncthreads();
            if (tid == 0) {
                floatx4 s = {0.f, 0.f, 0.f, 0.f};
                #pragma unroll
                for (int k = 0; k < 16; ++k)
                    s += *(const floatx4*)(smem + REDF4 + k * 16);
                *(floatx4*)(partial + (size_t)bid * 4) = s;
            }
        }
    }

    // x-convert stores (loads issued at kernel start); 2 adjacent pixels
    if (cv) {
        f16* dst = xpad + ((size_t)((bi * 16 + csl) * 66 + cgr + 1) * 68 + cgc + 1) * 4;
        half4f va = {(f16)cxa0, (f16)cxa1, (f16)cxa2, (f16)1.0f};
        half4f vb = {(f16)cxb0, (f16)cxb1, (f16)cxb2, (f16)1.0f};
        *(half4f*)(dst)     = va;
        *(half4f*)(dst + 4) = vb;
    }
}

__global__ __launch_bounds__(64) void head_finish(
    const float* __restrict__ partial,  // (256,4): bid = bi*8+strip
    const float* __restrict__ bout,
    float* __restrict__ out)
{
    int b = threadIdx.x;
    if (b >= NB) return;
    float l0 = bout[0], l1 = bout[1], l2 = bout[2], l3 = bout[3];
    for (int s = 0; s < 8; ++s) {
        floatx4 p = *(const floatx4*)(partial + (size_t)(b * 8 + s) * 4);
        l0 += p[0]; l1 += p[1]; l2 += p[2]; l3 += p[3];
    }
    float m = fmaxf(fmaxf(l0, l1), fmaxf(l2, l3));
    float e0 = expf(l0 - m), e1 = expf(l1 - m);
    float e2 = expf(l2 - m), e3 = expf(l3 - m);
    float inv = 1.0f / (e0 + e1 + e2 + e3);
    out[b * 4 + 0] = e0 * inv;
    out[b * 4 + 1] = e1 * inv;
    out[b * 4 + 2] = e2 * inv;
    out[b * 4 + 3] = e3 * inv;
}

// ========== fallback (ws too small): r8-style LDS per-step path ==========
__global__ __launch_bounds__(256) void prepack_fb(
    const float* __restrict__ Wx, const float* __restrict__ Wh,
    const float* __restrict__ bias, f16* __restrict__ WB)
{
    int i = blockIdx.x * 256 + threadIdx.x;
    if (i < 4096) WB[i] = (f16)wb_entry(i, Wx, Wh, bias);
}

#define FB_XOFF 4352
#define FB_SMEM 6528

#define LDAS(off) ({                                                       \
    half4f lo_ = *(const half4f*)(smem + (off));                           \
    half4f hi_ = *(const half4f*)(smem + (off) + 8);                       \
    __builtin_shufflevector(lo_, hi_, 0, 1, 2, 3, 4, 5, 6, 7); })

__global__ __launch_bounds__(256, 4) void convlstm_step_fb(
    const float* __restrict__ x, const f16* __restrict__ WB,
    const f16* __restrict__ h_in, f16* __restrict__ h_out,
    float* __restrict__ c_buf, int t, int first)
{
    __shared__ __attribute__((aligned(16))) char smem[FB_SMEM];

    const int bid = blockIdx.x;
    const int bi  = bid >> 5;
    const int r0  = (bid & 31) << 1;
    const int tid = threadIdx.x;
    const int w    = tid >> 6;
    const int lane = tid & 63;
    const int p16  = lane & 15;
    const int g4   = lane >> 4;
    const int pr   = w >> 1;
    const int wcol = (w & 1) << 5;

    const float* xt = x + (((size_t)bi * NT + t) * 4096) * 3;

    for (int i = tid; i < 272; i += 256) {
        int lr = i / 68, lc = i - lr * 68;
        int gr = r0 - 1 + lr, gc = lc - 1;
        bool ok = ((unsigned)gr < 64u) && ((unsigned)gc < 64u);
        half4f xv = {0, 0, 0, (f16)1.0f};
        half8f hv = {0, 0, 0, 0, 0, 0, 0, 0};
        if (ok) {
            const float* xp = xt + (gr * 64 + gc) * 3;
            xv[0] = (f16)xp[0]; xv[1] = (f16)xp[1]; xv[2] = (f16)xp[2];
            if (!first)
                hv = *(const half8f*)(h_in + ((size_t)(bi * 4096 + gr * 64 + gc)) * 8);
        }
        *(half8f*)(smem + i * 16) = hv;
        *(half4f*)(smem + FB_XOFF + i * 8) = xv;
    }

    const half8f* WBv = (const half8f*)WB;
    half8f B00 = WBv[0*64+lane], B01 = WBv[1*64+lane];
    half8f B10 = WBv[2*64+lane], B11 = WBv[3*64+lane];
    half8f B20 = WBv[4*64+lane], B21 = WBv[5*64+lane];
    half8f B30 = WBv[6*64+lane], B31 = WBv[7*64+lane];

    const int f0 = g4 << 1;
    const size_t gp0 = (size_t)(bi * 4096 + (r0 + pr) * 64 + wcol + p16);
    const size_t gp1 = gp0 + 16;
    floatx2 cold0 = {0.f, 0.f}, cold1 = {0.f, 0.f};
    if (!first) {
        cold0 = *(const floatx2*)(c_buf + gp0 * 8 + f0);
        cold1 = *(const floatx2*)(c_buf + gp1 * 8 + f0);
    }

    __syncthreads();

    const int ty0 = (g4 >= 3) ? 1 : 0, tx0 = g4 - 3 * ty0;
    const int ty1 = 1 + ((g4 >= 2) ? 1 : 0), tx1 = (g4 + 4) - 3 * ty1;
    const int ty2 = (g4 == 3) ? 1 : 0, tx2 = (g4 == 2) ? 2 : 0;
    const int ty3 = (g4 == 0) ? 1 : 2, tx3 = (g4 == 1) ? 0 : 2;
    const int inc2 = (g4 == 0) ? 256 : 128;
    int o0 = ((pr + ty0) * 68 + wcol + p16 + tx0) * 16;
    int o1 = ((pr + ty1) * 68 + wcol + p16 + tx1) * 16;
    int o2 = (g4 == 0) ? ((pr + 2) * 68 + wcol + p16 + 2) * 16
                       : FB_XOFF + ((pr + ty2) * 68 + wcol + p16 + tx2) * 8;
    int o3 = FB_XOFF + ((pr + ty3) * 68 + wcol + p16 + tx3) * 8;

    #pragma unroll
    for (int tt = 0; tt < 2; ++tt) {
        half8f a0 = LDAS(o0), a1 = LDAS(o1), a2 = LDAS(o2), a3 = LDAS(o3);
        floatx2 cold = tt ? cold1 : cold0;
        float cc0, cc1, hh0, hh1;
        GATE_BODY(a0, a1, a2, a3, cold[0], cold[1], cc0, cc1, hh0, hh1);
        const size_t gp = tt ? gp1 : gp0;
        floatx2 cw = {cc0, cc1};
        *(floatx2*)(c_buf + gp * 8 + f0) = cw;
        half2f hw = {(f16)hh0, (f16)hh1};
        *(half2f*)(h_out + gp * 8 + f0) = hw;
        o0 += 256; o1 += 256; o2 += inc2; o3 += 128;
    }
}

__global__ __launch_bounds__(256) void head_partial_fb(
    const f16* __restrict__ h, const float* __restrict__ Wout,
    float* __restrict__ partial)
{
    const int b = blockIdx.x >> 4;
    const int chunk = blockIdx.x & 15;
    const int tid = threadIdx.x;
    const f16* hb = h + (size_t)b * 32768 + chunk * 2048;
    const float* wb = Wout + (size_t)(chunk * 2048) * 4;

    float acc[4] = {0.f, 0.f, 0.f, 0.f};
    #pragma unroll
    for (int it = 0; it < 8; ++it) {
        int i = it * 256 + tid;
        float hv = (float)hb[i];
        float4 wv = *(const float4*)(wb + (size_t)i * 4);
        acc[0] = fmaf(hv, wv.x, acc[0]);
        acc[1] = fmaf(hv, wv.y, acc[1]);
        acc[2] = fmaf(hv, wv.z, acc[2]);
        acc[3] = fmaf(hv, wv.w, acc[3]);
    }
    #pragma unroll
    for (int j = 0; j < 4; ++j)
        #pragma unroll
        for (int off = 32; off >= 1; off >>= 1)
            acc[j] += __shfl_down(acc[j], off, 64);

    __shared__ float red2[4][4];
    int lane = tid & 63, wv2 = tid >> 6;
    if (lane == 0) {
        #pragma unroll
        for (int j = 0; j < 4; ++j) red2[wv2][j] = acc[j];
    }
    __syncthreads();
    if (tid == 0) {
        #pragma unroll
        for (int j = 0; j < 4; ++j)
            partial[(size_t)blockIdx.x * 4 + j] =
                red2[0][j] + red2[1][j] + red2[2][j] + red2[3][j];
    }
}

__global__ __launch_bounds__(64) void head_finish_fb(
    const float* __restrict__ partial, const float* __restrict__ bout,
    float* __restrict__ out)
{
    int b = threadIdx.x;
    if (b >= NB) return;
    float logit[4] = {bout[0], bout[1], bout[2], bout[3]};
    #pragma unroll
    for (int k = 0; k < 16; ++k) {
        const float* p = partial + (size_t)(b * 16 + k) * 4;
        logit[0] += p[0]; logit[1] += p[1]; logit[2] += p[2]; logit[3] += p[3];
    }
    float m = fmaxf(fmaxf(logit[0], logit[1]), fmaxf(logit[2], logit[3]));
    float e[4], s = 0.f;
    #pragma unroll
    for (int j = 0; j < 4; ++j) { e[j] = expf(logit[j] - m); s += e[j]; }
    float inv = 1.0f / s;
    #pragma unroll
    for (int j = 0; j < 4; ++j) out[b * 4 + j] = e[j] * inv;
}

extern "C" void kernel_launch(void* const* d_in, const int* in_sizes, int n_in,
                              void* d_out, int out_size, void* d_ws, size_t ws_size,
                              hipStream_t stream) {
    const float* x    = (const float*)d_in[0];
    const float* Wx   = (const float*)d_in[1];
    const float* Wh   = (const float*)d_in[2];
    const float* b    = (const float*)d_in[3];
    const float* Wout = (const float*)d_in[4];
    const float* bout = (const float*)d_in[5];
    float* out = (float*)d_out;
    char* ws = (char*)d_ws;

    if (ws_size >= WS_NEED) {
        f16*   xpad  = (f16*)(ws + XPAD_OFF);
        f16*   h0    = (f16*)(ws + HPAD0_OFF);
        f16*   h1    = (f16*)(ws + HPAD1_OFF);
        float* cb    = (float*)(ws + CBUF_OFF);
        f16*   WBq   = (f16*)(ws + WBQ_OFF);
        float* part  = (float*)(ws + PART_OFF);

        init_all<<<2946, 256, 0, stream>>>(x, Wx, Wh, b, xpad, h0, h1, WBq);

        // fused kernel k covers t = 4k..4k+3; converts x slices 4k+4..4k+7.
        for (int k = 0; k < 4; ++k) {
            const f16* hin  = (k & 1) ? h0 : h1;   // k=0: h1 (unused, first)
            f16*       hout = (k & 1) ? h1 : h0;
            convlstm_fused4w<<<256, 1024, 0, stream>>>(
                x, xpad, WBq, hin, hout, cb, Wout, part,
                4 * k, (k == 0) ? 1 : 0, (k == 3) ? 1 : 0);
        }
        head_finish<<<1, 64, 0, stream>>>(part, bout, out);
    } else {
        f16*   hA      = (f16*)ws;                    // 2 MB
        f16*   hB      = (f16*)(ws + (1u << 21));     // 2 MB
        float* cb      = (float*)(ws + (1u << 22));   // 4 MB
        f16*   WBq     = (f16*)(ws + (1u << 23));     // 8 KB
        float* partial = (float*)(ws + (1u << 23) + 8192);

        prepack_fb<<<16, 256, 0, stream>>>(Wx, Wh, b, WBq);
        for (int t = 0; t < NT; ++t) {
            const f16* hin = (t & 1) ? hA : hB;
            f16*       hout = (t & 1) ? hB : hA;
            convlstm_step_fb<<<1024, 256, 0, stream>>>(x, WBq, hin, hout, cb,
                                                       t, (t == 0) ? 1 : 0);
        }
        head_partial_fb<<<512, 256, 0, stream>>>(hB, Wout, partial);
        head_finish_fb<<<1, 64, 0, stream>>>(partial, bout, out);
    }
}

// Round 19
// 64.000 us; speedup vs baseline: 10.1153x; 1.0276x over previous
//
#include <hip/hip_runtime.h>
#include <math.h>

#define NB 32
#define NT 16

typedef _Float16 f16;
typedef _Float16 half2f __attribute__((ext_vector_type(2)));
typedef _Float16 half4f __attribute__((ext_vector_type(4)));
typedef _Float16 half8f __attribute__((ext_vector_type(8)));
typedef float    floatx2 __attribute__((ext_vector_type(2)));
typedef float    floatx4 __attribute__((ext_vector_type(4)));

// ---- workspace layout (bytes) ----
#define XPAD_OFF  0u                     // (512, 66*68, 4) f16 = 18,382,848
#define HPAD0_OFF 18382848u              // (32, 66, 68, 8) f16 = 2,297,856
#define HPAD1_OFF 20680704u
#define CBUF_OFF  22978560u              // (32, 64, 64, 8) f32 = 4,194,304
#define WBQ_OFF   27172864u              // 4096 f16 = 8192
#define PART_OFF  27181056u              // 256 float4 = 4096
#define WS_NEED   27197440u

// ---- fused-4 R=8 kernel LDS (bytes) ----
// BANDA/BANDB: 14 rows x 68 x 16B (8ch f16) = 15,232 each
// CLDS: g4-major [4][12][64] floatx2, 8B pad per g4 block (bank-spread)
#define BANDA   0
#define BANDB   15232
#define CLDS4   30464
#define CLG     6152                     // 12*64*8 + 8 pad
#define REDF4   55072                    // 30464 + 4*6152 = 55072
#define SMEM5   55328

// cLDS address: lane-consecutive colA -> 8B stride (conflict-free);
// g4 blocks shifted by 2 banks (even 2-way = free).
#define CLA(ci, col) (CLDS4 + g4 * CLG + (((ci) * 64 + (col)) * 8))

__device__ __forceinline__ float hard_sigmoid(float v) {
    return fminf(fmaxf(fmaf(0.2f, v, 0.5f), 0.0f), 1.0f);
}
__device__ __forceinline__ float fast_tanh(float v) {
    float e = __builtin_amdgcn_exp2f(v * 2.8853900817779268f);
    return 1.0f - 2.0f * __builtin_amdgcn_rcpf(e + 1.0f);
}

// Weight-fragment entry (validated r12-r18): lane owns adjacent filters
// 2g4, 2g4+1; acc rows = [i,f,c,o].
__device__ __forceinline__ float wb_entry(int i, const float* Wx,
                                          const float* Wh, const float* bias) {
    int e = i & 7, l = (i >> 3) & 63, n = (i >> 9) & 1, j = i >> 10;
    int h = l >> 4;
    int rr = l & 15;
    int g = (rr & 3) * 8 + 2 * (rr >> 2) + n;
    float wv = 0.f;
    if (j == 0) {
        wv = Wh[(h * 8 + e) * 32 + g];
    } else if (j == 1) {
        wv = Wh[((4 + h) * 8 + e) * 32 + g];
    } else if (j == 2 && h == 0) {
        wv = Wh[(64 + e) * 32 + g];
    } else if (j == 3 && h == 3) {
        wv = (e == 3) ? bias[g] : 0.f;
    } else {
        int ty, txp;
        if (j == 2) { ty = (h == 3) ? 1 : 0; txp = (h == 2) ? 2 : 0; }
        else        { ty = (h == 0) ? 1 : 2; txp = (h == 1) ? 0 : 2; }
        int txq = txp + (e >> 2), c = e & 3;
        if (txq < 3 && c < 3)
            wv = Wx[((ty * 3 + txq) * 3 + c) * 32 + g];
    }
    return wv;
}

#define LDX(base, off) ({                                                  \
    half4f lo_ = *(const half4f*)((base) + (off));                         \
    half4f hi_ = *(const half4f*)((base) + (off) + 8);                     \
    __builtin_shufflevector(lo_, hi_, 0, 1, 2, 3, 4, 5, 6, 7); })

#define GATE_BODY(A0, A1, A2, A3, COLD0, COLD1, CC0, CC1, HH0, HH1)        \
    {                                                                      \
        floatx4 acc0 = {0.f, 0.f, 0.f, 0.f};                               \
        floatx4 acc1 = {0.f, 0.f, 0.f, 0.f};                               \
        acc0 = __builtin_amdgcn_mfma_f32_16x16x32_f16(B00, A0, acc0,0,0,0);\
        acc1 = __builtin_amdgcn_mfma_f32_16x16x32_f16(B01, A0, acc1,0,0,0);\
        acc0 = __builtin_amdgcn_mfma_f32_16x16x32_f16(B10, A1, acc0,0,0,0);\
        acc1 = __builtin_amdgcn_mfma_f32_16x16x32_f16(B11, A1, acc1,0,0,0);\
        acc0 = __builtin_amdgcn_mfma_f32_16x16x32_f16(B20, A2, acc0,0,0,0);\
        acc1 = __builtin_amdgcn_mfma_f32_16x16x32_f16(B21, A2, acc1,0,0,0);\
        acc0 = __builtin_amdgcn_mfma_f32_16x16x32_f16(B30, A3, acc0,0,0,0);\
        acc1 = __builtin_amdgcn_mfma_f32_16x16x32_f16(B31, A3, acc1,0,0,0);\
        float ig0 = hard_sigmoid(acc0[0]), fg0 = hard_sigmoid(acc0[1]);    \
        float cg0 = fast_tanh(acc0[2]),    og0 = hard_sigmoid(acc0[3]);    \
        CC0 = fmaf(fg0, COLD0, ig0 * cg0);                                 \
        HH0 = og0 * fast_tanh(CC0);                                        \
        float ig1 = hard_sigmoid(acc1[0]), fg1 = hard_sigmoid(acc1[1]);    \
        float cg1 = fast_tanh(acc1[2]),    og1 = hard_sigmoid(acc1[3]);    \
        CC1 = fmaf(fg1, COLD1, ig1 * cg1);                                 \
        HH1 = og1 * fast_tanh(CC1);                                        \
    }

// ---- init: xpad borders + h borders + WB + x slices 0..3 ----
__global__ __launch_bounds__(256) void init_all(
    const float* __restrict__ x,
    const float* __restrict__ Wx, const float* __restrict__ Wh,
    const float* __restrict__ bias,
    f16* __restrict__ xpad, f16* __restrict__ h0, f16* __restrict__ h1,
    f16* __restrict__ WB)
{
    int i = blockIdx.x * 256 + threadIdx.x;
    if (i < 200704) {                      // xpad borders: 512 x 392
        int bt = i / 392, p = i - bt * 392;
        int rr, cc;
        if (p < 136) { rr = (p < 68) ? 0 : 65; cc = p - ((p < 68) ? 0 : 68); }
        else { int q = p - 136; rr = 1 + (q >> 2); int m = q & 3;
               cc = (m == 0) ? 0 : 64 + m; }
        half4f v = {0, 0, 0, (f16)1.0f};
        *(half4f*)(xpad + ((size_t)(bt * 66 + rr) * 68 + cc) * 4) = v;
    } else if (i < 225792) {               // h borders: 2 x 32 x 392
        int k = i - 200704;
        int buf = k / 12544; k -= buf * 12544;
        int b = k / 392, p = k - b * 392;
        int rr, cc;
        if (p < 136) { rr = (p < 68) ? 0 : 65; cc = p - ((p < 68) ? 0 : 68); }
        else { int q = p - 136; rr = 1 + (q >> 2); int m = q & 3;
               cc = (m == 0) ? 0 : 64 + m; }
        f16* hp = buf ? h1 : h0;
        half8f zz = {0, 0, 0, 0, 0, 0, 0, 0};
        *(half8f*)(hp + ((size_t)(b * 66 + rr) * 68 + cc) * 8) = zz;
    } else if (i < 229888) {               // WB: 4096
        int k = i - 225792;
        WB[k] = (f16)wb_entry(k, Wx, Wh, bias);
    } else if (i < 754176) {               // x slices 0..3: 32 x 4 x 4096
        int j = i - 229888;
        int b = j >> 14;
        int rem = j & 16383;
        int s = rem >> 12, px = rem & 4095;
        const float* xp = x + ((size_t)(b * 16 + s) * 4096 + px) * 3;
        half4f v = {(f16)xp[0], (f16)xp[1], (f16)xp[2], (f16)1.0f};
        int gr = px >> 6, gc = px & 63;
        *(half4f*)(xpad + ((size_t)((b * 16 + s) * 66 + gr + 1) * 68 + gc + 1) * 4) = v;
    }
}

// ---- fused 4-step, R=8 strips (r18 structure) + x software pipelining:
// each phase's xpad operands are prefetched into registers DURING the
// previous phase (they are independent of this kernel's LDS writes), so
// the post-barrier critical path starts with data in hand. cLDS re-laid
// g4-major + 8B pad: 4-way bank conflict -> free 2-way.
__global__ __launch_bounds__(1024, 4) void convlstm_fused4w(
    const float* __restrict__ x,     // raw input (for next-slice conversion)
    f16* __restrict__ xpad,          // (512, 66*68, 4)
    const f16* __restrict__ WB,
    const f16* __restrict__ h_in,    // padded (32,66,68,8): h(t-1)
    f16* __restrict__ h_out,         // padded: h(t+3)
    float* __restrict__ c_buf,       // (32,64,64,8) f32: in c(t-1), out c(t+3)
    const float* __restrict__ Wout,  // (32768,4)
    float* __restrict__ partial,     // (256,4)
    int t, int first, int do_head)
{
    __shared__ __attribute__((aligned(16))) char smem[SMEM5];

    const int bid0 = blockIdx.x;
    const int bid  = ((bid0 & 7) << 5) | (bid0 >> 3);   // XCD-contiguous
    const int bi  = bid >> 3;
    const int r0  = (bid & 7) << 3;
    const int tid = threadIdx.x;
    const int w    = __builtin_amdgcn_readfirstlane(tid >> 6);  // 0..15
    const int lane = tid & 63;
    const int p16  = lane & 15;
    const int g4   = lane >> 4;
    const int f0   = g4 << 1;

    // early x-convert source loads: slices t+4..t+7; 2 adjacent px/thread
    const int csl = t + 4 + (tid >> 8);
    const bool cv = (csl < NT);
    const int cpb = (tid & 255) << 1;
    const int cgr = r0 + (cpb >> 6), cgc = cpb & 63;
    float cxa0 = 0.f, cxa1 = 0.f, cxa2 = 0.f;
    float cxb0 = 0.f, cxb1 = 0.f, cxb2 = 0.f;
    if (cv) {
        const float* p = x + ((size_t)(bi * NT + csl) * 4096 + cgr * 64 + cgc) * 3;
        cxa0 = p[0]; cxa1 = p[1]; cxa2 = p[2];
        cxb0 = p[3]; cxb1 = p[4]; cxb2 = p[5];
    }

    // weight fragments
    const half8f* WBv = (const half8f*)WB;
    half8f B00 = WBv[0*64+lane], B01 = WBv[1*64+lane];
    half8f B10 = WBv[2*64+lane], B11 = WBv[3*64+lane];
    half8f B20 = WBv[4*64+lane], B21 = WBv[5*64+lane];
    half8f B30 = WBv[6*64+lane], B31 = WBv[7*64+lane];

    // tap->offset tables (validated r7-r18)
    const int ty0 = (g4 >= 3) ? 1 : 0, tx0 = g4 - 3 * ty0;
    const int ty1 = 1 + ((g4 >= 2) ? 1 : 0), tx1 = (g4 + 4) - 3 * ty1;
    const int ty2 = (g4 == 3) ? 1 : 0, tx2 = (g4 == 2) ? 2 : 0;
    const int ty3 = (g4 == 0) ? 1 : 2, tx3 = (g4 == 1) ? 0 : 2;

    const half8f z8 = {0, 0, 0, 0, 0, 0, 0, 0};

    // ---- prefetch PHASE 1 x operands (slice t+1; 3 tiles/wave, all waves) --
    half8f p1x2[3], p1x3[3];
    #pragma unroll
    for (int k = 0; k < 3; ++k) {
        const int tau = k * 16 + w;
        const int bl = 1 + (tau >> 2), ct = tau & 3;
        const int row = r0 - 3 + bl;       // in-bounds of xpad (slice >= 1)
        const int colA = ct * 16 + p16;
        const char* xpA = (const char*)(xpad +
            ((size_t)((bi * 16 + t + 1) * 66 + row)) * 68 * 4);
        p1x2[k] = LDX(xpA, (ty2 * 68 + colA + tx2) * 8);
        p1x3[k] = LDX(xpA, (ty3 * 68 + colA + tx3) * 8);
    }

    // border cols (0, 65) of all 14 rows, both bands
    if (tid < 56) {
        int buf = tid / 28;
        int r2  = (tid % 28) >> 1;
        int cc  = (tid & 1) ? 65 : 0;
        *(half8f*)(smem + (buf ? BANDB : BANDA) + (r2 * 68 + cc) * 16) = z8;
    }

    // ======== PHASE 0: bl 0..13 (56 tiles), global h/c -> BANDA/cLDS ========
    #pragma unroll
    for (int k = 0; k < 4; ++k) {
        const int tau = k * 16 + w;
        if (tau < 56) {
            const int bl = tau >> 2, ct = tau & 3;
            const int row = r0 - 3 + bl;
            const bool vA = ((unsigned)row < 64u);
            const int colA = ct * 16 + p16;
            float cc0 = 0.f, cc1 = 0.f, hh0 = 0.f, hh1 = 0.f;
            if (vA) {
                floatx2 cold = {0.f, 0.f};
                if (!first)
                    cold = *(const floatx2*)(c_buf +
                               ((size_t)(bi * 4096 + row * 64 + colA)) * 8 + f0);
                const char* hpA = (const char*)(h_in + ((size_t)(bi * 66 + row)) * 68 * 8);
                const char* xpA = (const char*)(xpad +
                    ((size_t)((bi * 16 + t) * 66 + row)) * 68 * 4);
                half8f a0 = first ? z8 : *(const half8f*)(hpA + (ty0 * 68 + colA + tx0) * 16);
                half8f a1 = first ? z8 : *(const half8f*)(hpA + (ty1 * 68 + colA + tx1) * 16);
                half8f a2;
                if (g4 == 0) a2 = first ? z8 : *(const half8f*)(hpA + (2 * 68 + colA + 2) * 16);
                else         a2 = LDX(xpA, (ty2 * 68 + colA + tx2) * 8);
                half8f a3 = LDX(xpA, (ty3 * 68 + colA + tx3) * 8);
                GATE_BODY(a0, a1, a2, a3, cold[0], cold[1], cc0, cc1, hh0, hh1);
            }
            half2f hw = {(f16)hh0, (f16)hh1};
            *(half2f*)(smem + BANDA + (bl * 68 + 1 + colA) * 16 + f0 * 2) = hw;
            if (bl >= 1 && bl <= 12) {
                floatx2 cw = {cc0, cc1};
                *(floatx2*)(smem + CLA(bl - 1, colA)) = cw;
            }
        }
    }
    __syncthreads();

    // ======== PHASE 1: bl 1..12 (48 tiles), BANDA -> BANDB ========
    #pragma unroll
    for (int k = 0; k < 3; ++k) {
        const int tau = k * 16 + w;
        const int bl = 1 + (tau >> 2), ct = tau & 3;
        const int row = r0 - 3 + bl;
        const bool vA = ((unsigned)row < 64u);
        const int colA = ct * 16 + p16;
        float cc0 = 0.f, cc1 = 0.f, hh0 = 0.f, hh1 = 0.f;
        if (vA) {
            floatx2 cold = *(const floatx2*)(smem + CLA(bl - 1, colA));
            half8f a0 = *(const half8f*)(smem + BANDA + ((bl - 1 + ty0) * 68 + colA + tx0) * 16);
            half8f a1 = *(const half8f*)(smem + BANDA + ((bl - 1 + ty1) * 68 + colA + tx1) * 16);
            half8f a2 = (g4 == 0)
                ? *(const half8f*)(smem + BANDA + ((bl + 1) * 68 + colA + 2) * 16)
                : p1x2[k];
            half8f a3 = p1x3[k];
            GATE_BODY(a0, a1, a2, a3, cold[0], cold[1], cc0, cc1, hh0, hh1);
        }
        half2f hw = {(f16)hh0, (f16)hh1};
        *(half2f*)(smem + BANDB + (bl * 68 + 1 + colA) * 16 + f0 * 2) = hw;
        floatx2 cw = {cc0, cc1};
        *(floatx2*)(smem + CLA(bl - 1, colA)) = cw;
    }

    // ---- prefetch PHASE 2 x operands (slice t+2; tau<40) ----
    half8f p2x2[3], p2x3[3];
    #pragma unroll
    for (int k = 0; k < 3; ++k) {
        const int tau = k * 16 + w;
        if (tau < 40) {
            const int bl = 2 + (tau >> 2), ct = tau & 3;
            const int row = r0 - 3 + bl;
            const int colA = ct * 16 + p16;
            const char* xpA = (const char*)(xpad +
                ((size_t)((bi * 16 + t + 2) * 66 + row)) * 68 * 4);
            p2x2[k] = LDX(xpA, (ty2 * 68 + colA + tx2) * 8);
            p2x3[k] = LDX(xpA, (ty3 * 68 + colA + tx3) * 8);
        } else {
            p2x2[k] = z8; p2x3[k] = z8;
        }
    }
    __syncthreads();

    // ======== PHASE 2: bl 2..11 (40 tiles), BANDB -> BANDA ========
    #pragma unroll
    for (int k = 0; k < 3; ++k) {
        const int tau = k * 16 + w;
        if (tau < 40) {
            const int bl = 2 + (tau >> 2), ct = tau & 3;
            const int row = r0 - 3 + bl;
            const bool vA = ((unsigned)row < 64u);
            const int colA = ct * 16 + p16;
            float cc0 = 0.f, cc1 = 0.f, hh0 = 0.f, hh1 = 0.f;
            if (vA) {
                floatx2 cold = *(const floatx2*)(smem + CLA(bl - 1, colA));
                half8f a0 = *(const half8f*)(smem + BANDB + ((bl - 1 + ty0) * 68 + colA + tx0) * 16);
                half8f a1 = *(const half8f*)(smem + BANDB + ((bl - 1 + ty1) * 68 + colA + tx1) * 16);
                half8f a2 = (g4 == 0)
                    ? *(const half8f*)(smem + BANDB + ((bl + 1) * 68 + colA + 2) * 16)
                    : p2x2[k];
                half8f a3 = p2x3[k];
                GATE_BODY(a0, a1, a2, a3, cold[0], cold[1], cc0, cc1, hh0, hh1);
            }
            half2f hw = {(f16)hh0, (f16)hh1};
            *(half2f*)(smem + BANDA + (bl * 68 + 1 + colA) * 16 + f0 * 2) = hw;
            floatx2 cw = {cc0, cc1};
            *(floatx2*)(smem + CLA(bl - 1, colA)) = cw;
        }
    }

    // ---- prefetch PHASE 3 x operands (slice t+3; 2 tiles/wave) ----
    half8f p3x2[2], p3x3[2];
    #pragma unroll
    for (int k = 0; k < 2; ++k) {
        const int tau = k * 16 + w;
        const int bl = 3 + (tau >> 2), ct = tau & 3;
        const int row = r0 - 3 + bl;        // r0..r0+7, always valid
        const int colA = ct * 16 + p16;
        const char* xpA = (const char*)(xpad +
            ((size_t)((bi * 16 + t + 3) * 66 + row)) * 68 * 4);
        p3x2[k] = LDX(xpA, (ty2 * 68 + colA + tx2) * 8);
        p3x3[k] = LDX(xpA, (ty3 * 68 + colA + tx3) * 8);
    }
    __syncthreads();

    // ======== PHASE 3: bl 3..10 (32 tiles), BANDA -> global / head ========
    {
        float ha0 = 0.f, ha1 = 0.f, ha2 = 0.f, ha3 = 0.f;
        #pragma unroll
        for (int k = 0; k < 2; ++k) {
            const int tau = k * 16 + w;
            const int bl = 3 + (tau >> 2), ct = tau & 3;
            const int row = r0 - 3 + bl;
            const int colA = ct * 16 + p16;
            floatx2 cold = *(const floatx2*)(smem + CLA(bl - 1, colA));
            half8f a0 = *(const half8f*)(smem + BANDA + ((bl - 1 + ty0) * 68 + colA + tx0) * 16);
            half8f a1 = *(const half8f*)(smem + BANDA + ((bl - 1 + ty1) * 68 + colA + tx1) * 16);
            half8f a2 = (g4 == 0)
                ? *(const half8f*)(smem + BANDA + ((bl + 1) * 68 + colA + 2) * 16)
                : p3x2[k];
            half8f a3 = p3x3[k];
            float cc0, cc1, hh0, hh1;
            GATE_BODY(a0, a1, a2, a3, cold[0], cold[1], cc0, cc1, hh0, hh1);

            if (!do_head) {
                const size_t gp = (size_t)(bi * 4096 + row * 64 + colA);
                floatx2 cw = {cc0, cc1};
                *(floatx2*)(c_buf + gp * 8 + f0) = cw;
                const size_t hb = ((size_t)(bi * 66 + row + 1) * 68 + 1 + colA) * 8 + f0;
                half2f hw = {(f16)hh0, (f16)hh1};
                *(half2f*)(h_out + hb) = hw;
            } else {
                int pix = row * 64 + colA;
                floatx4 wa  = *(const floatx4*)(Wout + (size_t)(pix * 8 + f0) * 4);
                floatx4 wb2 = *(const floatx4*)(Wout + (size_t)(pix * 8 + f0 + 1) * 4);
                ha0 = fmaf(hh0, wa[0], fmaf(hh1, wb2[0], ha0));
                ha1 = fmaf(hh0, wa[1], fmaf(hh1, wb2[1], ha1));
                ha2 = fmaf(hh0, wa[2], fmaf(hh1, wb2[2], ha2));
                ha3 = fmaf(hh0, wa[3], fmaf(hh1, wb2[3], ha3));
            }
        }

        if (do_head) {
            #pragma unroll
            for (int off = 32; off >= 1; off >>= 1) {
                ha0 += __shfl_down(ha0, off, 64);
                ha1 += __shfl_down(ha1, off, 64);
                ha2 += __shfl_down(ha2, off, 64);
                ha3 += __shfl_down(ha3, off, 64);
            }
            if (lane == 0) {
                floatx4 v = {ha0, ha1, ha2, ha3};
                *(floatx4*)(smem + REDF4 + w * 16) = v;
            }
            __syncthreads();
            if (tid == 0) {
                floatx4 s = {0.f, 0.f, 0.f, 0.f};
                #pragma unroll
                for (int k = 0; k < 16; ++k)
                    s += *(const floatx4*)(smem + REDF4 + k * 16);
                *(floatx4*)(partial + (size_t)bid * 4) = s;
            }
        }
    }

    // x-convert stores (loads issued at kernel start); 2 adjacent pixels
    if (cv) {
        f16* dst = xpad + ((size_t)((bi * 16 + csl) * 66 + cgr + 1) * 68 + cgc + 1) * 4;
        half4f va = {(f16)cxa0, (f16)cxa1, (f16)cxa2, (f16)1.0f};
        half4f vb = {(f16)cxb0, (f16)cxb1, (f16)cxb2, (f16)1.0f};
        *(half4f*)(dst)     = va;
        *(half4f*)(dst + 4) = vb;
    }
}

__global__ __launch_bounds__(64) void head_finish(
    const float* __restrict__ partial,  // (256,4): bid = bi*8+strip
    const float* __restrict__ bout,
    float* __restrict__ out)
{
    int b = threadIdx.x;
    if (b >= NB) return;
    float l0 = bout[0], l1 = bout[1], l2 = bout[2], l3 = bout[3];
    for (int s = 0; s < 8; ++s) {
        floatx4 p = *(const floatx4*)(partial + (size_t)(b * 8 + s) * 4);
        l0 += p[0]; l1 += p[1]; l2 += p[2]; l3 += p[3];
    }
    float m = fmaxf(fmaxf(l0, l1), fmaxf(l2, l3));
    float e0 = expf(l0 - m), e1 = expf(l1 - m);
    float e2 = expf(l2 - m), e3 = expf(l3 - m);
    float inv = 1.0f / (e0 + e1 + e2 + e3);
    out[b * 4 + 0] = e0 * inv;
    out[b * 4 + 1] = e1 * inv;
    out[b * 4 + 2] = e2 * inv;
    out[b * 4 + 3] = e3 * inv;
}

// ========== fallback (ws too small): r8-style LDS per-step path ==========
__global__ __launch_bounds__(256) void prepack_fb(
    const float* __restrict__ Wx, const float* __restrict__ Wh,
    const float* __restrict__ bias, f16* __restrict__ WB)
{
    int i = blockIdx.x * 256 + threadIdx.x;
    if (i < 4096) WB[i] = (f16)wb_entry(i, Wx, Wh, bias);
}

#define FB_XOFF 4352
#define FB_SMEM 6528

#define LDAS(off) ({                                                       \
    half4f lo_ = *(const half4f*)(smem + (off));                           \
    half4f hi_ = *(const half4f*)(smem + (off) + 8);                       \
    __builtin_shufflevector(lo_, hi_, 0, 1, 2, 3, 4, 5, 6, 7); })

__global__ __launch_bounds__(256, 4) void convlstm_step_fb(
    const float* __restrict__ x, const f16* __restrict__ WB,
    const f16* __restrict__ h_in, f16* __restrict__ h_out,
    float* __restrict__ c_buf, int t, int first)
{
    __shared__ __attribute__((aligned(16))) char smem[FB_SMEM];

    const int bid = blockIdx.x;
    const int bi  = bid >> 5;
    const int r0  = (bid & 31) << 1;
    const int tid = threadIdx.x;
    const int w    = tid >> 6;
    const int lane = tid & 63;
    const int p16  = lane & 15;
    const int g4   = lane >> 4;
    const int pr   = w >> 1;
    const int wcol = (w & 1) << 5;

    const float* xt = x + (((size_t)bi * NT + t) * 4096) * 3;

    for (int i = tid; i < 272; i += 256) {
        int lr = i / 68, lc = i - lr * 68;
        int gr = r0 - 1 + lr, gc = lc - 1;
        bool ok = ((unsigned)gr < 64u) && ((unsigned)gc < 64u);
        half4f xv = {0, 0, 0, (f16)1.0f};
        half8f hv = {0, 0, 0, 0, 0, 0, 0, 0};
        if (ok) {
            const float* xp = xt + (gr * 64 + gc) * 3;
            xv[0] = (f16)xp[0]; xv[1] = (f16)xp[1]; xv[2] = (f16)xp[2];
            if (!first)
                hv = *(const half8f*)(h_in + ((size_t)(bi * 4096 + gr * 64 + gc)) * 8);
        }
        *(half8f*)(smem + i * 16) = hv;
        *(half4f*)(smem + FB_XOFF + i * 8) = xv;
    }

    const half8f* WBv = (const half8f*)WB;
    half8f B00 = WBv[0*64+lane], B01 = WBv[1*64+lane];
    half8f B10 = WBv[2*64+lane], B11 = WBv[3*64+lane];
    half8f B20 = WBv[4*64+lane], B21 = WBv[5*64+lane];
    half8f B30 = WBv[6*64+lane], B31 = WBv[7*64+lane];

    const int f0 = g4 << 1;
    const size_t gp0 = (size_t)(bi * 4096 + (r0 + pr) * 64 + wcol + p16);
    const size_t gp1 = gp0 + 16;
    floatx2 cold0 = {0.f, 0.f}, cold1 = {0.f, 0.f};
    if (!first) {
        cold0 = *(const floatx2*)(c_buf + gp0 * 8 + f0);
        cold1 = *(const floatx2*)(c_buf + gp1 * 8 + f0);
    }

    __syncthreads();

    const int ty0 = (g4 >= 3) ? 1 : 0, tx0 = g4 - 3 * ty0;
    const int ty1 = 1 + ((g4 >= 2) ? 1 : 0), tx1 = (g4 + 4) - 3 * ty1;
    const int ty2 = (g4 == 3) ? 1 : 0, tx2 = (g4 == 2) ? 2 : 0;
    const int ty3 = (g4 == 0) ? 1 : 2, tx3 = (g4 == 1) ? 0 : 2;
    const int inc2 = (g4 == 0) ? 256 : 128;
    int o0 = ((pr + ty0) * 68 + wcol + p16 + tx0) * 16;
    int o1 = ((pr + ty1) * 68 + wcol + p16 + tx1) * 16;
    int o2 = (g4 == 0) ? ((pr + 2) * 68 + wcol + p16 + 2) * 16
                       : FB_XOFF + ((pr + ty2) * 68 + wcol + p16 + tx2) * 8;
    int o3 = FB_XOFF + ((pr + ty3) * 68 + wcol + p16 + tx3) * 8;

    #pragma unroll
    for (int tt = 0; tt < 2; ++tt) {
        half8f a0 = LDAS(o0), a1 = LDAS(o1), a2 = LDAS(o2), a3 = LDAS(o3);
        floatx2 cold = tt ? cold1 : cold0;
        float cc0, cc1, hh0, hh1;
        GATE_BODY(a0, a1, a2, a3, cold[0], cold[1], cc0, cc1, hh0, hh1);
        const size_t gp = tt ? gp1 : gp0;
        floatx2 cw = {cc0, cc1};
        *(floatx2*)(c_buf + gp * 8 + f0) = cw;
        half2f hw = {(f16)hh0, (f16)hh1};
        *(half2f*)(h_out + gp * 8 + f0) = hw;
        o0 += 256; o1 += 256; o2 += inc2; o3 += 128;
    }
}

__global__ __launch_bounds__(256) void head_partial_fb(
    const f16* __restrict__ h, const float* __restrict__ Wout,
    float* __restrict__ partial)
{
    const int b = blockIdx.x >> 4;
    const int chunk = blockIdx.x & 15;
    const int tid = threadIdx.x;
    const f16* hb = h + (size_t)b * 32768 + chunk * 2048;
    const float* wb = Wout + (size_t)(chunk * 2048) * 4;

    float acc[4] = {0.f, 0.f, 0.f, 0.f};
    #pragma unroll
    for (int it = 0; it < 8; ++it) {
        int i = it * 256 + tid;
        float hv = (float)hb[i];
        float4 wv = *(const float4*)(wb + (size_t)i * 4);
        acc[0] = fmaf(hv, wv.x, acc[0]);
        acc[1] = fmaf(hv, wv.y, acc[1]);
        acc[2] = fmaf(hv, wv.z, acc[2]);
        acc[3] = fmaf(hv, wv.w, acc[3]);
    }
    #pragma unroll
    for (int j = 0; j < 4; ++j)
        #pragma unroll
        for (int off = 32; off >= 1; off >>= 1)
            acc[j] += __shfl_down(acc[j], off, 64);

    __shared__ float red2[4][4];
    int lane = tid & 63, wv2 = tid >> 6;
    if (lane == 0) {
        #pragma unroll
        for (int j = 0; j < 4; ++j) red2[wv2][j] = acc[j];
    }
    __syncthreads();
    if (tid == 0) {
        #pragma unroll
        for (int j = 0; j < 4; ++j)
            partial[(size_t)blockIdx.x * 4 + j] =
                red2[0][j] + red2[1][j] + red2[2][j] + red2[3][j];
    }
}

__global__ __launch_bounds__(64) void head_finish_fb(
    const float* __restrict__ partial, const float* __restrict__ bout,
    float* __restrict__ out)
{
    int b = threadIdx.x;
    if (b >= NB) return;
    float logit[4] = {bout[0], bout[1], bout[2], bout[3]};
    #pragma unroll
    for (int k = 0; k < 16; ++k) {
        const float* p = partial + (size_t)(b * 16 + k) * 4;
        logit[0] += p[0]; logit[1] += p[1]; logit[2] += p[2]; logit[3] += p[3];
    }
    float m = fmaxf(fmaxf(logit[0], logit[1]), fmaxf(logit[2], logit[3]));
    float e[4], s = 0.f;
    #pragma unroll
    for (int j = 0; j < 4; ++j) { e[j] = expf(logit[j] - m); s += e[j]; }
    float inv = 1.0f / s;
    #pragma unroll
    for (int j = 0; j < 4; ++j) out[b * 4 + j] = e[j] * inv;
}

extern "C" void kernel_launch(void* const* d_in, const int* in_sizes, int n_in,
                              void* d_out, int out_size, void* d_ws, size_t ws_size,
                              hipStream_t stream) {
    const float* x    = (const float*)d_in[0];
    const float* Wx   = (const float*)d_in[1];
    const float* Wh   = (const float*)d_in[2];
    const float* b    = (const float*)d_in[3];
    const float* Wout = (const float*)d_in[4];
    const float* bout = (const float*)d_in[5];
    float* out = (float*)d_out;
    char* ws = (char*)d_ws;

    if (ws_size >= WS_NEED) {
        f16*   xpad  = (f16*)(ws + XPAD_OFF);
        f16*   h0    = (f16*)(ws + HPAD0_OFF);
        f16*   h1    = (f16*)(ws + HPAD1_OFF);
        float* cb    = (float*)(ws + CBUF_OFF);
        f16*   WBq   = (f16*)(ws + WBQ_OFF);
        float* part  = (float*)(ws + PART_OFF);

        init_all<<<2946, 256, 0, stream>>>(x, Wx, Wh, b, xpad, h0, h1, WBq);

        // fused kernel k covers t = 4k..4k+3; converts x slices 4k+4..4k+7.
        for (int k = 0; k < 4; ++k) {
            const f16* hin  = (k & 1) ? h0 : h1;   // k=0: h1 (unused, first)
            f16*       hout = (k & 1) ? h1 : h0;
            convlstm_fused4w<<<256, 1024, 0, stream>>>(
                x, xpad, WBq, hin, hout, cb, Wout, part,
                4 * k, (k == 0) ? 1 : 0, (k == 3) ? 1 : 0);
        }
        head_finish<<<1, 64, 0, stream>>>(part, bout, out);
    } else {
        f16*   hA      = (f16*)ws;                    // 2 MB
        f16*   hB      = (f16*)(ws + (1u << 21));     // 2 MB
        float* cb      = (float*)(ws + (1u << 22));   // 4 MB
        f16*   WBq     = (f16*)(ws + (1u << 23));     // 8 KB
        float* partial = (float*)(ws + (1u << 23) + 8192);

        prepack_fb<<<16, 256, 0, stream>>>(Wx, Wh, b, WBq);
        for (int t = 0; t < NT; ++t) {
            const f16* hin = (t & 1) ? hA : hB;
            f16*       hout = (t & 1) ? hB : hA;
            convlstm_step_fb<<<1024, 256, 0, stream>>>(x, WBq, hin, hout, cb,
                                                       t, (t == 0) ? 1 : 0);
        }
        head_partial_fb<<<512, 256, 0, stream>>>(hB, Wout, partial);
        head_finish_fb<<<1, 64, 0, stream>>>(partial, bout, out);
    }
}